// Round 1
// baseline (11948.051 us; speedup 1.0000x reference)
//
#include <hip/hip_runtime.h>
#include <math.h>

namespace {

constexpr int B  = 256;
constexpr int N  = 64;
constexpr int D  = 512;
constexpr int H  = 8;
constexpr int NBLK = 4;
constexpr int M  = B * N;          // 16384 token rows
constexpr float EPS = 1e-5f;
constexpr float SCALE = 0.125f;    // 1/sqrt(64)

__device__ __forceinline__ float gelu_exact(float x) {
  return 0.5f * x * (1.0f + erff(x * 0.70710678118654752440f));
}

// ---------------------------------------------------------------------------
// Generic tiled fp32 GEMM: out[M,Nn] = epilogue(A[M,K] @ W[K,Nn] + bias)
// BM=64, BN=64, BK=32, 256 threads, 4x4 per thread. M, Nn multiples of 64.
// ---------------------------------------------------------------------------
template<bool GELU, bool BIAS>
__global__ __launch_bounds__(256) void gemm_kernel(
    const float* __restrict__ A, const float* __restrict__ W,
    const float* __restrict__ bias, float* __restrict__ out,
    int K, int Nn) {
  __shared__ float As[64][33];
  __shared__ float Bs[32][65];
  const int bm = blockIdx.x * 64;
  const int bn = blockIdx.y * 64;
  const int tid = threadIdx.x;
  const int tr = tid >> 4;      // 0..15 -> output rows tr*4..tr*4+3
  const int tc = tid & 15;      // 0..15 -> output cols tc*4..tc*4+3

  float acc[4][4] = {{0.f, 0.f, 0.f, 0.f}, {0.f, 0.f, 0.f, 0.f},
                     {0.f, 0.f, 0.f, 0.f}, {0.f, 0.f, 0.f, 0.f}};

  for (int k0 = 0; k0 < K; k0 += 32) {
    for (int i = tid; i < 64 * 32; i += 256) {
      int r = i >> 5, c = i & 31;
      int gk = k0 + c;
      As[r][c] = (gk < K) ? A[(size_t)(bm + r) * K + gk] : 0.f;
    }
    for (int i = tid; i < 32 * 64; i += 256) {
      int r = i >> 6, c = i & 63;
      int gk = k0 + r;
      Bs[r][c] = (gk < K) ? W[(size_t)gk * Nn + bn + c] : 0.f;
    }
    __syncthreads();
#pragma unroll
    for (int kk = 0; kk < 32; ++kk) {
      float a[4], b[4];
#pragma unroll
      for (int i = 0; i < 4; ++i) a[i] = As[tr * 4 + i][kk];
#pragma unroll
      for (int j = 0; j < 4; ++j) b[j] = Bs[kk][tc * 4 + j];
#pragma unroll
      for (int i = 0; i < 4; ++i)
#pragma unroll
        for (int j = 0; j < 4; ++j) acc[i][j] = fmaf(a[i], b[j], acc[i][j]);
    }
    __syncthreads();
  }

#pragma unroll
  for (int i = 0; i < 4; ++i) {
    int r = bm + tr * 4 + i;
#pragma unroll
    for (int j = 0; j < 4; ++j) {
      int c = bn + tc * 4 + j;
      float v = acc[i][j];
      if (BIAS) v += bias[c];
      if (GELU) v = gelu_exact(v);
      out[(size_t)r * Nn + c] = v;
    }
  }
}

// ---------------------------------------------------------------------------
// LayerNorm over D=512, optional fused residual add. One wave per row.
// ---------------------------------------------------------------------------
__global__ __launch_bounds__(256) void ln_kernel(
    const float* __restrict__ xin, const float* __restrict__ res,
    const float* __restrict__ g, const float* __restrict__ b,
    float* __restrict__ out) {
  const int row  = blockIdx.x * 4 + (threadIdx.x >> 6);
  const int lane = threadIdx.x & 63;
  const float* xr = xin + (size_t)row * D;

  float vals[8];
  float s = 0.f;
#pragma unroll
  for (int i = 0; i < 8; ++i) {
    float v = xr[i * 64 + lane];
    if (res) v += res[(size_t)row * D + i * 64 + lane];
    vals[i] = v;
    s += v;
  }
#pragma unroll
  for (int off = 1; off < 64; off <<= 1) s += __shfl_xor(s, off);
  const float mu = s * (1.f / D);

  float s2 = 0.f;
#pragma unroll
  for (int i = 0; i < 8; ++i) { float d = vals[i] - mu; s2 += d * d; }
#pragma unroll
  for (int off = 1; off < 64; off <<= 1) s2 += __shfl_xor(s2, off);
  const float rstd = rsqrtf(s2 * (1.f / D) + EPS);

#pragma unroll
  for (int i = 0; i < 8; ++i) {
    int c = i * 64 + lane;
    out[(size_t)row * D + c] = (vals[i] - mu) * rstd * g[c] + b[c];
  }
}

// ---------------------------------------------------------------------------
// Fused per-(batch, head) attention:
//   q = q_in[b] @ wq[:,hcols] + bq ; k,v likewise from kv_in[b]
//   S = causal_softmax(q k^T / 8) ; y[b,:,hcols] = S v
// 256 threads. LDS: q/k/v tiles [64][65] + staging; scores reuse the q tile.
// ---------------------------------------------------------------------------
__global__ __launch_bounds__(256) void attn_kernel(
    const float* __restrict__ kv_in, const float* __restrict__ q_in,
    const float* __restrict__ wq, const float* __restrict__ wk,
    const float* __restrict__ wv,
    const float* __restrict__ bq, const float* __restrict__ bk,
    const float* __restrict__ bv,
    float* __restrict__ y) {
  __shared__ float qs[64][65];
  __shared__ float ks[64][65];
  __shared__ float vs[64][65];
  __shared__ float As[64][17];   // input rows tile  [64][BK=16]
  __shared__ float Bs[16][65];   // weight tile      [BK=16][64]
  float* Ss = &qs[0][0];         // scores reuse q tile after it is consumed

  const int blk  = blockIdx.x;
  const int bidx = blk >> 3;     // / H
  const int h    = blk & 7;      // % H
  const int tid  = threadIdx.x;
  const int tr   = tid >> 4;
  const int tc   = tid & 15;
  const float* qin  = q_in  + (size_t)bidx * N * D;
  const float* kvin = kv_in + (size_t)bidx * N * D;

  // ---- Phase A: project q, k, v (each a [64,512]@[512,64] mini-GEMM) ----
  for (int t = 0; t < 3; ++t) {
    const float* in   = (t == 0) ? qin : kvin;
    const float* W    = (t == 0) ? wq : (t == 1 ? wk : wv);
    const float* bias = (t == 0) ? bq : (t == 1 ? bk : bv);
    float acc[4][4] = {{0.f, 0.f, 0.f, 0.f}, {0.f, 0.f, 0.f, 0.f},
                       {0.f, 0.f, 0.f, 0.f}, {0.f, 0.f, 0.f, 0.f}};
    for (int k0 = 0; k0 < D; k0 += 16) {
      for (int i = tid; i < 64 * 16; i += 256) {
        int r = i >> 4, c = i & 15;
        As[r][c] = in[(size_t)r * D + k0 + c];
      }
      for (int i = tid; i < 16 * 64; i += 256) {
        int r = i >> 6, c = i & 63;
        Bs[r][c] = W[(size_t)(k0 + r) * D + h * 64 + c];
      }
      __syncthreads();
#pragma unroll
      for (int kk = 0; kk < 16; ++kk) {
        float a[4], b[4];
#pragma unroll
        for (int i = 0; i < 4; ++i) a[i] = As[tr * 4 + i][kk];
#pragma unroll
        for (int j = 0; j < 4; ++j) b[j] = Bs[kk][tc * 4 + j];
#pragma unroll
        for (int i = 0; i < 4; ++i)
#pragma unroll
          for (int j = 0; j < 4; ++j) acc[i][j] = fmaf(a[i], b[j], acc[i][j]);
      }
      __syncthreads();
    }
    float* dst = (t == 0) ? &qs[0][0] : (t == 1 ? &ks[0][0] : &vs[0][0]);
#pragma unroll
    for (int i = 0; i < 4; ++i)
#pragma unroll
      for (int j = 0; j < 4; ++j)
        dst[(tr * 4 + i) * 65 + tc * 4 + j] = acc[i][j] + bias[h * 64 + tc * 4 + j];
    __syncthreads();
  }

  // ---- Phase B: scores S = q k^T * scale (registers), then store masked ----
  {
    float sacc[4][4] = {{0.f, 0.f, 0.f, 0.f}, {0.f, 0.f, 0.f, 0.f},
                        {0.f, 0.f, 0.f, 0.f}, {0.f, 0.f, 0.f, 0.f}};
#pragma unroll
    for (int kk = 0; kk < 64; ++kk) {
      float a[4], b[4];
#pragma unroll
      for (int i = 0; i < 4; ++i) a[i] = qs[tr * 4 + i][kk];
#pragma unroll
      for (int j = 0; j < 4; ++j) b[j] = ks[tc * 4 + j][kk];
#pragma unroll
      for (int i = 0; i < 4; ++i)
#pragma unroll
        for (int j = 0; j < 4; ++j) sacc[i][j] = fmaf(a[i], b[j], sacc[i][j]);
    }
    __syncthreads();  // everyone done reading qs; safe to overwrite as Ss
#pragma unroll
    for (int i = 0; i < 4; ++i)
#pragma unroll
      for (int j = 0; j < 4; ++j) {
        int n = tr * 4 + i, m2 = tc * 4 + j;
        Ss[n * 65 + m2] = (m2 <= n) ? sacc[i][j] * SCALE : -1e30f;
      }
    __syncthreads();
  }

  // ---- Phase C: causal softmax, one wave per row ----
  {
    const int wave = tid >> 6, lane = tid & 63;
    for (int n = wave; n < 64; n += 4) {
      float v = Ss[n * 65 + lane];
      float mx = v;
#pragma unroll
      for (int off = 1; off < 64; off <<= 1) mx = fmaxf(mx, __shfl_xor(mx, off));
      float p = (lane <= n) ? expf(v - mx) : 0.f;
      float sum = p;
#pragma unroll
      for (int off = 1; off < 64; off <<= 1) sum += __shfl_xor(sum, off);
      Ss[n * 65 + lane] = p / sum;
    }
    __syncthreads();
  }

  // ---- Phase D: y = S @ v -> global head slice ----
  {
    float acc[4][4] = {{0.f, 0.f, 0.f, 0.f}, {0.f, 0.f, 0.f, 0.f},
                       {0.f, 0.f, 0.f, 0.f}, {0.f, 0.f, 0.f, 0.f}};
#pragma unroll
    for (int kk = 0; kk < 64; ++kk) {
      float a[4], b[4];
#pragma unroll
      for (int i = 0; i < 4; ++i) a[i] = Ss[(tr * 4 + i) * 65 + kk];
#pragma unroll
      for (int j = 0; j < 4; ++j) b[j] = vs[kk][tc * 4 + j];
#pragma unroll
      for (int i = 0; i < 4; ++i)
#pragma unroll
        for (int j = 0; j < 4; ++j) acc[i][j] = fmaf(a[i], b[j], acc[i][j]);
    }
#pragma unroll
    for (int i = 0; i < 4; ++i) {
      int n = tr * 4 + i;
#pragma unroll
      for (int j = 0; j < 4; ++j) {
        int d = tc * 4 + j;
        y[(size_t)(bidx * 64 + n) * D + h * 64 + d] = acc[i][j];
      }
    }
  }
}

}  // namespace

extern "C" void kernel_launch(void* const* d_in, const int* in_sizes, int n_in,
                              void* d_out, int out_size, void* d_ws, size_t ws_size,
                              hipStream_t stream) {
  const float* action  = (const float*)d_in[0];
  const float* obs_rep = (const float*)d_in[1];
  // d_in[2] obs: unused by the reference
  const float* w_ae    = (const float*)d_in[3];
  const float* ln0_g   = (const float*)d_in[4];
  const float* ln0_b   = (const float*)d_in[5];
  const float* bln_g   = (const float*)d_in[6];
  const float* bln_b   = (const float*)d_in[7];
  const float* bwq     = (const float*)d_in[8];
  const float* bwk     = (const float*)d_in[9];
  const float* bwv     = (const float*)d_in[10];
  const float* bwp     = (const float*)d_in[11];
  const float* bbq     = (const float*)d_in[12];
  const float* bbk     = (const float*)d_in[13];
  const float* bbv     = (const float*)d_in[14];
  const float* bbp     = (const float*)d_in[15];
  const float* bw1     = (const float*)d_in[16];
  const float* bb1     = (const float*)d_in[17];
  const float* bw2     = (const float*)d_in[18];
  const float* bb2     = (const float*)d_in[19];
  const float* wh1     = (const float*)d_in[20];
  const float* bh1     = (const float*)d_in[21];
  const float* lnh_g   = (const float*)d_in[22];
  const float* lnh_b   = (const float*)d_in[23];
  const float* wh2     = (const float*)d_in[24];
  const float* bh2     = (const float*)d_in[25];

  float* x = (float*)d_ws;                 // [M, D] current residual stream
  float* t = x + (size_t)M * D;            // [M, D] scratch
  float* y = t + (size_t)M * D;            // [M, D] scratch

  const dim3 gFull(M / 64, D / 64);        // (256, 8)
  const dim3 gHead(M / 64, 1);
  const int lnGrid = M / 4;

  // Encoder: x = LN(gelu(action @ w_ae))
  gemm_kernel<true, false><<<gFull, 256, 0, stream>>>(action, w_ae, nullptr, t, 65, D);
  ln_kernel<<<lnGrid, 256, 0, stream>>>(t, nullptr, ln0_g, ln0_b, x);

  for (int i = 0; i < NBLK; ++i) {
    const float* wq0 = bwq + (size_t)(i * 2 + 0) * D * D;
    const float* wk0 = bwk + (size_t)(i * 2 + 0) * D * D;
    const float* wv0 = bwv + (size_t)(i * 2 + 0) * D * D;
    const float* wp0 = bwp + (size_t)(i * 2 + 0) * D * D;
    const float* wq1 = bwq + (size_t)(i * 2 + 1) * D * D;
    const float* wk1 = bwk + (size_t)(i * 2 + 1) * D * D;
    const float* wv1 = bwv + (size_t)(i * 2 + 1) * D * D;
    const float* wp1 = bwp + (size_t)(i * 2 + 1) * D * D;
    const float* bq0 = bbq + (size_t)(i * 2 + 0) * D;
    const float* bk0 = bbk + (size_t)(i * 2 + 0) * D;
    const float* bv0 = bbv + (size_t)(i * 2 + 0) * D;
    const float* bp0 = bbp + (size_t)(i * 2 + 0) * D;
    const float* bq1 = bbq + (size_t)(i * 2 + 1) * D;
    const float* bk1 = bbk + (size_t)(i * 2 + 1) * D;
    const float* bv1 = bbv + (size_t)(i * 2 + 1) * D;
    const float* bp1 = bbp + (size_t)(i * 2 + 1) * D;
    const float* g0 = bln_g + (size_t)(i * 3 + 0) * D;
    const float* b0 = bln_b + (size_t)(i * 3 + 0) * D;
    const float* g1 = bln_g + (size_t)(i * 3 + 1) * D;
    const float* b1 = bln_b + (size_t)(i * 3 + 1) * D;
    const float* g2 = bln_g + (size_t)(i * 3 + 2) * D;
    const float* b2 = bln_b + (size_t)(i * 3 + 2) * D;
    const float* w1i = bw1 + (size_t)i * D * D;
    const float* b1i = bb1 + (size_t)i * D;
    const float* w2i = bw2 + (size_t)i * D * D;
    const float* b2i = bb2 + (size_t)i * D;

    // Sublayer 1: masked self-attention, residual with x, LN
    attn_kernel<<<B * H, 256, 0, stream>>>(x, x, wq0, wk0, wv0, bq0, bk0, bv0, y);
    gemm_kernel<false, true><<<gFull, 256, 0, stream>>>(y, wp0, bp0, t, D, D);
    ln_kernel<<<lnGrid, 256, 0, stream>>>(t, x, g0, b0, x);

    // Sublayer 2: masked cross-attention (q = obs_rep), residual with obs_rep, LN
    attn_kernel<<<B * H, 256, 0, stream>>>(x, obs_rep, wq1, wk1, wv1, bq1, bk1, bv1, y);
    gemm_kernel<false, true><<<gFull, 256, 0, stream>>>(y, wp1, bp1, t, D, D);
    ln_kernel<<<lnGrid, 256, 0, stream>>>(t, obs_rep, g1, b1, x);

    // Sublayer 3: MLP, residual with x, LN
    gemm_kernel<true, true><<<gFull, 256, 0, stream>>>(x, w1i, b1i, t, D, D);
    gemm_kernel<false, true><<<gFull, 256, 0, stream>>>(t, w2i, b2i, y, D, D);
    ln_kernel<<<lnGrid, 256, 0, stream>>>(y, x, g2, b2, x);
  }

  // Head: logit = (LN(gelu(x @ wh1 + bh1))) @ wh2 + bh2
  gemm_kernel<true, true><<<gFull, 256, 0, stream>>>(x, wh1, bh1, t, D, D);
  ln_kernel<<<lnGrid, 256, 0, stream>>>(t, nullptr, lnh_g, lnh_b, y);
  gemm_kernel<false, true><<<gHead, 256, 0, stream>>>(y, wh2, bh2, (float*)d_out, D, 64);
}

// Round 2
// 2364.115 us; speedup vs baseline: 5.0539x; 5.0539x over previous
//
#include <hip/hip_runtime.h>
#include <hip/hip_bf16.h>
#include <math.h>

namespace {

constexpr int B  = 256;
constexpr int N  = 64;
constexpr int D  = 512;
constexpr int H  = 8;
constexpr int NBLK = 4;
constexpr int M  = B * N;          // 16384 token rows
constexpr float EPS = 1e-5f;
constexpr float SCALE = 0.125f;    // 1/sqrt(64)

typedef __attribute__((ext_vector_type(8))) short short8b;   // bf16x8 fragment (4 VGPRs)
typedef __attribute__((ext_vector_type(4))) float f32x4;     // MFMA accumulator

__device__ __forceinline__ float gelu_exact(float x) {
  return 0.5f * x * (1.0f + erff(x * 0.70710678118654752440f));
}

__device__ __forceinline__ unsigned short f2b_bits(float f) {
  __hip_bfloat16 h = __float2bfloat16(f);
  return *reinterpret_cast<unsigned short*>(&h);
}

__device__ __forceinline__ float b2f_bits(unsigned int u16) {
  union { unsigned int u; float f; } c; c.u = u16 << 16; return c.f;
}

#define GLOBAL_AS __attribute__((address_space(1)))
#define LDS_AS    __attribute__((address_space(3)))

__device__ __forceinline__ void gload_lds16(const void* g, void* l) {
  __builtin_amdgcn_global_load_lds((const GLOBAL_AS void*)g, (LDS_AS void*)l, 16, 0, 0);
}

// ---------------------------------------------------------------------------
// bf16 MFMA GEMM (m97 structure): out[M,512] = epi(A[M,512] @ Wt[512,512]^T + bias)
//   A  : [M, K=512] bf16 row-major
//   Wt : [N=512, K=512] bf16 row-major (pre-transposed weight)
// 128x128 tile, BK=32, 256 threads (4 waves, 2x2), double-buffered LDS,
// global_load_lds width 16, mfma_f32_16x16x32_bf16, 4x4 fragments per wave.
// ---------------------------------------------------------------------------
template<bool GELU, bool WF32, bool WBF16>
__global__ __launch_bounds__(256) void gemm_bf16_kernel(
    const __hip_bfloat16* __restrict__ A,
    const __hip_bfloat16* __restrict__ Wt,
    const float* __restrict__ bias,
    float* __restrict__ outF,
    __hip_bfloat16* __restrict__ outB) {
  constexpr int K = 512;
  constexpr int NSTEP = K / 32;    // 16
  __shared__ __hip_bfloat16 Als[2][128][32];
  __shared__ __hip_bfloat16 Bls[2][128][32];

  const int bm   = blockIdx.x * 128;
  const int bn   = blockIdx.y * 128;
  const int tid  = threadIdx.x;
  const int wave = tid >> 6;
  const int lane = tid & 63;
  const int wm   = (wave >> 1) * 64;   // wave's row origin within tile
  const int wn   = (wave & 1) * 64;    // wave's col origin within tile
  const int fr   = lane & 15;          // fragment row/col
  const int fg   = lane >> 4;          // k-group

  // Per-lane global staging pointers (chunk = wave*2 + {0,1}; 16 rows per chunk,
  // 4 lanes per row, 16B per lane). LDS dest is wave-uniform base + lane*16.
  const int srow = (lane >> 2);
  const int scol = (lane & 3) * 8;
  const __hip_bfloat16* gA0 = A  + (size_t)(bm + wave * 32 + srow) * K + scol;
  const __hip_bfloat16* gA1 = gA0 + 16 * K;
  const __hip_bfloat16* gB0 = Wt + (size_t)(bn + wave * 32 + srow) * K + scol;
  const __hip_bfloat16* gB1 = gB0 + 16 * K;

  f32x4 acc[4][4] = {};

  auto stage = [&](int buf, int ks) {
    const int ko = ks * 32;
    gload_lds16(gA0 + ko, &Als[buf][wave * 32][0]);
    gload_lds16(gA1 + ko, &Als[buf][wave * 32 + 16][0]);
    gload_lds16(gB0 + ko, &Bls[buf][wave * 32][0]);
    gload_lds16(gB1 + ko, &Bls[buf][wave * 32 + 16][0]);
  };

  stage(0, 0);
  int buf = 0;
  for (int ks = 0; ks < NSTEP; ++ks) {
    __syncthreads();                       // staging of `buf` complete
    if (ks + 1 < NSTEP) stage(buf ^ 1, ks + 1);
    short8b a[4], b[4];
#pragma unroll
    for (int mi = 0; mi < 4; ++mi)
      a[mi] = *reinterpret_cast<const short8b*>(&Als[buf][wm + mi * 16 + fr][fg * 8]);
#pragma unroll
    for (int ni = 0; ni < 4; ++ni)
      b[ni] = *reinterpret_cast<const short8b*>(&Bls[buf][wn + ni * 16 + fr][fg * 8]);
#pragma unroll
    for (int mi = 0; mi < 4; ++mi)
#pragma unroll
      for (int ni = 0; ni < 4; ++ni)
        acc[mi][ni] = __builtin_amdgcn_mfma_f32_16x16x32_bf16(a[mi], b[ni], acc[mi][ni], 0, 0, 0);
    buf ^= 1;
  }

  // Epilogue. C/D: col = lane&15, row = (lane>>4)*4 + reg  [guide-verified]
#pragma unroll
  for (int ni = 0; ni < 4; ++ni) {
    const int col = bn + wn + ni * 16 + fr;
    const float bv = bias[col];
#pragma unroll
    for (int mi = 0; mi < 4; ++mi) {
      const int row0 = bm + wm + mi * 16 + fg * 4;
#pragma unroll
      for (int r = 0; r < 4; ++r) {
        float v = acc[mi][ni][r] + bv;
        if (GELU) v = gelu_exact(v);
        const size_t idx = (size_t)(row0 + r) * D + col;
        if (WF32)  outF[idx] = v;
        if (WBF16) outB[idx] = __float2bfloat16(v);
      }
    }
  }
}

// ---------------------------------------------------------------------------
// Attention core: per (batch, head) block. Q,K,V precomputed bf16 [M,512].
//   S = causal_softmax(Q K^T / 8); y[b,:,h*64:+64] = S V   (bf16 out)
// ---------------------------------------------------------------------------
__global__ __launch_bounds__(256) void attn_core_kernel(
    const __hip_bfloat16* __restrict__ qg, const __hip_bfloat16* __restrict__ kg,
    const __hip_bfloat16* __restrict__ vg, __hip_bfloat16* __restrict__ yg) {
  __shared__ float Qs[64][65];
  __shared__ float Ks[64][65];
  __shared__ float Vs[64][65];
  float* Ss = &Qs[0][0];            // scores reuse Q tile after it is consumed

  const int bidx = blockIdx.x >> 3;
  const int h    = blockIdx.x & 7;
  const int tid  = threadIdx.x;
  const int tr   = tid >> 4;
  const int tc   = tid & 15;
  const size_t rbase = (size_t)bidx * 64;
  const int    col0  = h * 64;

  // Load + convert the three 64x64 bf16 tiles to fp32 LDS.
  for (int idx = tid; idx < 512; idx += 256) {
    const int row = idx >> 3, c8 = (idx & 7) * 8;
    const size_t off = (rbase + row) * D + col0 + c8;
    const uint4 pq = *reinterpret_cast<const uint4*>(qg + off);
    const uint4 pk = *reinterpret_cast<const uint4*>(kg + off);
    const uint4 pv = *reinterpret_cast<const uint4*>(vg + off);
    const unsigned int wq[4] = {pq.x, pq.y, pq.z, pq.w};
    const unsigned int wk[4] = {pk.x, pk.y, pk.z, pk.w};
    const unsigned int wv[4] = {pv.x, pv.y, pv.z, pv.w};
#pragma unroll
    for (int w = 0; w < 4; ++w) {
      Qs[row][c8 + 2 * w]     = b2f_bits(wq[w] & 0xffffu);
      Qs[row][c8 + 2 * w + 1] = b2f_bits(wq[w] >> 16);
      Ks[row][c8 + 2 * w]     = b2f_bits(wk[w] & 0xffffu);
      Ks[row][c8 + 2 * w + 1] = b2f_bits(wk[w] >> 16);
      Vs[row][c8 + 2 * w]     = b2f_bits(wv[w] & 0xffffu);
      Vs[row][c8 + 2 * w + 1] = b2f_bits(wv[w] >> 16);
    }
  }
  __syncthreads();

  // Scores S = Q K^T * scale, causal-masked.
  {
    float sacc[4][4] = {};
#pragma unroll
    for (int kk = 0; kk < 64; ++kk) {
      float a[4], b[4];
#pragma unroll
      for (int i = 0; i < 4; ++i) a[i] = Qs[tr * 4 + i][kk];
#pragma unroll
      for (int j = 0; j < 4; ++j) b[j] = Ks[tc * 4 + j][kk];
#pragma unroll
      for (int i = 0; i < 4; ++i)
#pragma unroll
        for (int j = 0; j < 4; ++j) sacc[i][j] = fmaf(a[i], b[j], sacc[i][j]);
    }
    __syncthreads();               // done reading Qs; safe to overwrite as Ss
#pragma unroll
    for (int i = 0; i < 4; ++i)
#pragma unroll
      for (int j = 0; j < 4; ++j) {
        const int n = tr * 4 + i, m2 = tc * 4 + j;
        Ss[n * 65 + m2] = (m2 <= n) ? sacc[i][j] * SCALE : -1e30f;
      }
    __syncthreads();
  }

  // Causal softmax: one wave per row.
  {
    const int wave = tid >> 6, lane = tid & 63;
    for (int n = wave; n < 64; n += 4) {
      float v = Ss[n * 65 + lane];
      float mx = v;
#pragma unroll
      for (int off = 1; off < 64; off <<= 1) mx = fmaxf(mx, __shfl_xor(mx, off));
      float p = (lane <= n) ? expf(v - mx) : 0.f;
      float sum = p;
#pragma unroll
      for (int off = 1; off < 64; off <<= 1) sum += __shfl_xor(sum, off);
      Ss[n * 65 + lane] = p / sum;
    }
    __syncthreads();
  }

  // y = S @ V -> bf16 head slice.
  {
    float acc[4][4] = {};
#pragma unroll
    for (int kk = 0; kk < 64; ++kk) {
      float a[4], b[4];
#pragma unroll
      for (int i = 0; i < 4; ++i) a[i] = Ss[(tr * 4 + i) * 65 + kk];
#pragma unroll
      for (int j = 0; j < 4; ++j) b[j] = Vs[kk][tc * 4 + j];
#pragma unroll
      for (int i = 0; i < 4; ++i)
#pragma unroll
        for (int j = 0; j < 4; ++j) acc[i][j] = fmaf(a[i], b[j], acc[i][j]);
    }
#pragma unroll
    for (int i = 0; i < 4; ++i) {
      const int n = tr * 4 + i;
      ushort4 o;
      o.x = f2b_bits(acc[i][0]); o.y = f2b_bits(acc[i][1]);
      o.z = f2b_bits(acc[i][2]); o.w = f2b_bits(acc[i][3]);
      *reinterpret_cast<ushort4*>(yg + (rbase + n) * D + col0 + tc * 4) = o;
    }
  }
}

// ---------------------------------------------------------------------------
// fp32 tiled GEMM (encoder K=65 and final head Nn=64 only).
// ---------------------------------------------------------------------------
template<bool GELU, bool BIAS>
__global__ __launch_bounds__(256) void gemm_f32_kernel(
    const float* __restrict__ A, const float* __restrict__ W,
    const float* __restrict__ bias, float* __restrict__ out,
    int K, int Nn) {
  __shared__ float As[64][33];
  __shared__ float Bs[32][65];
  const int bm = blockIdx.x * 64;
  const int bn = blockIdx.y * 64;
  const int tid = threadIdx.x;
  const int tr = tid >> 4;
  const int tc = tid & 15;

  float acc[4][4] = {};
  for (int k0 = 0; k0 < K; k0 += 32) {
    for (int i = tid; i < 64 * 32; i += 256) {
      int r = i >> 5, c = i & 31;
      int gk = k0 + c;
      As[r][c] = (gk < K) ? A[(size_t)(bm + r) * K + gk] : 0.f;
    }
    for (int i = tid; i < 32 * 64; i += 256) {
      int r = i >> 6, c = i & 63;
      int gk = k0 + r;
      Bs[r][c] = (gk < K) ? W[(size_t)gk * Nn + bn + c] : 0.f;
    }
    __syncthreads();
#pragma unroll
    for (int kk = 0; kk < 32; ++kk) {
      float a[4], b[4];
#pragma unroll
      for (int i = 0; i < 4; ++i) a[i] = As[tr * 4 + i][kk];
#pragma unroll
      for (int j = 0; j < 4; ++j) b[j] = Bs[kk][tc * 4 + j];
#pragma unroll
      for (int i = 0; i < 4; ++i)
#pragma unroll
        for (int j = 0; j < 4; ++j) acc[i][j] = fmaf(a[i], b[j], acc[i][j]);
    }
    __syncthreads();
  }
#pragma unroll
  for (int i = 0; i < 4; ++i) {
    int r = bm + tr * 4 + i;
#pragma unroll
    for (int j = 0; j < 4; ++j) {
      int c = bn + tc * 4 + j;
      float v = acc[i][j];
      if (BIAS) v += bias[c];
      if (GELU) v = gelu_exact(v);
      out[(size_t)r * Nn + c] = v;
    }
  }
}

// ---------------------------------------------------------------------------
// LayerNorm over D=512 with optional residual; fp32 out + optional bf16 copy.
// ---------------------------------------------------------------------------
__global__ __launch_bounds__(256) void ln_kernel(
    const float* __restrict__ xin, const float* __restrict__ res,
    const float* __restrict__ g, const float* __restrict__ b,
    float* __restrict__ out, __hip_bfloat16* __restrict__ outb) {
  const int row  = blockIdx.x * 4 + (threadIdx.x >> 6);
  const int lane = threadIdx.x & 63;
  const float* xr = xin + (size_t)row * D;

  float vals[8];
  float s = 0.f;
#pragma unroll
  for (int i = 0; i < 8; ++i) {
    float v = xr[i * 64 + lane];
    if (res) v += res[(size_t)row * D + i * 64 + lane];
    vals[i] = v;
    s += v;
  }
#pragma unroll
  for (int off = 1; off < 64; off <<= 1) s += __shfl_xor(s, off);
  const float mu = s * (1.f / D);

  float s2 = 0.f;
#pragma unroll
  for (int i = 0; i < 8; ++i) { float d = vals[i] - mu; s2 += d * d; }
#pragma unroll
  for (int off = 1; off < 64; off <<= 1) s2 += __shfl_xor(s2, off);
  const float rstd = rsqrtf(s2 * (1.f / D) + EPS);

#pragma unroll
  for (int i = 0; i < 8; ++i) {
    int c = i * 64 + lane;
    float o = (vals[i] - mu) * rstd * g[c] + b[c];
    out[(size_t)row * D + c] = o;
    if (outb) outb[(size_t)row * D + c] = __float2bfloat16(o);
  }
}

// ---------------------------------------------------------------------------
// Weight transpose+convert: src fp32 [nmat][K=512][N=512] -> dst bf16 [nmat][N][K]
// ---------------------------------------------------------------------------
__global__ __launch_bounds__(256) void wconv_kernel(
    const float* __restrict__ src, __hip_bfloat16* __restrict__ dst) {
  __shared__ float tile[32][33];
  const int mat = blockIdx.z;
  const float* s = src + (size_t)mat * D * D;
  __hip_bfloat16* d = dst + (size_t)mat * D * D;
  const int r0 = blockIdx.y * 32, c0 = blockIdx.x * 32;
  const int tr = threadIdx.x >> 5;   // 0..7
  const int tc = threadIdx.x & 31;
#pragma unroll
  for (int i = 0; i < 4; ++i)
    tile[tr + 8 * i][tc] = s[(size_t)(r0 + tr + 8 * i) * D + c0 + tc];
  __syncthreads();
#pragma unroll
  for (int i = 0; i < 4; ++i)
    d[(size_t)(c0 + tr + 8 * i) * D + r0 + tc] = __float2bfloat16(tile[tc][tr + 8 * i]);
}

// obs_rep fp32 -> bf16 copy
__global__ __launch_bounds__(256) void cvt_kernel(
    const float* __restrict__ src, __hip_bfloat16* __restrict__ dst, int n4) {
  const int i = blockIdx.x * 256 + threadIdx.x;
  if (i < n4) {
    const float4 v = reinterpret_cast<const float4*>(src)[i];
    ushort4 o;
    o.x = f2b_bits(v.x); o.y = f2b_bits(v.y);
    o.z = f2b_bits(v.z); o.w = f2b_bits(v.w);
    reinterpret_cast<ushort4*>(dst)[i] = o;
  }
}

}  // namespace

extern "C" void kernel_launch(void* const* d_in, const int* in_sizes, int n_in,
                              void* d_out, int out_size, void* d_ws, size_t ws_size,
                              hipStream_t stream) {
  const float* action  = (const float*)d_in[0];
  const float* obs_rep = (const float*)d_in[1];
  const float* w_ae    = (const float*)d_in[3];
  const float* ln0_g   = (const float*)d_in[4];
  const float* ln0_b   = (const float*)d_in[5];
  const float* bln_g   = (const float*)d_in[6];
  const float* bln_b   = (const float*)d_in[7];
  const float* bwq     = (const float*)d_in[8];
  const float* bwk     = (const float*)d_in[9];
  const float* bwv     = (const float*)d_in[10];
  const float* bwp     = (const float*)d_in[11];
  const float* bbq     = (const float*)d_in[12];
  const float* bbk     = (const float*)d_in[13];
  const float* bbv     = (const float*)d_in[14];
  const float* bbp     = (const float*)d_in[15];
  const float* bw1     = (const float*)d_in[16];
  const float* bb1     = (const float*)d_in[17];
  const float* bw2     = (const float*)d_in[18];
  const float* bb2     = (const float*)d_in[19];
  const float* wh1     = (const float*)d_in[20];
  const float* bh1     = (const float*)d_in[21];
  const float* lnh_g   = (const float*)d_in[22];
  const float* lnh_b   = (const float*)d_in[23];
  const float* wh2     = (const float*)d_in[24];
  const float* bh2     = (const float*)d_in[25];

  char* ws = (char*)d_ws;
  const size_t szF = (size_t)M * D * 4;    // 32 MB
  const size_t szB = (size_t)M * D * 2;    // 16 MB
  float* x  = (float*)ws;                 ws += szF;
  float* t  = (float*)ws;                 ws += szF;
  __hip_bfloat16* xb  = (__hip_bfloat16*)ws; ws += szB;
  __hip_bfloat16* hb  = (__hip_bfloat16*)ws; ws += szB;   // attn-out / MLP mid
  __hip_bfloat16* qb  = (__hip_bfloat16*)ws; ws += szB;
  __hip_bfloat16* kb  = (__hip_bfloat16*)ws; ws += szB;
  __hip_bfloat16* vb  = (__hip_bfloat16*)ws; ws += szB;
  __hip_bfloat16* orb = (__hip_bfloat16*)ws; ws += szB;
  __hip_bfloat16* wT  = (__hip_bfloat16*)ws;               // 41 * 512*512 bf16

  const size_t MAT = (size_t)D * D;        // 262144
  // wT layout: q:0-7, k:8-15, v:16-23, p:24-31, w1:32-35, w2:36-39, wh1:40
  wconv_kernel<<<dim3(16, 16, 8), 256, 0, stream>>>(bwq, wT + 0  * MAT);
  wconv_kernel<<<dim3(16, 16, 8), 256, 0, stream>>>(bwk, wT + 8  * MAT);
  wconv_kernel<<<dim3(16, 16, 8), 256, 0, stream>>>(bwv, wT + 16 * MAT);
  wconv_kernel<<<dim3(16, 16, 8), 256, 0, stream>>>(bwp, wT + 24 * MAT);
  wconv_kernel<<<dim3(16, 16, 4), 256, 0, stream>>>(bw1, wT + 32 * MAT);
  wconv_kernel<<<dim3(16, 16, 4), 256, 0, stream>>>(bw2, wT + 36 * MAT);
  wconv_kernel<<<dim3(16, 16, 1), 256, 0, stream>>>(wh1, wT + 40 * MAT);
  cvt_kernel<<<(M * D / 4 + 255) / 256, 256, 0, stream>>>(obs_rep, orb, M * D / 4);

  const dim3 gB(M / 128, D / 128);         // (128, 4) for bf16 GEMMs
  const int lnGrid = M / 4;

  // Encoder: x = LN(gelu(action @ w_ae))
  gemm_f32_kernel<true, false><<<dim3(M / 64, D / 64), 256, 0, stream>>>(
      action, w_ae, nullptr, t, 65, D);
  ln_kernel<<<lnGrid, 256, 0, stream>>>(t, nullptr, ln0_g, ln0_b, x, xb);

  for (int i = 0; i < NBLK; ++i) {
    const __hip_bfloat16* wq0 = wT + (0  + i * 2 + 0) * MAT;
    const __hip_bfloat16* wk0 = wT + (8  + i * 2 + 0) * MAT;
    const __hip_bfloat16* wv0 = wT + (16 + i * 2 + 0) * MAT;
    const __hip_bfloat16* wp0 = wT + (24 + i * 2 + 0) * MAT;
    const __hip_bfloat16* wq1 = wT + (0  + i * 2 + 1) * MAT;
    const __hip_bfloat16* wk1 = wT + (8  + i * 2 + 1) * MAT;
    const __hip_bfloat16* wv1 = wT + (16 + i * 2 + 1) * MAT;
    const __hip_bfloat16* wp1 = wT + (24 + i * 2 + 1) * MAT;
    const __hip_bfloat16* w1i = wT + (32 + i) * MAT;
    const __hip_bfloat16* w2i = wT + (36 + i) * MAT;
    const float* bq0 = bbq + (size_t)(i * 2 + 0) * D;
    const float* bk0 = bbk + (size_t)(i * 2 + 0) * D;
    const float* bv0 = bbv + (size_t)(i * 2 + 0) * D;
    const float* bp0 = bbp + (size_t)(i * 2 + 0) * D;
    const float* bq1 = bbq + (size_t)(i * 2 + 1) * D;
    const float* bk1 = bbk + (size_t)(i * 2 + 1) * D;
    const float* bv1 = bbv + (size_t)(i * 2 + 1) * D;
    const float* bp1 = bbp + (size_t)(i * 2 + 1) * D;
    const float* g0 = bln_g + (size_t)(i * 3 + 0) * D;
    const float* b0 = bln_b + (size_t)(i * 3 + 0) * D;
    const float* g1 = bln_g + (size_t)(i * 3 + 1) * D;
    const float* b1 = bln_b + (size_t)(i * 3 + 1) * D;
    const float* g2 = bln_g + (size_t)(i * 3 + 2) * D;
    const float* b2 = bln_b + (size_t)(i * 3 + 2) * D;
    const float* b1i = bb1 + (size_t)i * D;
    const float* b2i = bb2 + (size_t)i * D;

    // Sublayer 1: self-attention
    gemm_bf16_kernel<false, false, true><<<gB, 256, 0, stream>>>(xb, wq0, bq0, nullptr, qb);
    gemm_bf16_kernel<false, false, true><<<gB, 256, 0, stream>>>(xb, wk0, bk0, nullptr, kb);
    gemm_bf16_kernel<false, false, true><<<gB, 256, 0, stream>>>(xb, wv0, bv0, nullptr, vb);
    attn_core_kernel<<<B * H, 256, 0, stream>>>(qb, kb, vb, hb);
    gemm_bf16_kernel<false, true, false><<<gB, 256, 0, stream>>>(hb, wp0, bp0, t, nullptr);
    ln_kernel<<<lnGrid, 256, 0, stream>>>(t, x, g0, b0, x, xb);

    // Sublayer 2: cross-attention (q from obs_rep)
    gemm_bf16_kernel<false, false, true><<<gB, 256, 0, stream>>>(orb, wq1, bq1, nullptr, qb);
    gemm_bf16_kernel<false, false, true><<<gB, 256, 0, stream>>>(xb, wk1, bk1, nullptr, kb);
    gemm_bf16_kernel<false, false, true><<<gB, 256, 0, stream>>>(xb, wv1, bv1, nullptr, vb);
    attn_core_kernel<<<B * H, 256, 0, stream>>>(qb, kb, vb, hb);
    gemm_bf16_kernel<false, true, false><<<gB, 256, 0, stream>>>(hb, wp1, bp1, t, nullptr);
    ln_kernel<<<lnGrid, 256, 0, stream>>>(t, obs_rep, g1, b1, x, xb);

    // Sublayer 3: MLP
    gemm_bf16_kernel<true, false, true><<<gB, 256, 0, stream>>>(xb, w1i, b1i, nullptr, hb);
    gemm_bf16_kernel<false, true, false><<<gB, 256, 0, stream>>>(hb, w2i, b2i, t, nullptr);
    ln_kernel<<<lnGrid, 256, 0, stream>>>(t, x, g2, b2, x, xb);
  }

  // Head: logit = LN(gelu(x @ wh1 + bh1)) @ wh2 + bh2
  gemm_bf16_kernel<true, true, false><<<gB, 256, 0, stream>>>(xb, wT + 40 * MAT, bh1, t, nullptr);
  ln_kernel<<<lnGrid, 256, 0, stream>>>(t, nullptr, lnh_g, lnh_b, x, nullptr);
  gemm_f32_kernel<false, true><<<dim3(M / 64, 1), 256, 0, stream>>>(
      x, wh2, bh2, (float*)d_out, D, 64);
}

// Round 3
// 1390.030 us; speedup vs baseline: 8.5955x; 1.7008x over previous
//
#include <hip/hip_runtime.h>
#include <hip/hip_bf16.h>
#include <math.h>

namespace {

constexpr int B  = 256;
constexpr int N  = 64;
constexpr int D  = 512;
constexpr int H  = 8;
constexpr int NBLK = 4;
constexpr int M  = B * N;          // 16384 token rows
constexpr float EPS = 1e-5f;
constexpr float SCALE = 0.125f;    // 1/sqrt(64)

typedef __attribute__((ext_vector_type(8))) short short8b;   // bf16x8 fragment
typedef __attribute__((ext_vector_type(4))) float f32x4;     // MFMA accumulator

__device__ __forceinline__ float gelu_exact(float x) {
  return 0.5f * x * (1.0f + erff(x * 0.70710678118654752440f));
}

__device__ __forceinline__ unsigned short f2b_bits(float f) {
  __hip_bfloat16 h = __float2bfloat16(f);
  return *reinterpret_cast<unsigned short*>(&h);
}

#define GLOBAL_AS __attribute__((address_space(1)))
#define LDS_AS    __attribute__((address_space(3)))

__device__ __forceinline__ void gload_lds16(const void* g, void* l) {
  __builtin_amdgcn_global_load_lds((const GLOBAL_AS void*)g, (LDS_AS void*)l, 16, 0, 0);
}

// ---------------------------------------------------------------------------
// bf16 MFMA GEMM (m97 structure), K = KSTEPS*32.
//   A  : [M, K] bf16 row-major
//   Wt : [Ncols, K] bf16 row-major (pre-transposed weight)
// MODE 0: f32 out [row*ostride+col], cols < nvalid only
// MODE 1: bf16 out [row*ostride+col]
// MODE 2: bf16 out transposed per head: vt[(b*8+h)*4096 + (col&63)*64 + (tok&63)]
// ---------------------------------------------------------------------------
template<int KSTEPS, bool GELU, int MODE>
__global__ __launch_bounds__(256) void gemm_bf16_kernel(
    const __hip_bfloat16* __restrict__ A,
    const __hip_bfloat16* __restrict__ Wt,
    const float* __restrict__ bias,
    void* __restrict__ out, int ostride, int nvalid) {
  constexpr int K = KSTEPS * 32;
  __shared__ __hip_bfloat16 Als[2][128][32];
  __shared__ __hip_bfloat16 Bls[2][128][32];

  const int bm   = blockIdx.x * 128;
  const int bn   = blockIdx.y * 128;
  const int tid  = threadIdx.x;
  const int wave = tid >> 6;
  const int lane = tid & 63;
  const int wm   = (wave >> 1) * 64;
  const int wn   = (wave & 1) * 64;
  const int fr   = lane & 15;
  const int fg   = lane >> 4;

  const int srow = (lane >> 2);
  const int scol = (lane & 3) * 8;
  const __hip_bfloat16* gA0 = A  + (size_t)(bm + wave * 32 + srow) * K + scol;
  const __hip_bfloat16* gA1 = gA0 + 16 * K;
  const __hip_bfloat16* gB0 = Wt + (size_t)(bn + wave * 32 + srow) * K + scol;
  const __hip_bfloat16* gB1 = gB0 + 16 * K;

  f32x4 acc[4][4] = {};

  auto stage = [&](int buf, int ks) {
    const int ko = ks * 32;
    gload_lds16(gA0 + ko, &Als[buf][wave * 32][0]);
    gload_lds16(gA1 + ko, &Als[buf][wave * 32 + 16][0]);
    gload_lds16(gB0 + ko, &Bls[buf][wave * 32][0]);
    gload_lds16(gB1 + ko, &Bls[buf][wave * 32 + 16][0]);
  };

  stage(0, 0);
  int buf = 0;
  for (int ks = 0; ks < KSTEPS; ++ks) {
    __syncthreads();
    if (ks + 1 < KSTEPS) stage(buf ^ 1, ks + 1);
    short8b a[4], b[4];
#pragma unroll
    for (int mi = 0; mi < 4; ++mi)
      a[mi] = *reinterpret_cast<const short8b*>(&Als[buf][wm + mi * 16 + fr][fg * 8]);
#pragma unroll
    for (int ni = 0; ni < 4; ++ni)
      b[ni] = *reinterpret_cast<const short8b*>(&Bls[buf][wn + ni * 16 + fr][fg * 8]);
#pragma unroll
    for (int mi = 0; mi < 4; ++mi)
#pragma unroll
      for (int ni = 0; ni < 4; ++ni)
        acc[mi][ni] = __builtin_amdgcn_mfma_f32_16x16x32_bf16(a[mi], b[ni], acc[mi][ni], 0, 0, 0);
    buf ^= 1;
  }

  // C/D: col = lane&15, row = (lane>>4)*4 + reg
#pragma unroll
  for (int ni = 0; ni < 4; ++ni) {
    const int col = bn + wn + ni * 16 + fr;
    const float bv = (bias && col < nvalid) ? bias[col] : 0.f;
#pragma unroll
    for (int mi = 0; mi < 4; ++mi) {
      const int row0 = bm + wm + mi * 16 + fg * 4;
      if (MODE == 2) {
        ushort4 o;
        float v0 = acc[mi][ni][0] + bv, v1 = acc[mi][ni][1] + bv;
        float v2 = acc[mi][ni][2] + bv, v3 = acc[mi][ni][3] + bv;
        o.x = f2b_bits(v0); o.y = f2b_bits(v1); o.z = f2b_bits(v2); o.w = f2b_bits(v3);
        const int b8 = row0 >> 6, nl = row0 & 63;
        const int hh = col >> 6, dl = col & 63;
        *reinterpret_cast<ushort4*>((__hip_bfloat16*)out +
            ((size_t)(b8 * 8 + hh) * 4096 + dl * 64 + nl)) = o;
      } else {
#pragma unroll
        for (int r = 0; r < 4; ++r) {
          float v = acc[mi][ni][r] + bv;
          if (GELU) v = gelu_exact(v);
          if (col < nvalid) {
            const size_t idx = (size_t)(row0 + r) * ostride + col;
            if (MODE == 0) ((float*)out)[idx] = v;
            else           ((__hip_bfloat16*)out)[idx] = __float2bfloat16(v);
          }
        }
      }
    }
  }
}

// ---------------------------------------------------------------------------
// MFMA attention core: one block per (b,h).
//   qk : [M][1024] bf16 (q cols 0-511, k cols 512-1023)
//   vt : [B*H][64][64] bf16, per-head transposed V (vt[bh][d][n])
//   yg : [M][512] bf16 attention output
// LDS tiles swizzled: byte ^= (row&7)<<4 (T2, kills 16-way conflicts).
// ---------------------------------------------------------------------------
__global__ __launch_bounds__(256) void attn_mfma_kernel(
    const __hip_bfloat16* __restrict__ qk,
    const __hip_bfloat16* __restrict__ vt,
    __hip_bfloat16* __restrict__ yg) {
  __shared__ __align__(16) char smem[33280];
  unsigned short* Qs  = (unsigned short*)smem;             // [64][64] bf16 swz
  unsigned short* Ks  = (unsigned short*)(smem + 8192);    // [64][64]
  float*          Ss  = (float*)smem;                      // [64][66] (unions Qs+Ks)
  unsigned short* Vts = (unsigned short*)(smem + 16896);   // [64][64]
  unsigned short* Ps  = (unsigned short*)(smem + 25088);   // [64][64]

  const int tid  = threadIdx.x;
  const int bh   = blockIdx.x;
  const int bidx = bh >> 3, h = bh & 7;
  const size_t rbase = (size_t)bidx * 64;
  const int col0 = h * 64;

  // Load Q,K (from qk) and pre-transposed V tiles; swizzled LDS writes.
  const __hip_bfloat16* vtg = vt + (size_t)bh * 4096;
#pragma unroll
  for (int p = 0; p < 2; ++p) {
    const int idx = tid + p * 256;        // 0..511
    const int row = idx >> 3, c8 = (idx & 7) * 8;
    const int lb  = (row * 128 + c8 * 2) ^ ((row & 7) << 4);
    const size_t goff = (rbase + row) * 1024 + c8;
    const uint4 vq = *reinterpret_cast<const uint4*>(qk + goff + col0);
    const uint4 vk = *reinterpret_cast<const uint4*>(qk + goff + 512 + col0);
    const uint4 vv = *reinterpret_cast<const uint4*>(vtg + idx * 8);
    *reinterpret_cast<uint4*>((char*)Qs  + lb) = vq;
    *reinterpret_cast<uint4*>((char*)Ks  + lb) = vk;
    *reinterpret_cast<uint4*>((char*)Vts + lb) = vv;
  }
  __syncthreads();

  const int wave = tid >> 6, lane = tid & 63;
  const int fr = lane & 15, fg = lane >> 4;
  const int wr = (wave >> 1) * 32, wc = (wave & 1) * 32;

  auto ldfrag = [&](const unsigned short* base, int row, int ks) -> short8b {
    const int byte = (row * 128 + ks * 64 + fg * 16) ^ ((row & 7) << 4);
    return *reinterpret_cast<const short8b*>((const char*)base + byte);
  };

  // QK^T: each wave computes a 32x32 quadrant.
  f32x4 acc[2][2] = {};
#pragma unroll
  for (int ks = 0; ks < 2; ++ks) {
    short8b a[2], b[2];
    a[0] = ldfrag(Qs, wr + fr, ks);
    a[1] = ldfrag(Qs, wr + 16 + fr, ks);
    b[0] = ldfrag(Ks, wc + fr, ks);
    b[1] = ldfrag(Ks, wc + 16 + fr, ks);
#pragma unroll
    for (int mi = 0; mi < 2; ++mi)
#pragma unroll
      for (int ni = 0; ni < 2; ++ni)
        acc[mi][ni] = __builtin_amdgcn_mfma_f32_16x16x32_bf16(a[mi], b[ni], acc[mi][ni], 0, 0, 0);
  }
  __syncthreads();   // done reading Qs/Ks; Ss overwrites them

  // Masked, scaled scores -> Ss fp32.
#pragma unroll
  for (int mi = 0; mi < 2; ++mi)
#pragma unroll
    for (int ni = 0; ni < 2; ++ni) {
      const int m2 = wc + ni * 16 + fr;
#pragma unroll
      for (int r = 0; r < 4; ++r) {
        const int n = wr + mi * 16 + fg * 4 + r;
        Ss[n * 66 + m2] = (m2 <= n) ? acc[mi][ni][r] * SCALE : -1e30f;
      }
    }
  __syncthreads();

  // Causal softmax: wave w owns rows [w*16, w*16+16); write bf16 P (swizzled).
  for (int n = wave * 16; n < wave * 16 + 16; ++n) {
    const float v = Ss[n * 66 + lane];
    float mx = v;
#pragma unroll
    for (int off = 1; off < 64; off <<= 1) mx = fmaxf(mx, __shfl_xor(mx, off));
    const float p = (lane <= n) ? __expf(v - mx) : 0.f;
    float sum = p;
#pragma unroll
    for (int off = 1; off < 64; off <<= 1) sum += __shfl_xor(sum, off);
    const int byte = (n * 128 + lane * 2) ^ ((n & 7) << 4);
    *(unsigned short*)((char*)Ps + byte) = f2b_bits(p / sum);
  }
  __syncthreads();

  // PV: y[n][d] = sum_m P[n,m] * Vt[d,m].
  f32x4 acc2[2][2] = {};
#pragma unroll
  for (int ks = 0; ks < 2; ++ks) {
    short8b a[2], b[2];
    a[0] = ldfrag(Ps, wr + fr, ks);
    a[1] = ldfrag(Ps, wr + 16 + fr, ks);
    b[0] = ldfrag(Vts, wc + fr, ks);
    b[1] = ldfrag(Vts, wc + 16 + fr, ks);
#pragma unroll
    for (int mi = 0; mi < 2; ++mi)
#pragma unroll
      for (int ni = 0; ni < 2; ++ni)
        acc2[mi][ni] = __builtin_amdgcn_mfma_f32_16x16x32_bf16(a[mi], b[ni], acc2[mi][ni], 0, 0, 0);
  }
#pragma unroll
  for (int mi = 0; mi < 2; ++mi)
#pragma unroll
    for (int r = 0; r < 4; ++r) {
      const int n = wr + mi * 16 + fg * 4 + r;
      yg[(rbase + n) * 512 + col0 + wc + fr]      = __float2bfloat16(acc2[mi][0][r]);
      yg[(rbase + n) * 512 + col0 + wc + 16 + fr] = __float2bfloat16(acc2[mi][1][r]);
    }
}

// ---------------------------------------------------------------------------
// LayerNorm over D=512 with optional residual; fp32 out + optional bf16 copy.
// ---------------------------------------------------------------------------
__global__ __launch_bounds__(256) void ln_kernel(
    const float* __restrict__ xin, const float* __restrict__ res,
    const float* __restrict__ g, const float* __restrict__ b,
    float* __restrict__ out, __hip_bfloat16* __restrict__ outb) {
  const int row  = blockIdx.x * 4 + (threadIdx.x >> 6);
  const int lane = threadIdx.x & 63;
  const float* xr = xin + (size_t)row * D;

  float vals[8];
  float s = 0.f;
#pragma unroll
  for (int i = 0; i < 8; ++i) {
    float v = xr[i * 64 + lane];
    if (res) v += res[(size_t)row * D + i * 64 + lane];
    vals[i] = v;
    s += v;
  }
#pragma unroll
  for (int off = 1; off < 64; off <<= 1) s += __shfl_xor(s, off);
  const float mu = s * (1.f / D);

  float s2 = 0.f;
#pragma unroll
  for (int i = 0; i < 8; ++i) { float d = vals[i] - mu; s2 += d * d; }
#pragma unroll
  for (int off = 1; off < 64; off <<= 1) s2 += __shfl_xor(s2, off);
  const float rstd = rsqrtf(s2 * (1.f / D) + EPS);

#pragma unroll
  for (int i = 0; i < 8; ++i) {
    int c = i * 64 + lane;
    float o = (vals[i] - mu) * rstd * g[c] + b[c];
    out[(size_t)row * D + c] = o;
    if (outb) outb[(size_t)row * D + c] = __float2bfloat16(o);
  }
}

// ---------------------------------------------------------------------------
// Weight transpose+convert: src fp32 [zmat][512][512] -> dst bf16 [*][512][512]^T
// dst matrix z goes to dst + z*zstride*MAT.
// ---------------------------------------------------------------------------
__global__ __launch_bounds__(256) void wconv_kernel(
    const float* __restrict__ src, __hip_bfloat16* __restrict__ dst, int zstride) {
  __shared__ float tile[32][33];
  const int mat = blockIdx.z;
  const float* s = src + (size_t)mat * D * D;
  __hip_bfloat16* d = dst + (size_t)mat * zstride * D * D;
  const int r0 = blockIdx.y * 32, c0 = blockIdx.x * 32;
  const int tr = threadIdx.x >> 5;
  const int tc = threadIdx.x & 31;
#pragma unroll
  for (int i = 0; i < 4; ++i)
    tile[tr + 8 * i][tc] = s[(size_t)(r0 + tr + 8 * i) * D + c0 + tc];
  __syncthreads();
#pragma unroll
  for (int i = 0; i < 4; ++i)
    d[(size_t)(c0 + tr + 8 * i) * D + r0 + tc] = __float2bfloat16(tile[tc][tr + 8 * i]);
}

// fp32 -> bf16 vector copy
__global__ __launch_bounds__(256) void cvt_kernel(
    const float* __restrict__ src, __hip_bfloat16* __restrict__ dst, int n4) {
  const int i = blockIdx.x * 256 + threadIdx.x;
  if (i < n4) {
    const float4 v = reinterpret_cast<const float4*>(src)[i];
    ushort4 o;
    o.x = f2b_bits(v.x); o.y = f2b_bits(v.y);
    o.z = f2b_bits(v.z); o.w = f2b_bits(v.w);
    reinterpret_cast<ushort4*>(dst)[i] = o;
  }
}

// action [M][65] fp32 -> actb [M][96] bf16 (zero padded)
__global__ __launch_bounds__(256) void act_cvt_kernel(
    const float* __restrict__ src, __hip_bfloat16* __restrict__ dst) {
  for (int i = blockIdx.x * 256 + threadIdx.x; i < M * 96; i += gridDim.x * 256) {
    const int row = i / 96, k = i - row * 96;
    dst[i] = (k < 65) ? __float2bfloat16(src[(size_t)row * 65 + k]) : __float2bfloat16(0.f);
  }
}

// w_ae [65][512] -> waeT [512][96] bf16 padded
__global__ __launch_bounds__(256) void wae_conv_kernel(
    const float* __restrict__ src, __hip_bfloat16* __restrict__ dst) {
  for (int i = blockIdx.x * 256 + threadIdx.x; i < 512 * 96; i += gridDim.x * 256) {
    const int n = i / 96, k = i - n * 96;
    dst[i] = (k < 65) ? __float2bfloat16(src[(size_t)k * 512 + n]) : __float2bfloat16(0.f);
  }
}

// wh2 [512][64] -> wh2p [128][512] bf16 (rows 64-127 zero)
__global__ __launch_bounds__(256) void wh2_conv_kernel(
    const float* __restrict__ src, __hip_bfloat16* __restrict__ dst) {
  for (int i = blockIdx.x * 256 + threadIdx.x; i < 128 * 512; i += gridDim.x * 256) {
    const int n = i >> 9, k = i & 511;
    dst[i] = (n < 64) ? __float2bfloat16(src[(size_t)k * 64 + n]) : __float2bfloat16(0.f);
  }
}

// pack q/k biases: bqk[l][0:512] = bbq[l], bqk[l][512:1024] = bbk[l]  (l = 0..7)
__global__ __launch_bounds__(256) void bias_pack_kernel(
    const float* __restrict__ bbq, const float* __restrict__ bbk,
    float* __restrict__ bqk) {
  const int i = blockIdx.x * 256 + threadIdx.x;  // 0..8191
  if (i < 8 * 1024) {
    const int l = i >> 10, c = i & 1023;
    bqk[i] = (c < 512) ? bbq[l * 512 + c] : bbk[l * 512 + (c - 512)];
  }
}

}  // namespace

extern "C" void kernel_launch(void* const* d_in, const int* in_sizes, int n_in,
                              void* d_out, int out_size, void* d_ws, size_t ws_size,
                              hipStream_t stream) {
  const float* action  = (const float*)d_in[0];
  const float* obs_rep = (const float*)d_in[1];
  const float* w_ae    = (const float*)d_in[3];
  const float* ln0_g   = (const float*)d_in[4];
  const float* ln0_b   = (const float*)d_in[5];
  const float* bln_g   = (const float*)d_in[6];
  const float* bln_b   = (const float*)d_in[7];
  const float* bwq     = (const float*)d_in[8];
  const float* bwk     = (const float*)d_in[9];
  const float* bwv     = (const float*)d_in[10];
  const float* bwp     = (const float*)d_in[11];
  const float* bbq     = (const float*)d_in[12];
  const float* bbk     = (const float*)d_in[13];
  const float* bbv     = (const float*)d_in[14];
  const float* bbp     = (const float*)d_in[15];
  const float* bw1     = (const float*)d_in[16];
  const float* bb1     = (const float*)d_in[17];
  const float* bw2     = (const float*)d_in[18];
  const float* bb2     = (const float*)d_in[19];
  const float* wh1     = (const float*)d_in[20];
  const float* bh1     = (const float*)d_in[21];
  const float* lnh_g   = (const float*)d_in[22];
  const float* lnh_b   = (const float*)d_in[23];
  const float* wh2     = (const float*)d_in[24];
  const float* bh2     = (const float*)d_in[25];

  char* ws = (char*)d_ws;
  const size_t MAT = (size_t)D * D;
  const size_t szF = (size_t)M * D * 4;        // 32 MB
  const size_t szB = (size_t)M * D * 2;        // 16 MB

  __hip_bfloat16* qkb = (__hip_bfloat16*)ws;   // [M][1024] bf16 (32 MB)
  float* t            = (float*)ws;            // alias: f32 [M][512] pre-LN scratch
  ws += 2 * szB * 2;                           // 32 MB region
  float* x  = (float*)ws;                 ws += szF;
  __hip_bfloat16* xb  = (__hip_bfloat16*)ws; ws += szB;
  __hip_bfloat16* hb  = (__hip_bfloat16*)ws; ws += szB;
  __hip_bfloat16* vtb = (__hip_bfloat16*)ws; ws += szB;   // [B*H][64][64]
  __hip_bfloat16* orb = (__hip_bfloat16*)ws; ws += szB;
  __hip_bfloat16* actb = (__hip_bfloat16*)ws; ws += (size_t)M * 96 * 2;
  __hip_bfloat16* wTqk = (__hip_bfloat16*)ws; ws += 16 * MAT * 2;  // 8x [q^T|k^T]
  __hip_bfloat16* wTv  = (__hip_bfloat16*)ws; ws += 8 * MAT * 2;
  __hip_bfloat16* wTp  = (__hip_bfloat16*)ws; ws += 8 * MAT * 2;
  __hip_bfloat16* wTw1 = (__hip_bfloat16*)ws; ws += 4 * MAT * 2;
  __hip_bfloat16* wTw2 = (__hip_bfloat16*)ws; ws += 4 * MAT * 2;
  __hip_bfloat16* wTh1 = (__hip_bfloat16*)ws; ws += MAT * 2;
  __hip_bfloat16* wh2p = (__hip_bfloat16*)ws; ws += 128 * 512 * 2;
  __hip_bfloat16* waeT = (__hip_bfloat16*)ws; ws += 512 * 96 * 2;
  float* bqk          = (float*)ws;          ws += 8 * 1024 * 4;

  // ---- one-time prep ----
  wconv_kernel<<<dim3(16, 16, 8), 256, 0, stream>>>(bwq, wTqk, 2);        // q^T at slot 2z
  wconv_kernel<<<dim3(16, 16, 8), 256, 0, stream>>>(bwk, wTqk + MAT, 2);  // k^T at 2z+1
  wconv_kernel<<<dim3(16, 16, 8), 256, 0, stream>>>(bwv, wTv, 1);
  wconv_kernel<<<dim3(16, 16, 8), 256, 0, stream>>>(bwp, wTp, 1);
  wconv_kernel<<<dim3(16, 16, 4), 256, 0, stream>>>(bw1, wTw1, 1);
  wconv_kernel<<<dim3(16, 16, 4), 256, 0, stream>>>(bw2, wTw2, 1);
  wconv_kernel<<<dim3(16, 16, 1), 256, 0, stream>>>(wh1, wTh1, 1);
  wae_conv_kernel<<<192, 256, 0, stream>>>(w_ae, waeT);
  wh2_conv_kernel<<<256, 256, 0, stream>>>(wh2, wh2p);
  bias_pack_kernel<<<32, 256, 0, stream>>>(bbq, bbk, bqk);
  cvt_kernel<<<(M * D / 4 + 255) / 256, 256, 0, stream>>>(obs_rep, orb, M * D / 4);
  act_cvt_kernel<<<2048, 256, 0, stream>>>(action, actb);

  const dim3 gN512(M / 128, 4);
  const dim3 gN1024(M / 128, 8);
  const int lnGrid = M / 4;

  // ---- encoder: x = LN(gelu(action @ w_ae)) ----
  gemm_bf16_kernel<3, true, 0><<<gN512, 256, 0, stream>>>(
      actb, waeT, nullptr, t, D, D);
  ln_kernel<<<lnGrid, 256, 0, stream>>>(t, nullptr, ln0_g, ln0_b, x, xb);

  for (int i = 0; i < NBLK; ++i) {
    const __hip_bfloat16* qk0 = wTqk + (size_t)(i * 2 + 0) * 2 * MAT;
    const __hip_bfloat16* qk1 = wTqk + (size_t)(i * 2 + 1) * 2 * MAT;
    const __hip_bfloat16* wv0 = wTv + (size_t)(i * 2 + 0) * MAT;
    const __hip_bfloat16* wv1 = wTv + (size_t)(i * 2 + 1) * MAT;
    const __hip_bfloat16* wp0 = wTp + (size_t)(i * 2 + 0) * MAT;
    const __hip_bfloat16* wp1 = wTp + (size_t)(i * 2 + 1) * MAT;
    const __hip_bfloat16* w1i = wTw1 + (size_t)i * MAT;
    const __hip_bfloat16* w2i = wTw2 + (size_t)i * MAT;
    const float* bqk0 = bqk + (size_t)(i * 2 + 0) * 1024;
    const float* bqk1 = bqk + (size_t)(i * 2 + 1) * 1024;
    const float* bv0 = bbv + (size_t)(i * 2 + 0) * D;
    const float* bv1 = bbv + (size_t)(i * 2 + 1) * D;
    const float* bp0 = bbp + (size_t)(i * 2 + 0) * D;
    const float* bp1 = bbp + (size_t)(i * 2 + 1) * D;
    const float* g0 = bln_g + (size_t)(i * 3 + 0) * D;
    const float* b0 = bln_b + (size_t)(i * 3 + 0) * D;
    const float* g1 = bln_g + (size_t)(i * 3 + 1) * D;
    const float* b1 = bln_b + (size_t)(i * 3 + 1) * D;
    const float* g2 = bln_g + (size_t)(i * 3 + 2) * D;
    const float* b2 = bln_b + (size_t)(i * 3 + 2) * D;
    const float* b1i = bb1 + (size_t)i * D;
    const float* b2i = bb2 + (size_t)i * D;

    // ---- sublayer 1: self-attention ----
    gemm_bf16_kernel<16, false, 1><<<gN1024, 256, 0, stream>>>(
        xb, qk0, bqk0, qkb, 1024, 1024);                       // fused Q+K
    gemm_bf16_kernel<16, false, 2><<<gN512, 256, 0, stream>>>(
        xb, wv0, bv0, vtb, 0, D);                              // V (transposed store)
    attn_mfma_kernel<<<B * H, 256, 0, stream>>>(qkb, vtb, hb);
    gemm_bf16_kernel<16, false, 0><<<gN512, 256, 0, stream>>>(
        hb, wp0, bp0, t, D, D);
    ln_kernel<<<lnGrid, 256, 0, stream>>>(t, x, g0, b0, x, xb);

    // ---- sublayer 2: cross-attention (q from obs_rep) ----
    gemm_bf16_kernel<16, false, 1><<<gN512, 256, 0, stream>>>(
        orb, qk1, bqk1, qkb, 1024, D);                         // Q -> cols 0-511
    gemm_bf16_kernel<16, false, 1><<<gN512, 256, 0, stream>>>(
        xb, qk1 + MAT, bqk1 + 512, qkb + 512, 1024, D);        // K -> cols 512-1023
    gemm_bf16_kernel<16, false, 2><<<gN512, 256, 0, stream>>>(
        xb, wv1, bv1, vtb, 0, D);
    attn_mfma_kernel<<<B * H, 256, 0, stream>>>(qkb, vtb, hb);
    gemm_bf16_kernel<16, false, 0><<<gN512, 256, 0, stream>>>(
        hb, wp1, bp1, t, D, D);
    ln_kernel<<<lnGrid, 256, 0, stream>>>(t, obs_rep, g1, b1, x, xb);

    // ---- sublayer 3: MLP ----
    gemm_bf16_kernel<16, true, 1><<<gN512, 256, 0, stream>>>(
        xb, w1i, b1i, hb, D, D);
    gemm_bf16_kernel<16, false, 0><<<gN512, 256, 0, stream>>>(
        hb, w2i, b2i, t, D, D);
    ln_kernel<<<lnGrid, 256, 0, stream>>>(t, x, g2, b2, x, xb);
  }

  // ---- head ----
  gemm_bf16_kernel<16, true, 0><<<gN512, 256, 0, stream>>>(
      xb, wTh1, bh1, t, D, D);
  ln_kernel<<<lnGrid, 256, 0, stream>>>(t, nullptr, lnh_g, lnh_b, x, xb);
  gemm_bf16_kernel<16, false, 0><<<dim3(M / 128, 1), 256, 0, stream>>>(
      xb, wh2p, bh2, (float*)d_out, 64, 64);
}

// Round 4
// 1253.075 us; speedup vs baseline: 9.5350x; 1.1093x over previous
//
#include <hip/hip_runtime.h>
#include <hip/hip_bf16.h>
#include <math.h>

namespace {

constexpr int B  = 256;
constexpr int N  = 64;
constexpr int D  = 512;
constexpr int H  = 8;
constexpr int NBLK = 4;
constexpr int M  = B * N;          // 16384 token rows
constexpr float EPS = 1e-5f;
constexpr float SCALE = 0.125f;    // 1/sqrt(64)
constexpr int NEVER = 1 << 20;

typedef __attribute__((ext_vector_type(8))) short short8b;
typedef __attribute__((ext_vector_type(4))) float f32x4;

__device__ __forceinline__ float gelu_exact(float x) {
  return 0.5f * x * (1.0f + erff(x * 0.70710678118654752440f));
}

__device__ __forceinline__ unsigned short f2b_bits(float f) {
  __hip_bfloat16 h = __float2bfloat16(f);
  return *reinterpret_cast<unsigned short*>(&h);
}

#define GLOBAL_AS __attribute__((address_space(1)))
#define LDS_AS    __attribute__((address_space(3)))

__device__ __forceinline__ void gload_lds16(const void* g, void* l) {
  __builtin_amdgcn_global_load_lds((const GLOBAL_AS void*)g, (LDS_AS void*)l, 16, 0, 0);
}

// ---------------------------------------------------------------------------
// Standard bf16 MFMA GEMM (m97 structure), 128x128 tile, 4 waves.
//   A  : [M, K] bf16 row-major, K = KSTEPS*32
//   Wt : [Ncols, K] bf16 row-major (pre-transposed weight)
// Epilogue: col < SPLIT -> bf16 out1[row*ostr1+col] (optionally GELU)
//           col >= SPLIT -> vt transposed per-head store (bias added)
//           F32OUT: f32 out1[row*ostr1+col] for col < nvalid
// ---------------------------------------------------------------------------
template<int KSTEPS, bool GELU, int SPLIT, bool F32OUT>
__global__ __launch_bounds__(256) void gemm_std_kernel(
    const __hip_bfloat16* __restrict__ A,
    const __hip_bfloat16* __restrict__ Wt,
    const float* __restrict__ bias,
    void* __restrict__ out1, int ostr1,
    __hip_bfloat16* __restrict__ vt, int nvalid) {
  constexpr int K = KSTEPS * 32;
  __shared__ __hip_bfloat16 Als[2][128][32];
  __shared__ __hip_bfloat16 Bls[2][128][32];

  const int bm   = blockIdx.x * 128;
  const int bn   = blockIdx.y * 128;
  const int tid  = threadIdx.x;
  const int wave = tid >> 6;
  const int lane = tid & 63;
  const int wm   = (wave >> 1) * 64;
  const int wn   = (wave & 1) * 64;
  const int fr   = lane & 15;
  const int fg   = lane >> 4;

  const int srow = (lane >> 2);
  const int scol = (lane & 3) * 8;
  const __hip_bfloat16* gA0 = A  + (size_t)(bm + wave * 32 + srow) * K + scol;
  const __hip_bfloat16* gA1 = gA0 + 16 * K;
  const __hip_bfloat16* gB0 = Wt + (size_t)(bn + wave * 32 + srow) * K + scol;
  const __hip_bfloat16* gB1 = gB0 + 16 * K;

  f32x4 acc[4][4] = {};

  auto stage = [&](int buf, int ks) {
    const int ko = ks * 32;
    gload_lds16(gA0 + ko, &Als[buf][wave * 32][0]);
    gload_lds16(gA1 + ko, &Als[buf][wave * 32 + 16][0]);
    gload_lds16(gB0 + ko, &Bls[buf][wave * 32][0]);
    gload_lds16(gB1 + ko, &Bls[buf][wave * 32 + 16][0]);
  };

  stage(0, 0);
  int buf = 0;
  for (int ks = 0; ks < KSTEPS; ++ks) {
    __syncthreads();
    if (ks + 1 < KSTEPS) stage(buf ^ 1, ks + 1);
    short8b a[4], b[4];
#pragma unroll
    for (int mi = 0; mi < 4; ++mi)
      a[mi] = *reinterpret_cast<const short8b*>(&Als[buf][wm + mi * 16 + fr][fg * 8]);
#pragma unroll
    for (int ni = 0; ni < 4; ++ni)
      b[ni] = *reinterpret_cast<const short8b*>(&Bls[buf][wn + ni * 16 + fr][fg * 8]);
#pragma unroll
    for (int mi = 0; mi < 4; ++mi)
#pragma unroll
      for (int ni = 0; ni < 4; ++ni)
        acc[mi][ni] = __builtin_amdgcn_mfma_f32_16x16x32_bf16(a[mi], b[ni], acc[mi][ni], 0, 0, 0);
    buf ^= 1;
  }

  // C/D: col = lane&15, row = (lane>>4)*4 + reg
#pragma unroll
  for (int ni = 0; ni < 4; ++ni) {
    const int col = bn + wn + ni * 16 + fr;
    float bv = 0.f;
    if (bias) bv = (F32OUT && col >= nvalid) ? 0.f : bias[col];
#pragma unroll
    for (int mi = 0; mi < 4; ++mi) {
      const int row0 = bm + wm + mi * 16 + fg * 4;
      if (!F32OUT && col >= SPLIT) {
        const int vcol = col - SPLIT;
        ushort4 o;
        o.x = f2b_bits(acc[mi][ni][0] + bv);
        o.y = f2b_bits(acc[mi][ni][1] + bv);
        o.z = f2b_bits(acc[mi][ni][2] + bv);
        o.w = f2b_bits(acc[mi][ni][3] + bv);
        const int b8 = row0 >> 6, nl = row0 & 63;
        const int hh = vcol >> 6, dl = vcol & 63;
        *reinterpret_cast<ushort4*>(vt +
            ((size_t)(b8 * 8 + hh) * 4096 + dl * 64 + nl)) = o;
      } else {
#pragma unroll
        for (int q = 0; q < 4; ++q) {
          float v = acc[mi][ni][q] + bv;
          if (GELU) v = gelu_exact(v);
          if (F32OUT) {
            if (col < nvalid)
              ((float*)out1)[(size_t)(row0 + q) * ostr1 + col] = v;
          } else {
            ((__hip_bfloat16*)out1)[(size_t)(row0 + q) * ostr1 + col] = __float2bfloat16(v);
          }
        }
      }
    }
  }
}

// ---------------------------------------------------------------------------
// Fused GEMM + bias (+GELU) + residual + LayerNorm.
// Tile: BM=64 rows x BN=512 (full width), 512 threads (8 waves), K=KSTEPS*32.
// Wave w owns cols [w*64, w*64+64). Outputs: x f32 + xb bf16.
// ---------------------------------------------------------------------------
template<int KSTEPS, bool GELU_PRE, bool RES>
__global__ __launch_bounds__(512) void gemm_ln_kernel(
    const __hip_bfloat16* __restrict__ A,
    const __hip_bfloat16* __restrict__ Wt,
    const float* __restrict__ bias,
    const float* __restrict__ res,
    const float* __restrict__ g, const float* __restrict__ bb,
    float* __restrict__ outF, __hip_bfloat16* __restrict__ outB) {
  constexpr int K = KSTEPS * 32;
  __shared__ __hip_bfloat16 Als[2][64][32];     // 8 KB
  __shared__ __hip_bfloat16 Bls[2][512][32];    // 64 KB
  __shared__ float red[64][8];
  __shared__ float mrow[64];
  __shared__ float rrow[64];

  const int bm   = blockIdx.x * 64;
  const int tid  = threadIdx.x;
  const int wave = tid >> 6;
  const int lane = tid & 63;
  const int fr   = lane & 15;
  const int fg   = lane >> 4;
  const int srow = lane >> 2;
  const int scol = (lane & 3) * 8;

  auto stage = [&](int buf, int ks) {
    const int ko = ks * 32;
    if (wave < 4)
      gload_lds16(A + (size_t)(bm + wave * 16 + srow) * K + ko + scol,
                  &Als[buf][wave * 16][0]);
#pragma unroll
    for (int c = 0; c < 4; ++c)
      gload_lds16(Wt + (size_t)(wave * 64 + c * 16 + srow) * K + ko + scol,
                  &Bls[buf][wave * 64 + c * 16][0]);
  };

  f32x4 acc[4][4] = {};
  stage(0, 0);
  int buf = 0;
  for (int ks = 0; ks < KSTEPS; ++ks) {
    __syncthreads();
    if (ks + 1 < KSTEPS) stage(buf ^ 1, ks + 1);
    short8b a[4], b[4];
#pragma unroll
    for (int mi = 0; mi < 4; ++mi)
      a[mi] = *reinterpret_cast<const short8b*>(&Als[buf][mi * 16 + fr][fg * 8]);
#pragma unroll
    for (int ni = 0; ni < 4; ++ni)
      b[ni] = *reinterpret_cast<const short8b*>(&Bls[buf][wave * 64 + ni * 16 + fr][fg * 8]);
#pragma unroll
    for (int mi = 0; mi < 4; ++mi)
#pragma unroll
      for (int ni = 0; ni < 4; ++ni)
        acc[mi][ni] = __builtin_amdgcn_mfma_f32_16x16x32_bf16(a[mi], b[ni], acc[mi][ni], 0, 0, 0);
    buf ^= 1;
  }

  // ---- epilogue: v = acc + bias (+gelu) (+res); then row-LN over 512 cols ----
  float v[4][4][4];
  float bvc[4];
#pragma unroll
  for (int ni = 0; ni < 4; ++ni)
    bvc[ni] = bias ? bias[wave * 64 + ni * 16 + fr] : 0.f;
#pragma unroll
  for (int mi = 0; mi < 4; ++mi)
#pragma unroll
    for (int q = 0; q < 4; ++q) {
      const int row = bm + mi * 16 + fg * 4 + q;
#pragma unroll
      for (int ni = 0; ni < 4; ++ni) {
        float t = acc[mi][ni][q] + bvc[ni];
        if (GELU_PRE) t = gelu_exact(t);
        if (RES) t += res[(size_t)row * D + wave * 64 + ni * 16 + fr];
        v[mi][ni][q] = t;
      }
    }

  // row sums (wave-local): reduce 4 cols/lane then 16-lane butterfly
  float ps[16];
#pragma unroll
  for (int mi = 0; mi < 4; ++mi)
#pragma unroll
    for (int q = 0; q < 4; ++q)
      ps[mi * 4 + q] = v[mi][0][q] + v[mi][1][q] + v[mi][2][q] + v[mi][3][q];
#pragma unroll
  for (int mask = 1; mask < 16; mask <<= 1)
#pragma unroll
    for (int t = 0; t < 16; ++t) ps[t] += __shfl_xor(ps[t], mask);
  if (fr == 0) {
#pragma unroll
    for (int mi = 0; mi < 4; ++mi)
#pragma unroll
      for (int q = 0; q < 4; ++q)
        red[mi * 16 + fg * 4 + q][wave] = ps[mi * 4 + q];
  }
  __syncthreads();
  if (tid < 64) {
    float s = 0.f;
#pragma unroll
    for (int w = 0; w < 8; ++w) s += red[tid][w];
    mrow[tid] = s * (1.f / 512.f);
  }
  __syncthreads();
  float mu[16];
#pragma unroll
  for (int mi = 0; mi < 4; ++mi)
#pragma unroll
    for (int q = 0; q < 4; ++q) mu[mi * 4 + q] = mrow[mi * 16 + fg * 4 + q];

  // row sum of squares
  float ps2[16];
#pragma unroll
  for (int mi = 0; mi < 4; ++mi)
#pragma unroll
    for (int q = 0; q < 4; ++q) {
      const float m = mu[mi * 4 + q];
      float s = 0.f;
#pragma unroll
      for (int ni = 0; ni < 4; ++ni) {
        const float d = v[mi][ni][q] - m;
        s += d * d;
      }
      ps2[mi * 4 + q] = s;
    }
#pragma unroll
  for (int mask = 1; mask < 16; mask <<= 1)
#pragma unroll
    for (int t = 0; t < 16; ++t) ps2[t] += __shfl_xor(ps2[t], mask);
  if (fr == 0) {
#pragma unroll
    for (int mi = 0; mi < 4; ++mi)
#pragma unroll
      for (int q = 0; q < 4; ++q)
        red[mi * 16 + fg * 4 + q][wave] = ps2[mi * 4 + q];
  }
  __syncthreads();
  if (tid < 64) {
    float s = 0.f;
#pragma unroll
    for (int w = 0; w < 8; ++w) s += red[tid][w];
    rrow[tid] = rsqrtf(s * (1.f / 512.f) + EPS);
  }
  __syncthreads();

#pragma unroll
  for (int ni = 0; ni < 4; ++ni) {
    const int col = wave * 64 + ni * 16 + fr;
    const float gc = g[col], bc = bb[col];
#pragma unroll
    for (int mi = 0; mi < 4; ++mi)
#pragma unroll
      for (int q = 0; q < 4; ++q) {
        const int lrow = mi * 16 + fg * 4 + q;
        const int row = bm + lrow;
        const float o = (v[mi][ni][q] - mu[mi * 4 + q]) * rrow[lrow] * gc + bc;
        outF[(size_t)row * D + col] = o;
        outB[(size_t)row * D + col] = __float2bfloat16(o);
      }
  }
}

// ---------------------------------------------------------------------------
// MFMA attention core: one block per (b,h); q/k pointers + row strides.
// vt: [B*H][64][64] per-head transposed V. yg: [M][512] bf16.
// ---------------------------------------------------------------------------
__global__ __launch_bounds__(256) void attn_mfma_kernel(
    const __hip_bfloat16* __restrict__ qg, int qstr,
    const __hip_bfloat16* __restrict__ kg, int kstr,
    const __hip_bfloat16* __restrict__ vt,
    __hip_bfloat16* __restrict__ yg) {
  __shared__ __align__(16) char smem[33280];
  unsigned short* Qs  = (unsigned short*)smem;             // [64][64] bf16 swz
  unsigned short* Ks  = (unsigned short*)(smem + 8192);
  float*          Ss  = (float*)smem;                      // [64][66]
  unsigned short* Vts = (unsigned short*)(smem + 16896);
  unsigned short* Ps  = (unsigned short*)(smem + 25088);

  const int tid  = threadIdx.x;
  const int bh   = blockIdx.x;
  const int bidx = bh >> 3, h = bh & 7;
  const size_t rbase = (size_t)bidx * 64;
  const int col0 = h * 64;

  const __hip_bfloat16* vtg = vt + (size_t)bh * 4096;
#pragma unroll
  for (int p = 0; p < 2; ++p) {
    const int idx = tid + p * 256;
    const int row = idx >> 3, c8 = (idx & 7) * 8;
    const int lb  = (row * 128 + c8 * 2) ^ ((row & 7) << 4);
    const uint4 vq = *reinterpret_cast<const uint4*>(qg + (rbase + row) * qstr + col0 + c8);
    const uint4 vk = *reinterpret_cast<const uint4*>(kg + (rbase + row) * kstr + col0 + c8);
    const uint4 vv = *reinterpret_cast<const uint4*>(vtg + idx * 8);
    *reinterpret_cast<uint4*>((char*)Qs  + lb) = vq;
    *reinterpret_cast<uint4*>((char*)Ks  + lb) = vk;
    *reinterpret_cast<uint4*>((char*)Vts + lb) = vv;
  }
  __syncthreads();

  const int wave = tid >> 6, lane = tid & 63;
  const int fr = lane & 15, fg = lane >> 4;
  const int wr = (wave >> 1) * 32, wc = (wave & 1) * 32;

  auto ldfrag = [&](const unsigned short* base, int row, int ks) -> short8b {
    const int byte = (row * 128 + ks * 64 + fg * 16) ^ ((row & 7) << 4);
    return *reinterpret_cast<const short8b*>((const char*)base + byte);
  };

  f32x4 acc[2][2] = {};
#pragma unroll
  for (int ks = 0; ks < 2; ++ks) {
    short8b a[2], b[2];
    a[0] = ldfrag(Qs, wr + fr, ks);
    a[1] = ldfrag(Qs, wr + 16 + fr, ks);
    b[0] = ldfrag(Ks, wc + fr, ks);
    b[1] = ldfrag(Ks, wc + 16 + fr, ks);
#pragma unroll
    for (int mi = 0; mi < 2; ++mi)
#pragma unroll
      for (int ni = 0; ni < 2; ++ni)
        acc[mi][ni] = __builtin_amdgcn_mfma_f32_16x16x32_bf16(a[mi], b[ni], acc[mi][ni], 0, 0, 0);
  }
  __syncthreads();

#pragma unroll
  for (int mi = 0; mi < 2; ++mi)
#pragma unroll
    for (int ni = 0; ni < 2; ++ni) {
      const int m2 = wc + ni * 16 + fr;
#pragma unroll
      for (int r = 0; r < 4; ++r) {
        const int n = wr + mi * 16 + fg * 4 + r;
        Ss[n * 66 + m2] = (m2 <= n) ? acc[mi][ni][r] * SCALE : -1e30f;
      }
    }
  __syncthreads();

  for (int n = wave * 16; n < wave * 16 + 16; ++n) {
    const float vv = Ss[n * 66 + lane];
    float mx = vv;
#pragma unroll
    for (int off = 1; off < 64; off <<= 1) mx = fmaxf(mx, __shfl_xor(mx, off));
    const float p = (lane <= n) ? __expf(vv - mx) : 0.f;
    float sum = p;
#pragma unroll
    for (int off = 1; off < 64; off <<= 1) sum += __shfl_xor(sum, off);
    const int byte = (n * 128 + lane * 2) ^ ((n & 7) << 4);
    *(unsigned short*)((char*)Ps + byte) = f2b_bits(p / sum);
  }
  __syncthreads();

  f32x4 acc2[2][2] = {};
#pragma unroll
  for (int ks = 0; ks < 2; ++ks) {
    short8b a[2], b[2];
    a[0] = ldfrag(Ps, wr + fr, ks);
    a[1] = ldfrag(Ps, wr + 16 + fr, ks);
    b[0] = ldfrag(Vts, wc + fr, ks);
    b[1] = ldfrag(Vts, wc + 16 + fr, ks);
#pragma unroll
    for (int mi = 0; mi < 2; ++mi)
#pragma unroll
      for (int ni = 0; ni < 2; ++ni)
        acc2[mi][ni] = __builtin_amdgcn_mfma_f32_16x16x32_bf16(a[mi], b[ni], acc2[mi][ni], 0, 0, 0);
  }
#pragma unroll
  for (int mi = 0; mi < 2; ++mi)
#pragma unroll
    for (int r = 0; r < 4; ++r) {
      const int n = wr + mi * 16 + fg * 4 + r;
      yg[(rbase + n) * 512 + col0 + wc + fr]      = __float2bfloat16(acc2[mi][0][r]);
      yg[(rbase + n) * 512 + col0 + wc + 16 + fr] = __float2bfloat16(acc2[mi][1][r]);
    }
}

// ---------------------------------------------------------------------------
// Weight transpose+convert: matrix z: src + (soff + z*sstr)*MAT (fp32 [512][512])
//   -> dst + z*dstr (bf16 [512][512] transposed)
// ---------------------------------------------------------------------------
__global__ __launch_bounds__(256) void wconv_kernel(
    const float* __restrict__ src, __hip_bfloat16* __restrict__ dst,
    int soff, int sstr, long dstr) {
  __shared__ float tile[32][33];
  const int mat = blockIdx.z;
  const float* s = src + (size_t)(soff + mat * sstr) * D * D;
  __hip_bfloat16* d = dst + (size_t)mat * dstr;
  const int r0 = blockIdx.y * 32, c0 = blockIdx.x * 32;
  const int tr = threadIdx.x >> 5;
  const int tc = threadIdx.x & 31;
#pragma unroll
  for (int i = 0; i < 4; ++i)
    tile[tr + 8 * i][tc] = s[(size_t)(r0 + tr + 8 * i) * D + c0 + tc];
  __syncthreads();
#pragma unroll
  for (int i = 0; i < 4; ++i)
    d[(size_t)(c0 + tr + 8 * i) * D + r0 + tc] = __float2bfloat16(tile[tc][tr + 8 * i]);
}

__global__ __launch_bounds__(256) void cvt_kernel(
    const float* __restrict__ src, __hip_bfloat16* __restrict__ dst, int n4) {
  const int i = blockIdx.x * 256 + threadIdx.x;
  if (i < n4) {
    const float4 v = reinterpret_cast<const float4*>(src)[i];
    ushort4 o;
    o.x = f2b_bits(v.x); o.y = f2b_bits(v.y);
    o.z = f2b_bits(v.z); o.w = f2b_bits(v.w);
    reinterpret_cast<ushort4*>(dst)[i] = o;
  }
}

__global__ __launch_bounds__(256) void act_cvt_kernel(
    const float* __restrict__ src, __hip_bfloat16* __restrict__ dst) {
  for (int i = blockIdx.x * 256 + threadIdx.x; i < M * 96; i += gridDim.x * 256) {
    const int row = i / 96, k = i - row * 96;
    dst[i] = (k < 65) ? __float2bfloat16(src[(size_t)row * 65 + k]) : __float2bfloat16(0.f);
  }
}

__global__ __launch_bounds__(256) void wae_conv_kernel(
    const float* __restrict__ src, __hip_bfloat16* __restrict__ dst) {
  for (int i = blockIdx.x * 256 + threadIdx.x; i < 512 * 96; i += gridDim.x * 256) {
    const int n = i / 96, k = i - n * 96;
    dst[i] = (k < 65) ? __float2bfloat16(src[(size_t)k * 512 + n]) : __float2bfloat16(0.f);
  }
}

__global__ __launch_bounds__(256) void wh2_conv_kernel(
    const float* __restrict__ src, __hip_bfloat16* __restrict__ dst) {
  for (int i = blockIdx.x * 256 + threadIdx.x; i < 128 * 512; i += gridDim.x * 256) {
    const int n = i >> 9, k = i & 511;
    dst[i] = (n < 64) ? __float2bfloat16(src[(size_t)k * 64 + n]) : __float2bfloat16(0.f);
  }
}

// self QKV bias: [NB][1536] = bq|bk|bv of sublayer 0
__global__ __launch_bounds__(256) void pack_selfb_kernel(
    const float* __restrict__ bq, const float* __restrict__ bk,
    const float* __restrict__ bv, float* __restrict__ dst) {
  const int i = blockIdx.x * 256 + threadIdx.x;
  if (i < NBLK * 1536) {
    const int blk = i / 1536, c = i - blk * 1536;
    const int seg = c >> 9, cc = c & 511;
    const float* s = (seg == 0) ? bq : (seg == 1) ? bk : bv;
    dst[i] = s[(size_t)(blk * 2) * 512 + cc];
  }
}

// cross KV bias: [NB][1024] = bk|bv of sublayer 1
__global__ __launch_bounds__(256) void pack_ckvb_kernel(
    const float* __restrict__ bk, const float* __restrict__ bv,
    float* __restrict__ dst) {
  const int i = blockIdx.x * 256 + threadIdx.x;
  if (i < NBLK * 1024) {
    const int blk = i >> 10, c = i & 1023;
    dst[i] = (c < 512) ? bk[(size_t)(blk * 2 + 1) * 512 + c]
                       : bv[(size_t)(blk * 2 + 1) * 512 + (c - 512)];
  }
}

}  // namespace

extern "C" void kernel_launch(void* const* d_in, const int* in_sizes, int n_in,
                              void* d_out, int out_size, void* d_ws, size_t ws_size,
                              hipStream_t stream) {
  const float* action  = (const float*)d_in[0];
  const float* obs_rep = (const float*)d_in[1];
  const float* w_ae    = (const float*)d_in[3];
  const float* ln0_g   = (const float*)d_in[4];
  const float* ln0_b   = (const float*)d_in[5];
  const float* bln_g   = (const float*)d_in[6];
  const float* bln_b   = (const float*)d_in[7];
  const float* bwq     = (const float*)d_in[8];
  const float* bwk     = (const float*)d_in[9];
  const float* bwv     = (const float*)d_in[10];
  const float* bwp     = (const float*)d_in[11];
  const float* bbq     = (const float*)d_in[12];
  const float* bbk     = (const float*)d_in[13];
  const float* bbv     = (const float*)d_in[14];
  const float* bbp     = (const float*)d_in[15];
  const float* bw1     = (const float*)d_in[16];
  const float* bb1     = (const float*)d_in[17];
  const float* bw2     = (const float*)d_in[18];
  const float* bb2     = (const float*)d_in[19];
  const float* wh1     = (const float*)d_in[20];
  const float* bh1     = (const float*)d_in[21];
  const float* lnh_g   = (const float*)d_in[22];
  const float* lnh_b   = (const float*)d_in[23];
  const float* wh2     = (const float*)d_in[24];
  const float* bh2     = (const float*)d_in[25];

  char* ws = (char*)d_ws;
  const size_t MAT = (size_t)D * D;
  const size_t szF = (size_t)M * D * 4;        // 32 MB
  const size_t szB = (size_t)M * D * 2;        // 16 MB

  float* x            = (float*)ws;          ws += szF;
  __hip_bfloat16* xb  = (__hip_bfloat16*)ws; ws += szB;
  __hip_bfloat16* hb  = (__hip_bfloat16*)ws; ws += szB;
  __hip_bfloat16* vtb = (__hip_bfloat16*)ws; ws += szB;
  __hip_bfloat16* orb = (__hip_bfloat16*)ws; ws += szB;
  __hip_bfloat16* qkb = (__hip_bfloat16*)ws; ws += 2 * szB;  // [M][1024]
  __hip_bfloat16* qcb = (__hip_bfloat16*)ws; ws += szB;      // [M][512] cross Q
  __hip_bfloat16* kb  = (__hip_bfloat16*)ws; ws += szB;      // [M][512] cross K
  __hip_bfloat16* actb = (__hip_bfloat16*)ws; ws += (size_t)M * 96 * 2;
  __hip_bfloat16* wSelf = (__hip_bfloat16*)ws; ws += (size_t)NBLK * 1536 * 512 * 2;
  __hip_bfloat16* wCq   = (__hip_bfloat16*)ws; ws += (size_t)NBLK * 512 * 512 * 2;
  __hip_bfloat16* wCkv  = (__hip_bfloat16*)ws; ws += (size_t)NBLK * 1024 * 512 * 2;
  __hip_bfloat16* wTp   = (__hip_bfloat16*)ws; ws += 8 * MAT * 2;
  __hip_bfloat16* wTw1  = (__hip_bfloat16*)ws; ws += 4 * MAT * 2;
  __hip_bfloat16* wTw2  = (__hip_bfloat16*)ws; ws += 4 * MAT * 2;
  __hip_bfloat16* wTh1  = (__hip_bfloat16*)ws; ws += MAT * 2;
  __hip_bfloat16* wh2p  = (__hip_bfloat16*)ws; ws += 128 * 512 * 2;
  __hip_bfloat16* waeT  = (__hip_bfloat16*)ws; ws += 512 * 96 * 2;
  float* selfb         = (float*)ws;         ws += (size_t)NBLK * 1536 * 4;
  float* ckvb          = (float*)ws;         ws += (size_t)NBLK * 1024 * 4;

  // ---- one-time prep ----
  const long SS = 1536 * 512;
  wconv_kernel<<<dim3(16, 16, 4), 256, 0, stream>>>(bwq, wSelf, 0, 2, SS);
  wconv_kernel<<<dim3(16, 16, 4), 256, 0, stream>>>(bwk, wSelf + 512 * 512, 0, 2, SS);
  wconv_kernel<<<dim3(16, 16, 4), 256, 0, stream>>>(bwv, wSelf + 1024 * 512, 0, 2, SS);
  wconv_kernel<<<dim3(16, 16, 4), 256, 0, stream>>>(bwq, wCq, 1, 2, (long)MAT);
  wconv_kernel<<<dim3(16, 16, 4), 256, 0, stream>>>(bwk, wCkv, 1, 2, 1024 * 512L);
  wconv_kernel<<<dim3(16, 16, 4), 256, 0, stream>>>(bwv, wCkv + 512 * 512, 1, 2, 1024 * 512L);
  wconv_kernel<<<dim3(16, 16, 8), 256, 0, stream>>>(bwp, wTp, 0, 1, (long)MAT);
  wconv_kernel<<<dim3(16, 16, 4), 256, 0, stream>>>(bw1, wTw1, 0, 1, (long)MAT);
  wconv_kernel<<<dim3(16, 16, 4), 256, 0, stream>>>(bw2, wTw2, 0, 1, (long)MAT);
  wconv_kernel<<<dim3(16, 16, 1), 256, 0, stream>>>(wh1, wTh1, 0, 1, (long)MAT);
  wae_conv_kernel<<<192, 256, 0, stream>>>(w_ae, waeT);
  wh2_conv_kernel<<<256, 256, 0, stream>>>(wh2, wh2p);
  pack_selfb_kernel<<<(NBLK * 1536 + 255) / 256, 256, 0, stream>>>(bbq, bbk, bbv, selfb);
  pack_ckvb_kernel<<<(NBLK * 1024 + 255) / 256, 256, 0, stream>>>(bbk, bbv, ckvb);
  cvt_kernel<<<(M * D / 4 + 255) / 256, 256, 0, stream>>>(obs_rep, orb, M * D / 4);
  act_cvt_kernel<<<2048, 256, 0, stream>>>(action, actb);

  const int lnGrid = M / 64;   // 256 blocks, 512 threads

  // ---- encoder: x = LN(gelu(action @ w_ae)) ----
  gemm_ln_kernel<3, true, false><<<lnGrid, 512, 0, stream>>>(
      actb, waeT, nullptr, nullptr, ln0_g, ln0_b, x, xb);

  for (int i = 0; i < NBLK; ++i) {
    const float* g0 = bln_g + (size_t)(i * 3 + 0) * D;
    const float* b0 = bln_b + (size_t)(i * 3 + 0) * D;
    const float* g1 = bln_g + (size_t)(i * 3 + 1) * D;
    const float* b1 = bln_b + (size_t)(i * 3 + 1) * D;
    const float* g2 = bln_g + (size_t)(i * 3 + 2) * D;
    const float* b2 = bln_b + (size_t)(i * 3 + 2) * D;

    // ---- sublayer 1: self-attention ----
    gemm_std_kernel<16, false, 1024, false><<<dim3(M / 128, 12), 256, 0, stream>>>(
        xb, wSelf + (size_t)i * SS, selfb + (size_t)i * 1536, qkb, 1024, vtb, D);
    attn_mfma_kernel<<<B * H, 256, 0, stream>>>(qkb, 1024, qkb + 512, 1024, vtb, hb);
    gemm_ln_kernel<16, false, true><<<lnGrid, 512, 0, stream>>>(
        hb, wTp + (size_t)(i * 2) * MAT, bbp + (size_t)(i * 2) * D, x, g0, b0, x, xb);

    // ---- sublayer 2: cross-attention ----
    gemm_std_kernel<16, false, NEVER, false><<<dim3(M / 128, 4), 256, 0, stream>>>(
        orb, wCq + (size_t)i * MAT, bbq + (size_t)(i * 2 + 1) * D, qcb, 512, nullptr, D);
    gemm_std_kernel<16, false, 512, false><<<dim3(M / 128, 8), 256, 0, stream>>>(
        xb, wCkv + (size_t)i * 1024 * 512, ckvb + (size_t)i * 1024, kb, 512, vtb, D);
    attn_mfma_kernel<<<B * H, 256, 0, stream>>>(qcb, 512, kb, 512, vtb, hb);
    gemm_ln_kernel<16, false, true><<<lnGrid, 512, 0, stream>>>(
        hb, wTp + (size_t)(i * 2 + 1) * MAT, bbp + (size_t)(i * 2 + 1) * D,
        obs_rep, g1, b1, x, xb);

    // ---- sublayer 3: MLP ----
    gemm_std_kernel<16, true, NEVER, false><<<dim3(M / 128, 4), 256, 0, stream>>>(
        xb, wTw1 + (size_t)i * MAT, bb1 + (size_t)i * D, hb, 512, nullptr, D);
    gemm_ln_kernel<16, false, true><<<lnGrid, 512, 0, stream>>>(
        hb, wTw2 + (size_t)i * MAT, bb2 + (size_t)i * D, x, g2, b2, x, xb);
  }

  // ---- head ----
  gemm_ln_kernel<16, true, false><<<lnGrid, 512, 0, stream>>>(
      xb, wTh1, bh1, nullptr, lnh_g, lnh_b, x, xb);
  gemm_std_kernel<16, false, NEVER, true><<<dim3(M / 128, 1), 256, 0, stream>>>(
      xb, wh2p, bh2, (float*)d_out, 64, nullptr, 64);
}

// Round 5
// 1138.917 us; speedup vs baseline: 10.4907x; 1.1002x over previous
//
#include <hip/hip_runtime.h>
#include <hip/hip_bf16.h>
#include <math.h>

namespace {

constexpr int B  = 256;
constexpr int N  = 64;
constexpr int D  = 512;
constexpr int H  = 8;
constexpr int NBLK = 4;
constexpr int M  = B * N;          // 16384 token rows
constexpr float EPS = 1e-5f;
constexpr float SCALE = 0.125f;    // 1/sqrt(64)
constexpr int NEVER = 1 << 20;

typedef __attribute__((ext_vector_type(8))) short short8b;
typedef __attribute__((ext_vector_type(4))) float f32x4;

__device__ __forceinline__ float gelu_exact(float x) {
  return 0.5f * x * (1.0f + erff(x * 0.70710678118654752440f));
}

__device__ __forceinline__ unsigned short f2b_bits(float f) {
  __hip_bfloat16 h = __float2bfloat16(f);
  return *reinterpret_cast<unsigned short*>(&h);
}

#define GLOBAL_AS __attribute__((address_space(1)))
#define LDS_AS    __attribute__((address_space(3)))

__device__ __forceinline__ void gload_lds16(const void* g, void* l) {
  __builtin_amdgcn_global_load_lds((const GLOBAL_AS void*)g, (LDS_AS void*)l, 16, 0, 0);
}

// ---------------------------------------------------------------------------
// Deep-pipelined bf16 MFMA GEMM (T3+T4 counted-vmcnt structure).
// Tile BM=128 x BN=256, BK=64, 512 threads (8 waves, 2M x 4N, 64x64/wave).
// 3 LDS buffers (144 KB); 1 raw s_barrier + s_waitcnt vmcnt(6) per K-tile;
// loads stay 2 tiles deep, never drained in the main loop (T4).
// LDS read swizzle: slot ^= (row&7), applied to BOTH the global staging
// source address (LDS dest linear, rule #21) and the ds_read address (T2).
// K = 512 fixed. Epilogue: col<SPLIT -> bf16 out1 (opt GELU);
// col>=SPLIT -> per-head transposed V store.
// ---------------------------------------------------------------------------
template<bool GELU, int SPLIT>
__global__ __launch_bounds__(512, 2) void gemm_dp_kernel(
    const __hip_bfloat16* __restrict__ A,
    const __hip_bfloat16* __restrict__ Wt,
    const float* __restrict__ bias,
    __hip_bfloat16* __restrict__ out1, int ostr1,
    __hip_bfloat16* __restrict__ vt, int gy) {
  constexpr int K = 512;
  constexpr int NT = 8;                      // K / 64
  __shared__ __hip_bfloat16 Als[3][128][64]; // 48 KB
  __shared__ __hip_bfloat16 Bls[3][256][64]; // 96 KB

  // Bijective XCD swizzle (nwg % 8 == 0 for all launches here).
  const int nwg = gridDim.x;
  const int hw  = blockIdx.x;
  const int cpx = nwg >> 3;
  const int lg  = (hw & 7) * cpx + (hw >> 3);
  const int bm  = (lg / gy) * 128;
  const int bn  = (lg % gy) * 256;

  const int tid  = threadIdx.x;
  const int wave = tid >> 6;
  const int lane = tid & 63;
  const int wm   = (wave >> 2) * 64;   // 0 or 64
  const int wn   = (wave & 3) * 64;    // 0,64,128,192
  const int fr   = lane & 15;
  const int fg   = lane >> 4;

  // Staging: thread -> (row = tid>>3, slot = tid&7); source col-slot is
  // inverse-swizzled so linear LDS writes yield swizzled-read content.
  const int srow  = tid >> 3;                      // 0..63
  const int sslot = (tid & 7) ^ (srow & 7);
  const __hip_bfloat16* gA = A  + (size_t)(bm + srow) * K + sslot * 8;
  const __hip_bfloat16* gB = Wt + (size_t)(bn + srow) * K + sslot * 8;

  auto STAGE = [&](int buf, int kt) {
    const int ko = kt * 64;
    char* la = (char*)&Als[buf][0][0] + wave * 1024;
    char* lb = (char*)&Bls[buf][0][0] + wave * 1024;
    gload_lds16(gA + ko,           la);
    gload_lds16(gA + 64 * K + ko,  la + 8192);
    gload_lds16(gB + ko,           lb);
    gload_lds16(gB + 64 * K + ko,  lb + 8192);
    gload_lds16(gB + 128 * K + ko, lb + 16384);
    gload_lds16(gB + 192 * K + ko, lb + 24576);
  };

  auto lda = [&](int buf, int mi, int ks) -> short8b {
    const int row  = wm + mi * 16 + fr;
    const int byte = row * 128 + (((ks << 2) | fg) ^ (fr & 7)) * 16;
    return *reinterpret_cast<const short8b*>((const char*)&Als[buf][0][0] + byte);
  };
  auto ldb = [&](int buf, int ni, int ks) -> short8b {
    const int row  = wn + ni * 16 + fr;
    const int byte = row * 128 + (((ks << 2) | fg) ^ (fr & 7)) * 16;
    return *reinterpret_cast<const short8b*>((const char*)&Bls[buf][0][0] + byte);
  };

  // Prologue: two tiles in flight; wait for tile 0 only (vmcnt(6)).
  STAGE(0, 0);
  STAGE(1, 1);
  asm volatile("s_waitcnt vmcnt(6)" ::: "memory");
  __builtin_amdgcn_sched_barrier(0);
  __builtin_amdgcn_s_barrier();
  __builtin_amdgcn_sched_barrier(0);

  f32x4 acc[4][4] = {};
  for (int t = 0; t < NT; ++t) {
    const int cur = t % 3;
    if (t + 2 < NT) STAGE((t + 2) % 3, t + 2);

    short8b a0[4], b0[4], a1[4], b1[4];
#pragma unroll
    for (int mi = 0; mi < 4; ++mi) a0[mi] = lda(cur, mi, 0);
#pragma unroll
    for (int ni = 0; ni < 4; ++ni) b0[ni] = ldb(cur, ni, 0);
#pragma unroll
    for (int mi = 0; mi < 4; ++mi) a1[mi] = lda(cur, mi, 1);
#pragma unroll
    for (int ni = 0; ni < 4; ++ni) b1[ni] = ldb(cur, ni, 1);

    __builtin_amdgcn_s_setprio(1);
#pragma unroll
    for (int mi = 0; mi < 4; ++mi)
#pragma unroll
      for (int ni = 0; ni < 4; ++ni)
        acc[mi][ni] = __builtin_amdgcn_mfma_f32_16x16x32_bf16(a0[mi], b0[ni], acc[mi][ni], 0, 0, 0);
#pragma unroll
    for (int mi = 0; mi < 4; ++mi)
#pragma unroll
      for (int ni = 0; ni < 4; ++ni)
        acc[mi][ni] = __builtin_amdgcn_mfma_f32_16x16x32_bf16(a1[mi], b1[ni], acc[mi][ni], 0, 0, 0);
    __builtin_amdgcn_s_setprio(0);

    // Counted wait: tile t+1's 6 loads done; tile t+2's 6 stay in flight.
    if (t + 2 < NT) {
      asm volatile("s_waitcnt vmcnt(6)" ::: "memory");
    } else {
      asm volatile("s_waitcnt vmcnt(0)" ::: "memory");
    }
    __builtin_amdgcn_sched_barrier(0);
    __builtin_amdgcn_s_barrier();
    __builtin_amdgcn_sched_barrier(0);
  }

  // Epilogue. C/D: col = lane&15, row = (lane>>4)*4 + reg.
#pragma unroll
  for (int ni = 0; ni < 4; ++ni) {
    const int col = bn + wn + ni * 16 + fr;
    const float bv = bias ? bias[col] : 0.f;
#pragma unroll
    for (int mi = 0; mi < 4; ++mi) {
      const int row0 = bm + wm + mi * 16 + fg * 4;
      if (col >= SPLIT) {
        const int vcol = col - SPLIT;
        ushort4 o;
        o.x = f2b_bits(acc[mi][ni][0] + bv);
        o.y = f2b_bits(acc[mi][ni][1] + bv);
        o.z = f2b_bits(acc[mi][ni][2] + bv);
        o.w = f2b_bits(acc[mi][ni][3] + bv);
        const int b8 = row0 >> 6, nl = row0 & 63;
        const int hh = vcol >> 6, dl = vcol & 63;
        *reinterpret_cast<ushort4*>(vt +
            ((size_t)(b8 * 8 + hh) * 4096 + dl * 64 + nl)) = o;
      } else {
#pragma unroll
        for (int q = 0; q < 4; ++q) {
          float v = acc[mi][ni][q] + bv;
          if (GELU) v = gelu_exact(v);
          out1[(size_t)(row0 + q) * ostr1 + col] = __float2bfloat16(v);
        }
      }
    }
  }
}

// ---------------------------------------------------------------------------
// Standard bf16 MFMA GEMM (m97 structure) — kept for the tiny head GEMM.
// ---------------------------------------------------------------------------
template<int KSTEPS, bool GELU, int SPLIT, bool F32OUT>
__global__ __launch_bounds__(256) void gemm_std_kernel(
    const __hip_bfloat16* __restrict__ A,
    const __hip_bfloat16* __restrict__ Wt,
    const float* __restrict__ bias,
    void* __restrict__ out1, int ostr1,
    __hip_bfloat16* __restrict__ vt, int nvalid) {
  constexpr int K = KSTEPS * 32;
  __shared__ __hip_bfloat16 Als[2][128][32];
  __shared__ __hip_bfloat16 Bls[2][128][32];

  const int bm   = blockIdx.x * 128;
  const int bn   = blockIdx.y * 128;
  const int tid  = threadIdx.x;
  const int wave = tid >> 6;
  const int lane = tid & 63;
  const int wm   = (wave >> 1) * 64;
  const int wn   = (wave & 1) * 64;
  const int fr   = lane & 15;
  const int fg   = lane >> 4;

  const int srow = (lane >> 2);
  const int scol = (lane & 3) * 8;
  const __hip_bfloat16* gA0 = A  + (size_t)(bm + wave * 32 + srow) * K + scol;
  const __hip_bfloat16* gA1 = gA0 + 16 * K;
  const __hip_bfloat16* gB0 = Wt + (size_t)(bn + wave * 32 + srow) * K + scol;
  const __hip_bfloat16* gB1 = gB0 + 16 * K;

  f32x4 acc[4][4] = {};

  auto stage = [&](int buf, int ks) {
    const int ko = ks * 32;
    gload_lds16(gA0 + ko, &Als[buf][wave * 32][0]);
    gload_lds16(gA1 + ko, &Als[buf][wave * 32 + 16][0]);
    gload_lds16(gB0 + ko, &Bls[buf][wave * 32][0]);
    gload_lds16(gB1 + ko, &Bls[buf][wave * 32 + 16][0]);
  };

  stage(0, 0);
  int buf = 0;
  for (int ks = 0; ks < KSTEPS; ++ks) {
    __syncthreads();
    if (ks + 1 < KSTEPS) stage(buf ^ 1, ks + 1);
    short8b a[4], b[4];
#pragma unroll
    for (int mi = 0; mi < 4; ++mi)
      a[mi] = *reinterpret_cast<const short8b*>(&Als[buf][wm + mi * 16 + fr][fg * 8]);
#pragma unroll
    for (int ni = 0; ni < 4; ++ni)
      b[ni] = *reinterpret_cast<const short8b*>(&Bls[buf][wn + ni * 16 + fr][fg * 8]);
#pragma unroll
    for (int mi = 0; mi < 4; ++mi)
#pragma unroll
      for (int ni = 0; ni < 4; ++ni)
        acc[mi][ni] = __builtin_amdgcn_mfma_f32_16x16x32_bf16(a[mi], b[ni], acc[mi][ni], 0, 0, 0);
    buf ^= 1;
  }

#pragma unroll
  for (int ni = 0; ni < 4; ++ni) {
    const int col = bn + wn + ni * 16 + fr;
    float bv = 0.f;
    if (bias) bv = (F32OUT && col >= nvalid) ? 0.f : bias[col];
#pragma unroll
    for (int mi = 0; mi < 4; ++mi) {
      const int row0 = bm + wm + mi * 16 + fg * 4;
      if (!F32OUT && col >= SPLIT) {
        const int vcol = col - SPLIT;
        ushort4 o;
        o.x = f2b_bits(acc[mi][ni][0] + bv);
        o.y = f2b_bits(acc[mi][ni][1] + bv);
        o.z = f2b_bits(acc[mi][ni][2] + bv);
        o.w = f2b_bits(acc[mi][ni][3] + bv);
        const int b8 = row0 >> 6, nl = row0 & 63;
        const int hh = vcol >> 6, dl = vcol & 63;
        *reinterpret_cast<ushort4*>(vt +
            ((size_t)(b8 * 8 + hh) * 4096 + dl * 64 + nl)) = o;
      } else {
#pragma unroll
        for (int q = 0; q < 4; ++q) {
          float v = acc[mi][ni][q] + bv;
          if (GELU) v = gelu_exact(v);
          if (F32OUT) {
            if (col < nvalid)
              ((float*)out1)[(size_t)(row0 + q) * ostr1 + col] = v;
          } else {
            ((__hip_bfloat16*)out1)[(size_t)(row0 + q) * ostr1 + col] = __float2bfloat16(v);
          }
        }
      }
    }
  }
}

// ---------------------------------------------------------------------------
// Fused GEMM + bias (+GELU) + residual + LayerNorm (BM=64 x full 512 width).
// ---------------------------------------------------------------------------
template<int KSTEPS, bool GELU_PRE, bool RES>
__global__ __launch_bounds__(512) void gemm_ln_kernel(
    const __hip_bfloat16* __restrict__ A,
    const __hip_bfloat16* __restrict__ Wt,
    const float* __restrict__ bias,
    const float* __restrict__ res,
    const float* __restrict__ g, const float* __restrict__ bb,
    float* __restrict__ outF, __hip_bfloat16* __restrict__ outB) {
  constexpr int K = KSTEPS * 32;
  __shared__ __hip_bfloat16 Als[2][64][32];
  __shared__ __hip_bfloat16 Bls[2][512][32];
  __shared__ float red[64][8];
  __shared__ float mrow[64];
  __shared__ float rrow[64];

  const int bm   = blockIdx.x * 64;
  const int tid  = threadIdx.x;
  const int wave = tid >> 6;
  const int lane = tid & 63;
  const int fr   = lane & 15;
  const int fg   = lane >> 4;
  const int srow = lane >> 2;
  const int scol = (lane & 3) * 8;

  auto stage = [&](int buf, int ks) {
    const int ko = ks * 32;
    if (wave < 4)
      gload_lds16(A + (size_t)(bm + wave * 16 + srow) * K + ko + scol,
                  &Als[buf][wave * 16][0]);
#pragma unroll
    for (int c = 0; c < 4; ++c)
      gload_lds16(Wt + (size_t)(wave * 64 + c * 16 + srow) * K + ko + scol,
                  &Bls[buf][wave * 64 + c * 16][0]);
  };

  f32x4 acc[4][4] = {};
  stage(0, 0);
  int buf = 0;
  for (int ks = 0; ks < KSTEPS; ++ks) {
    __syncthreads();
    if (ks + 1 < KSTEPS) stage(buf ^ 1, ks + 1);
    short8b a[4], b[4];
#pragma unroll
    for (int mi = 0; mi < 4; ++mi)
      a[mi] = *reinterpret_cast<const short8b*>(&Als[buf][mi * 16 + fr][fg * 8]);
#pragma unroll
    for (int ni = 0; ni < 4; ++ni)
      b[ni] = *reinterpret_cast<const short8b*>(&Bls[buf][wave * 64 + ni * 16 + fr][fg * 8]);
#pragma unroll
    for (int mi = 0; mi < 4; ++mi)
#pragma unroll
      for (int ni = 0; ni < 4; ++ni)
        acc[mi][ni] = __builtin_amdgcn_mfma_f32_16x16x32_bf16(a[mi], b[ni], acc[mi][ni], 0, 0, 0);
    buf ^= 1;
  }

  float v[4][4][4];
  float bvc[4];
#pragma unroll
  for (int ni = 0; ni < 4; ++ni)
    bvc[ni] = bias ? bias[wave * 64 + ni * 16 + fr] : 0.f;
#pragma unroll
  for (int mi = 0; mi < 4; ++mi)
#pragma unroll
    for (int q = 0; q < 4; ++q) {
      const int row = bm + mi * 16 + fg * 4 + q;
#pragma unroll
      for (int ni = 0; ni < 4; ++ni) {
        float t = acc[mi][ni][q] + bvc[ni];
        if (GELU_PRE) t = gelu_exact(t);
        if (RES) t += res[(size_t)row * D + wave * 64 + ni * 16 + fr];
        v[mi][ni][q] = t;
      }
    }

  float ps[16];
#pragma unroll
  for (int mi = 0; mi < 4; ++mi)
#pragma unroll
    for (int q = 0; q < 4; ++q)
      ps[mi * 4 + q] = v[mi][0][q] + v[mi][1][q] + v[mi][2][q] + v[mi][3][q];
#pragma unroll
  for (int mask = 1; mask < 16; mask <<= 1)
#pragma unroll
    for (int t = 0; t < 16; ++t) ps[t] += __shfl_xor(ps[t], mask);
  if (fr == 0) {
#pragma unroll
    for (int mi = 0; mi < 4; ++mi)
#pragma unroll
      for (int q = 0; q < 4; ++q)
        red[mi * 16 + fg * 4 + q][wave] = ps[mi * 4 + q];
  }
  __syncthreads();
  if (tid < 64) {
    float s = 0.f;
#pragma unroll
    for (int w = 0; w < 8; ++w) s += red[tid][w];
    mrow[tid] = s * (1.f / 512.f);
  }
  __syncthreads();
  float mu[16];
#pragma unroll
  for (int mi = 0; mi < 4; ++mi)
#pragma unroll
    for (int q = 0; q < 4; ++q) mu[mi * 4 + q] = mrow[mi * 16 + fg * 4 + q];

  float ps2[16];
#pragma unroll
  for (int mi = 0; mi < 4; ++mi)
#pragma unroll
    for (int q = 0; q < 4; ++q) {
      const float m = mu[mi * 4 + q];
      float s = 0.f;
#pragma unroll
      for (int ni = 0; ni < 4; ++ni) {
        const float d = v[mi][ni][q] - m;
        s += d * d;
      }
      ps2[mi * 4 + q] = s;
    }
#pragma unroll
  for (int mask = 1; mask < 16; mask <<= 1)
#pragma unroll
    for (int t = 0; t < 16; ++t) ps2[t] += __shfl_xor(ps2[t], mask);
  if (fr == 0) {
#pragma unroll
    for (int mi = 0; mi < 4; ++mi)
#pragma unroll
      for (int q = 0; q < 4; ++q)
        red[mi * 16 + fg * 4 + q][wave] = ps2[mi * 4 + q];
  }
  __syncthreads();
  if (tid < 64) {
    float s = 0.f;
#pragma unroll
    for (int w = 0; w < 8; ++w) s += red[tid][w];
    rrow[tid] = rsqrtf(s * (1.f / 512.f) + EPS);
  }
  __syncthreads();

#pragma unroll
  for (int ni = 0; ni < 4; ++ni) {
    const int col = wave * 64 + ni * 16 + fr;
    const float gc = g[col], bc = bb[col];
#pragma unroll
    for (int mi = 0; mi < 4; ++mi)
#pragma unroll
      for (int q = 0; q < 4; ++q) {
        const int lrow = mi * 16 + fg * 4 + q;
        const int row = bm + lrow;
        const float o = (v[mi][ni][q] - mu[mi * 4 + q]) * rrow[lrow] * gc + bc;
        outF[(size_t)row * D + col] = o;
        outB[(size_t)row * D + col] = __float2bfloat16(o);
      }
  }
}

// ---------------------------------------------------------------------------
// MFMA attention core: one block per (b,h); q/k pointers + row strides.
// ---------------------------------------------------------------------------
__global__ __launch_bounds__(256) void attn_mfma_kernel(
    const __hip_bfloat16* __restrict__ qg, int qstr,
    const __hip_bfloat16* __restrict__ kg, int kstr,
    const __hip_bfloat16* __restrict__ vt,
    __hip_bfloat16* __restrict__ yg) {
  __shared__ __align__(16) char smem[33280];
  unsigned short* Qs  = (unsigned short*)smem;
  unsigned short* Ks  = (unsigned short*)(smem + 8192);
  float*          Ss  = (float*)smem;
  unsigned short* Vts = (unsigned short*)(smem + 16896);
  unsigned short* Ps  = (unsigned short*)(smem + 25088);

  const int tid  = threadIdx.x;
  const int bh   = blockIdx.x;
  const int bidx = bh >> 3, h = bh & 7;
  const size_t rbase = (size_t)bidx * 64;
  const int col0 = h * 64;

  const __hip_bfloat16* vtg = vt + (size_t)bh * 4096;
#pragma unroll
  for (int p = 0; p < 2; ++p) {
    const int idx = tid + p * 256;
    const int row = idx >> 3, c8 = (idx & 7) * 8;
    const int lb  = (row * 128 + c8 * 2) ^ ((row & 7) << 4);
    const uint4 vq = *reinterpret_cast<const uint4*>(qg + (rbase + row) * qstr + col0 + c8);
    const uint4 vk = *reinterpret_cast<const uint4*>(kg + (rbase + row) * kstr + col0 + c8);
    const uint4 vv = *reinterpret_cast<const uint4*>(vtg + idx * 8);
    *reinterpret_cast<uint4*>((char*)Qs  + lb) = vq;
    *reinterpret_cast<uint4*>((char*)Ks  + lb) = vk;
    *reinterpret_cast<uint4*>((char*)Vts + lb) = vv;
  }
  __syncthreads();

  const int wave = tid >> 6, lane = tid & 63;
  const int fr = lane & 15, fg = lane >> 4;
  const int wr = (wave >> 1) * 32, wc = (wave & 1) * 32;

  auto ldfrag = [&](const unsigned short* base, int row, int ks) -> short8b {
    const int byte = (row * 128 + ks * 64 + fg * 16) ^ ((row & 7) << 4);
    return *reinterpret_cast<const short8b*>((const char*)base + byte);
  };

  f32x4 acc[2][2] = {};
#pragma unroll
  for (int ks = 0; ks < 2; ++ks) {
    short8b a[2], b[2];
    a[0] = ldfrag(Qs, wr + fr, ks);
    a[1] = ldfrag(Qs, wr + 16 + fr, ks);
    b[0] = ldfrag(Ks, wc + fr, ks);
    b[1] = ldfrag(Ks, wc + 16 + fr, ks);
#pragma unroll
    for (int mi = 0; mi < 2; ++mi)
#pragma unroll
      for (int ni = 0; ni < 2; ++ni)
        acc[mi][ni] = __builtin_amdgcn_mfma_f32_16x16x32_bf16(a[mi], b[ni], acc[mi][ni], 0, 0, 0);
  }
  __syncthreads();

#pragma unroll
  for (int mi = 0; mi < 2; ++mi)
#pragma unroll
    for (int ni = 0; ni < 2; ++ni) {
      const int m2 = wc + ni * 16 + fr;
#pragma unroll
      for (int r = 0; r < 4; ++r) {
        const int n = wr + mi * 16 + fg * 4 + r;
        Ss[n * 66 + m2] = (m2 <= n) ? acc[mi][ni][r] * SCALE : -1e30f;
      }
    }
  __syncthreads();

  for (int n = wave * 16; n < wave * 16 + 16; ++n) {
    const float vv = Ss[n * 66 + lane];
    float mx = vv;
#pragma unroll
    for (int off = 1; off < 64; off <<= 1) mx = fmaxf(mx, __shfl_xor(mx, off));
    const float p = (lane <= n) ? __expf(vv - mx) : 0.f;
    float sum = p;
#pragma unroll
    for (int off = 1; off < 64; off <<= 1) sum += __shfl_xor(sum, off);
    const int byte = (n * 128 + lane * 2) ^ ((n & 7) << 4);
    *(unsigned short*)((char*)Ps + byte) = f2b_bits(p / sum);
  }
  __syncthreads();

  f32x4 acc2[2][2] = {};
#pragma unroll
  for (int ks = 0; ks < 2; ++ks) {
    short8b a[2], b[2];
    a[0] = ldfrag(Ps, wr + fr, ks);
    a[1] = ldfrag(Ps, wr + 16 + fr, ks);
    b[0] = ldfrag(Vts, wc + fr, ks);
    b[1] = ldfrag(Vts, wc + 16 + fr, ks);
#pragma unroll
    for (int mi = 0; mi < 2; ++mi)
#pragma unroll
      for (int ni = 0; ni < 2; ++ni)
        acc2[mi][ni] = __builtin_amdgcn_mfma_f32_16x16x32_bf16(a[mi], b[ni], acc2[mi][ni], 0, 0, 0);
  }
#pragma unroll
  for (int mi = 0; mi < 2; ++mi)
#pragma unroll
    for (int r = 0; r < 4; ++r) {
      const int n = wr + mi * 16 + fg * 4 + r;
      yg[(rbase + n) * 512 + col0 + wc + fr]      = __float2bfloat16(acc2[mi][0][r]);
      yg[(rbase + n) * 512 + col0 + wc + 16 + fr] = __float2bfloat16(acc2[mi][1][r]);
    }
}

// ---------------------------------------------------------------------------
// Prep kernels.
// ---------------------------------------------------------------------------
__global__ __launch_bounds__(256) void wconv_kernel(
    const float* __restrict__ src, __hip_bfloat16* __restrict__ dst,
    int soff, int sstr, long dstr) {
  __shared__ float tile[32][33];
  const int mat = blockIdx.z;
  const float* s = src + (size_t)(soff + mat * sstr) * D * D;
  __hip_bfloat16* d = dst + (size_t)mat * dstr;
  const int r0 = blockIdx.y * 32, c0 = blockIdx.x * 32;
  const int tr = threadIdx.x >> 5;
  const int tc = threadIdx.x & 31;
#pragma unroll
  for (int i = 0; i < 4; ++i)
    tile[tr + 8 * i][tc] = s[(size_t)(r0 + tr + 8 * i) * D + c0 + tc];
  __syncthreads();
#pragma unroll
  for (int i = 0; i < 4; ++i)
    d[(size_t)(c0 + tr + 8 * i) * D + r0 + tc] = __float2bfloat16(tile[tc][tr + 8 * i]);
}

__global__ __launch_bounds__(256) void cvt_kernel(
    const float* __restrict__ src, __hip_bfloat16* __restrict__ dst, int n4) {
  const int i = blockIdx.x * 256 + threadIdx.x;
  if (i < n4) {
    const float4 v = reinterpret_cast<const float4*>(src)[i];
    ushort4 o;
    o.x = f2b_bits(v.x); o.y = f2b_bits(v.y);
    o.z = f2b_bits(v.z); o.w = f2b_bits(v.w);
    reinterpret_cast<ushort4*>(dst)[i] = o;
  }
}

__global__ __launch_bounds__(256) void act_cvt_kernel(
    const float* __restrict__ src, __hip_bfloat16* __restrict__ dst) {
  for (int i = blockIdx.x * 256 + threadIdx.x; i < M * 96; i += gridDim.x * 256) {
    const int row = i / 96, k = i - row * 96;
    dst[i] = (k < 65) ? __float2bfloat16(src[(size_t)row * 65 + k]) : __float2bfloat16(0.f);
  }
}

__global__ __launch_bounds__(256) void wae_conv_kernel(
    const float* __restrict__ src, __hip_bfloat16* __restrict__ dst) {
  for (int i = blockIdx.x * 256 + threadIdx.x; i < 512 * 96; i += gridDim.x * 256) {
    const int n = i / 96, k = i - n * 96;
    dst[i] = (k < 65) ? __float2bfloat16(src[(size_t)k * 512 + n]) : __float2bfloat16(0.f);
  }
}

__global__ __launch_bounds__(256) void wh2_conv_kernel(
    const float* __restrict__ src, __hip_bfloat16* __restrict__ dst) {
  for (int i = blockIdx.x * 256 + threadIdx.x; i < 128 * 512; i += gridDim.x * 256) {
    const int n = i >> 9, k = i & 511;
    dst[i] = (n < 64) ? __float2bfloat16(src[(size_t)k * 64 + n]) : __float2bfloat16(0.f);
  }
}

__global__ __launch_bounds__(256) void pack_selfb_kernel(
    const float* __restrict__ bq, const float* __restrict__ bk,
    const float* __restrict__ bv, float* __restrict__ dst) {
  const int i = blockIdx.x * 256 + threadIdx.x;
  if (i < NBLK * 1536) {
    const int blk = i / 1536, c = i - blk * 1536;
    const int seg = c >> 9, cc = c & 511;
    const float* s = (seg == 0) ? bq : (seg == 1) ? bk : bv;
    dst[i] = s[(size_t)(blk * 2) * 512 + cc];
  }
}

__global__ __launch_bounds__(256) void pack_ckvb_kernel(
    const float* __restrict__ bk, const float* __restrict__ bv,
    float* __restrict__ dst) {
  const int i = blockIdx.x * 256 + threadIdx.x;
  if (i < NBLK * 1024) {
    const int blk = i >> 10, c = i & 1023;
    dst[i] = (c < 512) ? bk[(size_t)(blk * 2 + 1) * 512 + c]
                       : bv[(size_t)(blk * 2 + 1) * 512 + (c - 512)];
  }
}

}  // namespace

extern "C" void kernel_launch(void* const* d_in, const int* in_sizes, int n_in,
                              void* d_out, int out_size, void* d_ws, size_t ws_size,
                              hipStream_t stream) {
  const float* action  = (const float*)d_in[0];
  const float* obs_rep = (const float*)d_in[1];
  const float* w_ae    = (const float*)d_in[3];
  const float* ln0_g   = (const float*)d_in[4];
  const float* ln0_b   = (const float*)d_in[5];
  const float* bln_g   = (const float*)d_in[6];
  const float* bln_b   = (const float*)d_in[7];
  const float* bwq     = (const float*)d_in[8];
  const float* bwk     = (const float*)d_in[9];
  const float* bwv     = (const float*)d_in[10];
  const float* bwp     = (const float*)d_in[11];
  const float* bbq     = (const float*)d_in[12];
  const float* bbk     = (const float*)d_in[13];
  const float* bbv     = (const float*)d_in[14];
  const float* bbp     = (const float*)d_in[15];
  const float* bw1     = (const float*)d_in[16];
  const float* bb1     = (const float*)d_in[17];
  const float* bw2     = (const float*)d_in[18];
  const float* bb2     = (const float*)d_in[19];
  const float* wh1     = (const float*)d_in[20];
  const float* bh1     = (const float*)d_in[21];
  const float* lnh_g   = (const float*)d_in[22];
  const float* lnh_b   = (const float*)d_in[23];
  const float* wh2     = (const float*)d_in[24];
  const float* bh2     = (const float*)d_in[25];

  char* ws = (char*)d_ws;
  const size_t MAT = (size_t)D * D;
  const size_t szF = (size_t)M * D * 4;        // 32 MB
  const size_t szB = (size_t)M * D * 2;        // 16 MB

  float* x            = (float*)ws;          ws += szF;
  __hip_bfloat16* xb  = (__hip_bfloat16*)ws; ws += szB;
  __hip_bfloat16* hb  = (__hip_bfloat16*)ws; ws += szB;
  __hip_bfloat16* vtb = (__hip_bfloat16*)ws; ws += szB;
  __hip_bfloat16* orb = (__hip_bfloat16*)ws; ws += szB;
  __hip_bfloat16* qkb = (__hip_bfloat16*)ws; ws += 2 * szB;  // [M][1024]
  __hip_bfloat16* qcb = (__hip_bfloat16*)ws; ws += szB;      // [M][512] cross Q
  __hip_bfloat16* kb  = (__hip_bfloat16*)ws; ws += szB;      // [M][512] cross K
  __hip_bfloat16* actb = (__hip_bfloat16*)ws; ws += (size_t)M * 96 * 2;
  __hip_bfloat16* wSelf = (__hip_bfloat16*)ws; ws += (size_t)NBLK * 1536 * 512 * 2;
  __hip_bfloat16* wCq   = (__hip_bfloat16*)ws; ws += (size_t)NBLK * 512 * 512 * 2;
  __hip_bfloat16* wCkv  = (__hip_bfloat16*)ws; ws += (size_t)NBLK * 1024 * 512 * 2;
  __hip_bfloat16* wTp   = (__hip_bfloat16*)ws; ws += 8 * MAT * 2;
  __hip_bfloat16* wTw1  = (__hip_bfloat16*)ws; ws += 4 * MAT * 2;
  __hip_bfloat16* wTw2  = (__hip_bfloat16*)ws; ws += 4 * MAT * 2;
  __hip_bfloat16* wTh1  = (__hip_bfloat16*)ws; ws += MAT * 2;
  __hip_bfloat16* wh2p  = (__hip_bfloat16*)ws; ws += 128 * 512 * 2;
  __hip_bfloat16* waeT  = (__hip_bfloat16*)ws; ws += 512 * 96 * 2;
  float* selfb         = (float*)ws;         ws += (size_t)NBLK * 1536 * 4;
  float* ckvb          = (float*)ws;         ws += (size_t)NBLK * 1024 * 4;

  // ---- one-time prep ----
  const long SS = 1536 * 512;
  wconv_kernel<<<dim3(16, 16, 4), 256, 0, stream>>>(bwq, wSelf, 0, 2, SS);
  wconv_kernel<<<dim3(16, 16, 4), 256, 0, stream>>>(bwk, wSelf + 512 * 512, 0, 2, SS);
  wconv_kernel<<<dim3(16, 16, 4), 256, 0, stream>>>(bwv, wSelf + 1024 * 512, 0, 2, SS);
  wconv_kernel<<<dim3(16, 16, 4), 256, 0, stream>>>(bwq, wCq, 1, 2, (long)MAT);
  wconv_kernel<<<dim3(16, 16, 4), 256, 0, stream>>>(bwk, wCkv, 1, 2, 1024 * 512L);
  wconv_kernel<<<dim3(16, 16, 4), 256, 0, stream>>>(bwv, wCkv + 512 * 512, 1, 2, 1024 * 512L);
  wconv_kernel<<<dim3(16, 16, 8), 256, 0, stream>>>(bwp, wTp, 0, 1, (long)MAT);
  wconv_kernel<<<dim3(16, 16, 4), 256, 0, stream>>>(bw1, wTw1, 0, 1, (long)MAT);
  wconv_kernel<<<dim3(16, 16, 4), 256, 0, stream>>>(bw2, wTw2, 0, 1, (long)MAT);
  wconv_kernel<<<dim3(16, 16, 1), 256, 0, stream>>>(wh1, wTh1, 0, 1, (long)MAT);
  wae_conv_kernel<<<192, 256, 0, stream>>>(w_ae, waeT);
  wh2_conv_kernel<<<256, 256, 0, stream>>>(wh2, wh2p);
  pack_selfb_kernel<<<(NBLK * 1536 + 255) / 256, 256, 0, stream>>>(bbq, bbk, bbv, selfb);
  pack_ckvb_kernel<<<(NBLK * 1024 + 255) / 256, 256, 0, stream>>>(bbk, bbv, ckvb);
  cvt_kernel<<<(M * D / 4 + 255) / 256, 256, 0, stream>>>(obs_rep, orb, M * D / 4);
  act_cvt_kernel<<<2048, 256, 0, stream>>>(action, actb);

  const int lnGrid = M / 64;   // 256 blocks, 512 threads

  // ---- encoder: x = LN(gelu(action @ w_ae)) ----
  gemm_ln_kernel<3, true, false><<<lnGrid, 512, 0, stream>>>(
      actb, waeT, nullptr, nullptr, ln0_g, ln0_b, x, xb);

  for (int i = 0; i < NBLK; ++i) {
    const float* g0 = bln_g + (size_t)(i * 3 + 0) * D;
    const float* b0 = bln_b + (size_t)(i * 3 + 0) * D;
    const float* g1 = bln_g + (size_t)(i * 3 + 1) * D;
    const float* b1 = bln_b + (size_t)(i * 3 + 1) * D;
    const float* g2 = bln_g + (size_t)(i * 3 + 2) * D;
    const float* b2 = bln_b + (size_t)(i * 3 + 2) * D;

    // ---- sublayer 1: self-attention ----
    gemm_dp_kernel<false, 1024><<<M / 128 * 6, 512, 0, stream>>>(
        xb, wSelf + (size_t)i * SS, selfb + (size_t)i * 1536, qkb, 1024, vtb, 6);
    attn_mfma_kernel<<<B * H, 256, 0, stream>>>(qkb, 1024, qkb + 512, 1024, vtb, hb);
    gemm_ln_kernel<16, false, true><<<lnGrid, 512, 0, stream>>>(
        hb, wTp + (size_t)(i * 2) * MAT, bbp + (size_t)(i * 2) * D, x, g0, b0, x, xb);

    // ---- sublayer 2: cross-attention ----
    gemm_dp_kernel<false, NEVER><<<M / 128 * 2, 512, 0, stream>>>(
        orb, wCq + (size_t)i * MAT, bbq + (size_t)(i * 2 + 1) * D, qcb, 512, nullptr, 2);
    gemm_dp_kernel<false, 512><<<M / 128 * 4, 512, 0, stream>>>(
        xb, wCkv + (size_t)i * 1024 * 512, ckvb + (size_t)i * 1024, kb, 512, vtb, 4);
    attn_mfma_kernel<<<B * H, 256, 0, stream>>>(qcb, 512, kb, 512, vtb, hb);
    gemm_ln_kernel<16, false, true><<<lnGrid, 512, 0, stream>>>(
        hb, wTp + (size_t)(i * 2 + 1) * MAT, bbp + (size_t)(i * 2 + 1) * D,
        obs_rep, g1, b1, x, xb);

    // ---- sublayer 3: MLP ----
    gemm_dp_kernel<true, NEVER><<<M / 128 * 2, 512, 0, stream>>>(
        xb, wTw1 + (size_t)i * MAT, bb1 + (size_t)i * D, hb, 512, nullptr, 2);
    gemm_ln_kernel<16, false, true><<<lnGrid, 512, 0, stream>>>(
        hb, wTw2 + (size_t)i * MAT, bb2 + (size_t)i * D, x, g2, b2, x, xb);
  }

  // ---- head ----
  gemm_ln_kernel<16, true, false><<<lnGrid, 512, 0, stream>>>(
      xb, wTh1, bh1, nullptr, lnh_g, lnh_b, x, xb);
  gemm_std_kernel<16, false, NEVER, true><<<dim3(M / 128, 1), 256, 0, stream>>>(
      xb, wh2p, bh2, (float*)d_out, 64, nullptr, 64);
}

// Round 6
// 1038.846 us; speedup vs baseline: 11.5013x; 1.0963x over previous
//
#include <hip/hip_runtime.h>
#include <hip/hip_bf16.h>
#include <math.h>

namespace {

constexpr int B  = 256;
constexpr int N  = 64;
constexpr int D  = 512;
constexpr int H  = 8;
constexpr int NBLK = 4;
constexpr int M  = B * N;          // 16384 token rows
constexpr float EPS = 1e-5f;
constexpr float SCALE = 0.125f;    // 1/sqrt(64)
constexpr int NEVER = 1 << 20;

typedef __attribute__((ext_vector_type(8))) short short8b;
typedef __attribute__((ext_vector_type(4))) float f32x4;

__device__ __forceinline__ float gelu_exact(float x) {
  return 0.5f * x * (1.0f + erff(x * 0.70710678118654752440f));
}

__device__ __forceinline__ unsigned short f2b_bits(float f) {
  __hip_bfloat16 h = __float2bfloat16(f);
  return *reinterpret_cast<unsigned short*>(&h);
}

#define GLOBAL_AS __attribute__((address_space(1)))
#define LDS_AS    __attribute__((address_space(3)))

__device__ __forceinline__ void gload_lds16(const void* g, void* l) {
  __builtin_amdgcn_global_load_lds((const GLOBAL_AS void*)g, (LDS_AS void*)l, 16, 0, 0);
}

// ---------------------------------------------------------------------------
// Deep-pipelined bf16 MFMA GEMM (T3+T4 counted-vmcnt structure).
// Tile BM=128 x BN=256, BK=64, 512 threads (8 waves, 2M x 4N, 64x64/wave).
// 3 LDS buffers (144 KB); 1 raw s_barrier + s_waitcnt vmcnt(6) per K-tile.
// K = 512 fixed. Epilogue: col<SPLIT -> bf16 out1 (opt GELU);
// col>=SPLIT -> per-head transposed V store.
// ---------------------------------------------------------------------------
template<bool GELU, int SPLIT>
__global__ __launch_bounds__(512, 2) void gemm_dp_kernel(
    const __hip_bfloat16* __restrict__ A,
    const __hip_bfloat16* __restrict__ Wt,
    const float* __restrict__ bias,
    __hip_bfloat16* __restrict__ out1, int ostr1,
    __hip_bfloat16* __restrict__ vt, int gy) {
  constexpr int K = 512;
  constexpr int NT = 8;                      // K / 64
  __shared__ __hip_bfloat16 Als[3][128][64]; // 48 KB
  __shared__ __hip_bfloat16 Bls[3][256][64]; // 96 KB

  const int nwg = gridDim.x;
  const int hw  = blockIdx.x;
  const int cpx = nwg >> 3;
  const int lg  = (hw & 7) * cpx + (hw >> 3);
  const int bm  = (lg / gy) * 128;
  const int bn  = (lg % gy) * 256;

  const int tid  = threadIdx.x;
  const int wave = tid >> 6;
  const int lane = tid & 63;
  const int wm   = (wave >> 2) * 64;
  const int wn   = (wave & 3) * 64;
  const int fr   = lane & 15;
  const int fg   = lane >> 4;

  const int srow  = tid >> 3;
  const int sslot = (tid & 7) ^ (srow & 7);
  const __hip_bfloat16* gA = A  + (size_t)(bm + srow) * K + sslot * 8;
  const __hip_bfloat16* gB = Wt + (size_t)(bn + srow) * K + sslot * 8;

  auto STAGE = [&](int buf, int kt) {
    const int ko = kt * 64;
    char* la = (char*)&Als[buf][0][0] + wave * 1024;
    char* lb = (char*)&Bls[buf][0][0] + wave * 1024;
    gload_lds16(gA + ko,           la);
    gload_lds16(gA + 64 * K + ko,  la + 8192);
    gload_lds16(gB + ko,           lb);
    gload_lds16(gB + 64 * K + ko,  lb + 8192);
    gload_lds16(gB + 128 * K + ko, lb + 16384);
    gload_lds16(gB + 192 * K + ko, lb + 24576);
  };

  auto lda = [&](int buf, int mi, int ks) -> short8b {
    const int row  = wm + mi * 16 + fr;
    const int byte = row * 128 + (((ks << 2) | fg) ^ (fr & 7)) * 16;
    return *reinterpret_cast<const short8b*>((const char*)&Als[buf][0][0] + byte);
  };
  auto ldb = [&](int buf, int ni, int ks) -> short8b {
    const int row  = wn + ni * 16 + fr;
    const int byte = row * 128 + (((ks << 2) | fg) ^ (fr & 7)) * 16;
    return *reinterpret_cast<const short8b*>((const char*)&Bls[buf][0][0] + byte);
  };

  STAGE(0, 0);
  STAGE(1, 1);
  asm volatile("s_waitcnt vmcnt(6)" ::: "memory");
  __builtin_amdgcn_sched_barrier(0);
  __builtin_amdgcn_s_barrier();
  __builtin_amdgcn_sched_barrier(0);

  f32x4 acc[4][4] = {};
  for (int t = 0; t < NT; ++t) {
    const int cur = t % 3;
    if (t + 2 < NT) STAGE((t + 2) % 3, t + 2);

    short8b a0[4], b0[4], a1[4], b1[4];
#pragma unroll
    for (int mi = 0; mi < 4; ++mi) a0[mi] = lda(cur, mi, 0);
#pragma unroll
    for (int ni = 0; ni < 4; ++ni) b0[ni] = ldb(cur, ni, 0);
#pragma unroll
    for (int mi = 0; mi < 4; ++mi) a1[mi] = lda(cur, mi, 1);
#pragma unroll
    for (int ni = 0; ni < 4; ++ni) b1[ni] = ldb(cur, ni, 1);

    __builtin_amdgcn_s_setprio(1);
#pragma unroll
    for (int mi = 0; mi < 4; ++mi)
#pragma unroll
      for (int ni = 0; ni < 4; ++ni)
        acc[mi][ni] = __builtin_amdgcn_mfma_f32_16x16x32_bf16(a0[mi], b0[ni], acc[mi][ni], 0, 0, 0);
#pragma unroll
    for (int mi = 0; mi < 4; ++mi)
#pragma unroll
      for (int ni = 0; ni < 4; ++ni)
        acc[mi][ni] = __builtin_amdgcn_mfma_f32_16x16x32_bf16(a1[mi], b1[ni], acc[mi][ni], 0, 0, 0);
    __builtin_amdgcn_s_setprio(0);

    if (t + 2 < NT) {
      asm volatile("s_waitcnt vmcnt(6)" ::: "memory");
    } else {
      asm volatile("s_waitcnt vmcnt(0)" ::: "memory");
    }
    __builtin_amdgcn_sched_barrier(0);
    __builtin_amdgcn_s_barrier();
    __builtin_amdgcn_sched_barrier(0);
  }

#pragma unroll
  for (int ni = 0; ni < 4; ++ni) {
    const int col = bn + wn + ni * 16 + fr;
    const float bv = bias ? bias[col] : 0.f;
#pragma unroll
    for (int mi = 0; mi < 4; ++mi) {
      const int row0 = bm + wm + mi * 16 + fg * 4;
      if (col >= SPLIT) {
        const int vcol = col - SPLIT;
        ushort4 o;
        o.x = f2b_bits(acc[mi][ni][0] + bv);
        o.y = f2b_bits(acc[mi][ni][1] + bv);
        o.z = f2b_bits(acc[mi][ni][2] + bv);
        o.w = f2b_bits(acc[mi][ni][3] + bv);
        const int b8 = row0 >> 6, nl = row0 & 63;
        const int hh = vcol >> 6, dl = vcol & 63;
        *reinterpret_cast<ushort4*>(vt +
            ((size_t)(b8 * 8 + hh) * 4096 + dl * 64 + nl)) = o;
      } else {
#pragma unroll
        for (int q = 0; q < 4; ++q) {
          float v = acc[mi][ni][q] + bv;
          if (GELU) v = gelu_exact(v);
          out1[(size_t)(row0 + q) * ostr1 + col] = __float2bfloat16(v);
        }
      }
    }
  }
}

// ---------------------------------------------------------------------------
// Standard bf16 MFMA GEMM (m97 structure) — for the tiny head GEMM (f32 out).
// ---------------------------------------------------------------------------
template<int KSTEPS>
__global__ __launch_bounds__(256) void gemm_head_kernel(
    const __hip_bfloat16* __restrict__ A,
    const __hip_bfloat16* __restrict__ Wt,
    const float* __restrict__ bias,
    float* __restrict__ out1, int ostr1, int nvalid) {
  constexpr int K = KSTEPS * 32;
  __shared__ __hip_bfloat16 Als[2][128][32];
  __shared__ __hip_bfloat16 Bls[2][128][32];

  const int bm   = blockIdx.x * 128;
  const int bn   = blockIdx.y * 128;
  const int tid  = threadIdx.x;
  const int wave = tid >> 6;
  const int lane = tid & 63;
  const int wm   = (wave >> 1) * 64;
  const int wn   = (wave & 1) * 64;
  const int fr   = lane & 15;
  const int fg   = lane >> 4;

  const int srow = (lane >> 2);
  const int scol = (lane & 3) * 8;
  const __hip_bfloat16* gA0 = A  + (size_t)(bm + wave * 32 + srow) * K + scol;
  const __hip_bfloat16* gA1 = gA0 + 16 * K;
  const __hip_bfloat16* gB0 = Wt + (size_t)(bn + wave * 32 + srow) * K + scol;
  const __hip_bfloat16* gB1 = gB0 + 16 * K;

  f32x4 acc[4][4] = {};

  auto stage = [&](int buf, int ks) {
    const int ko = ks * 32;
    gload_lds16(gA0 + ko, &Als[buf][wave * 32][0]);
    gload_lds16(gA1 + ko, &Als[buf][wave * 32 + 16][0]);
    gload_lds16(gB0 + ko, &Bls[buf][wave * 32][0]);
    gload_lds16(gB1 + ko, &Bls[buf][wave * 32 + 16][0]);
  };

  stage(0, 0);
  int buf = 0;
  for (int ks = 0; ks < KSTEPS; ++ks) {
    __syncthreads();
    if (ks + 1 < KSTEPS) stage(buf ^ 1, ks + 1);
    short8b a[4], b[4];
#pragma unroll
    for (int mi = 0; mi < 4; ++mi)
      a[mi] = *reinterpret_cast<const short8b*>(&Als[buf][wm + mi * 16 + fr][fg * 8]);
#pragma unroll
    for (int ni = 0; ni < 4; ++ni)
      b[ni] = *reinterpret_cast<const short8b*>(&Bls[buf][wn + ni * 16 + fr][fg * 8]);
#pragma unroll
    for (int mi = 0; mi < 4; ++mi)
#pragma unroll
      for (int ni = 0; ni < 4; ++ni)
        acc[mi][ni] = __builtin_amdgcn_mfma_f32_16x16x32_bf16(a[mi], b[ni], acc[mi][ni], 0, 0, 0);
    buf ^= 1;
  }

#pragma unroll
  for (int ni = 0; ni < 4; ++ni) {
    const int col = bn + wn + ni * 16 + fr;
    if (col >= nvalid) continue;
    const float bv = bias ? bias[col] : 0.f;
#pragma unroll
    for (int mi = 0; mi < 4; ++mi) {
      const int row0 = bm + wm + mi * 16 + fg * 4;
#pragma unroll
      for (int q = 0; q < 4; ++q)
        out1[(size_t)(row0 + q) * ostr1 + col] = acc[mi][ni][q] + bv;
    }
  }
}

// ---------------------------------------------------------------------------
// Fused GEMM + bias (+GELU) + bf16 residual + LayerNorm -> bf16 out.
// Tile BM=64 x BN=512 (full width), 512 threads (8 waves).
// ---------------------------------------------------------------------------
template<int KSTEPS, bool GELU_PRE, bool RES>
__global__ __launch_bounds__(512) void gemm_ln_kernel(
    const __hip_bfloat16* __restrict__ A,
    const __hip_bfloat16* __restrict__ Wt,
    const float* __restrict__ bias,
    const __hip_bfloat16* __restrict__ resb,
    const float* __restrict__ g, const float* __restrict__ bb,
    __hip_bfloat16* __restrict__ outB) {
  constexpr int K = KSTEPS * 32;
  __shared__ __hip_bfloat16 Als[2][64][32];
  __shared__ __hip_bfloat16 Bls[2][512][32];
  __shared__ float red[64][8];
  __shared__ float mrow[64];
  __shared__ float rrow[64];

  const int bm   = blockIdx.x * 64;
  const int tid  = threadIdx.x;
  const int wave = tid >> 6;
  const int lane = tid & 63;
  const int fr   = lane & 15;
  const int fg   = lane >> 4;
  const int srow = lane >> 2;
  const int scol = (lane & 3) * 8;

  auto stage = [&](int buf, int ks) {
    const int ko = ks * 32;
    if (wave < 4)
      gload_lds16(A + (size_t)(bm + wave * 16 + srow) * K + ko + scol,
                  &Als[buf][wave * 16][0]);
#pragma unroll
    for (int c = 0; c < 4; ++c)
      gload_lds16(Wt + (size_t)(wave * 64 + c * 16 + srow) * K + ko + scol,
                  &Bls[buf][wave * 64 + c * 16][0]);
  };

  f32x4 acc[4][4] = {};
  stage(0, 0);
  int buf = 0;
  for (int ks = 0; ks < KSTEPS; ++ks) {
    __syncthreads();
    if (ks + 1 < KSTEPS) stage(buf ^ 1, ks + 1);
    short8b a[4], b[4];
#pragma unroll
    for (int mi = 0; mi < 4; ++mi)
      a[mi] = *reinterpret_cast<const short8b*>(&Als[buf][mi * 16 + fr][fg * 8]);
#pragma unroll
    for (int ni = 0; ni < 4; ++ni)
      b[ni] = *reinterpret_cast<const short8b*>(&Bls[buf][wave * 64 + ni * 16 + fr][fg * 8]);
#pragma unroll
    for (int mi = 0; mi < 4; ++mi)
#pragma unroll
      for (int ni = 0; ni < 4; ++ni)
        acc[mi][ni] = __builtin_amdgcn_mfma_f32_16x16x32_bf16(a[mi], b[ni], acc[mi][ni], 0, 0, 0);
    buf ^= 1;
  }

  float v[4][4][4];
  float bvc[4];
#pragma unroll
  for (int ni = 0; ni < 4; ++ni)
    bvc[ni] = bias ? bias[wave * 64 + ni * 16 + fr] : 0.f;
#pragma unroll
  for (int mi = 0; mi < 4; ++mi)
#pragma unroll
    for (int q = 0; q < 4; ++q) {
      const int row = bm + mi * 16 + fg * 4 + q;
#pragma unroll
      for (int ni = 0; ni < 4; ++ni) {
        float t = acc[mi][ni][q] + bvc[ni];
        if (GELU_PRE) t = gelu_exact(t);
        if (RES)
          t += __bfloat162float(resb[(size_t)row * D + wave * 64 + ni * 16 + fr]);
        v[mi][ni][q] = t;
      }
    }

  float ps[16];
#pragma unroll
  for (int mi = 0; mi < 4; ++mi)
#pragma unroll
    for (int q = 0; q < 4; ++q)
      ps[mi * 4 + q] = v[mi][0][q] + v[mi][1][q] + v[mi][2][q] + v[mi][3][q];
#pragma unroll
  for (int mask = 1; mask < 16; mask <<= 1)
#pragma unroll
    for (int t = 0; t < 16; ++t) ps[t] += __shfl_xor(ps[t], mask);
  if (fr == 0) {
#pragma unroll
    for (int mi = 0; mi < 4; ++mi)
#pragma unroll
      for (int q = 0; q < 4; ++q)
        red[mi * 16 + fg * 4 + q][wave] = ps[mi * 4 + q];
  }
  __syncthreads();
  if (tid < 64) {
    float s = 0.f;
#pragma unroll
    for (int w = 0; w < 8; ++w) s += red[tid][w];
    mrow[tid] = s * (1.f / 512.f);
  }
  __syncthreads();
  float mu[16];
#pragma unroll
  for (int mi = 0; mi < 4; ++mi)
#pragma unroll
    for (int q = 0; q < 4; ++q) mu[mi * 4 + q] = mrow[mi * 16 + fg * 4 + q];

  float ps2[16];
#pragma unroll
  for (int mi = 0; mi < 4; ++mi)
#pragma unroll
    for (int q = 0; q < 4; ++q) {
      const float m = mu[mi * 4 + q];
      float s = 0.f;
#pragma unroll
      for (int ni = 0; ni < 4; ++ni) {
        const float d = v[mi][ni][q] - m;
        s += d * d;
      }
      ps2[mi * 4 + q] = s;
    }
#pragma unroll
  for (int mask = 1; mask < 16; mask <<= 1)
#pragma unroll
    for (int t = 0; t < 16; ++t) ps2[t] += __shfl_xor(ps2[t], mask);
  if (fr == 0) {
#pragma unroll
    for (int mi = 0; mi < 4; ++mi)
#pragma unroll
      for (int q = 0; q < 4; ++q)
        red[mi * 16 + fg * 4 + q][wave] = ps2[mi * 4 + q];
  }
  __syncthreads();
  if (tid < 64) {
    float s = 0.f;
#pragma unroll
    for (int w = 0; w < 8; ++w) s += red[tid][w];
    rrow[tid] = rsqrtf(s * (1.f / 512.f) + EPS);
  }
  __syncthreads();

#pragma unroll
  for (int ni = 0; ni < 4; ++ni) {
    const int col = wave * 64 + ni * 16 + fr;
    const float gc = g[col], bc = bb[col];
#pragma unroll
    for (int mi = 0; mi < 4; ++mi)
#pragma unroll
      for (int q = 0; q < 4; ++q) {
        const int lrow = mi * 16 + fg * 4 + q;
        const int row = bm + lrow;
        const float o = (v[mi][ni][q] - mu[mi * 4 + q]) * rrow[lrow] * gc + bc;
        outB[(size_t)row * D + col] = __float2bfloat16(o);
      }
  }
}

// ---------------------------------------------------------------------------
// MFMA attention core: one block per (b,h); q/k pointers + row strides.
// ---------------------------------------------------------------------------
__global__ __launch_bounds__(256) void attn_mfma_kernel(
    const __hip_bfloat16* __restrict__ qg, int qstr,
    const __hip_bfloat16* __restrict__ kg, int kstr,
    const __hip_bfloat16* __restrict__ vt,
    __hip_bfloat16* __restrict__ yg) {
  __shared__ __align__(16) char smem[33280];
  unsigned short* Qs  = (unsigned short*)smem;
  unsigned short* Ks  = (unsigned short*)(smem + 8192);
  float*          Ss  = (float*)smem;
  unsigned short* Vts = (unsigned short*)(smem + 16896);
  unsigned short* Ps  = (unsigned short*)(smem + 25088);

  const int tid  = threadIdx.x;
  const int bh   = blockIdx.x;
  const int bidx = bh >> 3, h = bh & 7;
  const size_t rbase = (size_t)bidx * 64;
  const int col0 = h * 64;

  const __hip_bfloat16* vtg = vt + (size_t)bh * 4096;
#pragma unroll
  for (int p = 0; p < 2; ++p) {
    const int idx = tid + p * 256;
    const int row = idx >> 3, c8 = (idx & 7) * 8;
    const int lb  = (row * 128 + c8 * 2) ^ ((row & 7) << 4);
    const uint4 vq = *reinterpret_cast<const uint4*>(qg + (rbase + row) * qstr + col0 + c8);
    const uint4 vk = *reinterpret_cast<const uint4*>(kg + (rbase + row) * kstr + col0 + c8);
    const uint4 vv = *reinterpret_cast<const uint4*>(vtg + idx * 8);
    *reinterpret_cast<uint4*>((char*)Qs  + lb) = vq;
    *reinterpret_cast<uint4*>((char*)Ks  + lb) = vk;
    *reinterpret_cast<uint4*>((char*)Vts + lb) = vv;
  }
  __syncthreads();

  const int wave = tid >> 6, lane = tid & 63;
  const int fr = lane & 15, fg = lane >> 4;
  const int wr = (wave >> 1) * 32, wc = (wave & 1) * 32;

  auto ldfrag = [&](const unsigned short* base, int row, int ks) -> short8b {
    const int byte = (row * 128 + ks * 64 + fg * 16) ^ ((row & 7) << 4);
    return *reinterpret_cast<const short8b*>((const char*)base + byte);
  };

  f32x4 acc[2][2] = {};
#pragma unroll
  for (int ks = 0; ks < 2; ++ks) {
    short8b a[2], b[2];
    a[0] = ldfrag(Qs, wr + fr, ks);
    a[1] = ldfrag(Qs, wr + 16 + fr, ks);
    b[0] = ldfrag(Ks, wc + fr, ks);
    b[1] = ldfrag(Ks, wc + 16 + fr, ks);
#pragma unroll
    for (int mi = 0; mi < 2; ++mi)
#pragma unroll
      for (int ni = 0; ni < 2; ++ni)
        acc[mi][ni] = __builtin_amdgcn_mfma_f32_16x16x32_bf16(a[mi], b[ni], acc[mi][ni], 0, 0, 0);
  }
  __syncthreads();

#pragma unroll
  for (int mi = 0; mi < 2; ++mi)
#pragma unroll
    for (int ni = 0; ni < 2; ++ni) {
      const int m2 = wc + ni * 16 + fr;
#pragma unroll
      for (int r = 0; r < 4; ++r) {
        const int n = wr + mi * 16 + fg * 4 + r;
        Ss[n * 66 + m2] = (m2 <= n) ? acc[mi][ni][r] * SCALE : -1e30f;
      }
    }
  __syncthreads();

  for (int n = wave * 16; n < wave * 16 + 16; ++n) {
    const float vv = Ss[n * 66 + lane];
    float mx = vv;
#pragma unroll
    for (int off = 1; off < 64; off <<= 1) mx = fmaxf(mx, __shfl_xor(mx, off));
    const float p = (lane <= n) ? __expf(vv - mx) : 0.f;
    float sum = p;
#pragma unroll
    for (int off = 1; off < 64; off <<= 1) sum += __shfl_xor(sum, off);
    const int byte = (n * 128 + lane * 2) ^ ((n & 7) << 4);
    *(unsigned short*)((char*)Ps + byte) = f2b_bits(p / sum);
  }
  __syncthreads();

  f32x4 acc2[2][2] = {};
#pragma unroll
  for (int ks = 0; ks < 2; ++ks) {
    short8b a[2], b[2];
    a[0] = ldfrag(Ps, wr + fr, ks);
    a[1] = ldfrag(Ps, wr + 16 + fr, ks);
    b[0] = ldfrag(Vts, wc + fr, ks);
    b[1] = ldfrag(Vts, wc + 16 + fr, ks);
#pragma unroll
    for (int mi = 0; mi < 2; ++mi)
#pragma unroll
      for (int ni = 0; ni < 2; ++ni)
        acc2[mi][ni] = __builtin_amdgcn_mfma_f32_16x16x32_bf16(a[mi], b[ni], acc2[mi][ni], 0, 0, 0);
  }
#pragma unroll
  for (int mi = 0; mi < 2; ++mi)
#pragma unroll
    for (int r = 0; r < 4; ++r) {
      const int n = wr + mi * 16 + fg * 4 + r;
      yg[(rbase + n) * 512 + col0 + wc + fr]      = __float2bfloat16(acc2[mi][0][r]);
      yg[(rbase + n) * 512 + col0 + wc + 16 + fr] = __float2bfloat16(acc2[mi][1][r]);
    }
}

// ---------------------------------------------------------------------------
// Fused prep: all 41 [512][512] weight transposes in one dispatch (z-mapped).
// ---------------------------------------------------------------------------
__global__ __launch_bounds__(256) void wconv_all_kernel(
    const float* __restrict__ bwq, const float* __restrict__ bwk,
    const float* __restrict__ bwv, const float* __restrict__ bwp,
    const float* __restrict__ bw1, const float* __restrict__ bw2,
    const float* __restrict__ wh1,
    __hip_bfloat16* __restrict__ wSelf, __hip_bfloat16* __restrict__ wCq,
    __hip_bfloat16* __restrict__ wCkv, __hip_bfloat16* __restrict__ wTp,
    __hip_bfloat16* __restrict__ wTw1, __hip_bfloat16* __restrict__ wTw2,
    __hip_bfloat16* __restrict__ wTh1) {
  const size_t MAT = (size_t)D * D;
  const size_t SS = (size_t)1536 * 512, KV = (size_t)1024 * 512;
  const int z = blockIdx.z;
  const float* src;
  __hip_bfloat16* dst;
  if (z < 8)       { int i = z >> 1; src = bwq + (size_t)z * MAT;
                     dst = (z & 1) ? wCq + (size_t)i * MAT : wSelf + (size_t)i * SS; }
  else if (z < 16) { int zz = z - 8, i = zz >> 1; src = bwk + (size_t)zz * MAT;
                     dst = (zz & 1) ? wCkv + (size_t)i * KV
                                    : wSelf + (size_t)i * SS + 512 * 512; }
  else if (z < 24) { int zz = z - 16, i = zz >> 1; src = bwv + (size_t)zz * MAT;
                     dst = (zz & 1) ? wCkv + (size_t)i * KV + 512 * 512
                                    : wSelf + (size_t)i * SS + 1024 * 512; }
  else if (z < 32) { int zz = z - 24; src = bwp + (size_t)zz * MAT; dst = wTp + (size_t)zz * MAT; }
  else if (z < 36) { int zz = z - 32; src = bw1 + (size_t)zz * MAT; dst = wTw1 + (size_t)zz * MAT; }
  else if (z < 40) { int zz = z - 36; src = bw2 + (size_t)zz * MAT; dst = wTw2 + (size_t)zz * MAT; }
  else             { src = wh1; dst = wTh1; }

  __shared__ float tile[32][33];
  const int r0 = blockIdx.y * 32, c0 = blockIdx.x * 32;
  const int tr = threadIdx.x >> 5;
  const int tc = threadIdx.x & 31;
#pragma unroll
  for (int i = 0; i < 4; ++i)
    tile[tr + 8 * i][tc] = src[(size_t)(r0 + tr + 8 * i) * D + c0 + tc];
  __syncthreads();
#pragma unroll
  for (int i = 0; i < 4; ++i)
    dst[(size_t)(c0 + tr + 8 * i) * D + r0 + tc] = __float2bfloat16(tile[tc][tr + 8 * i]);
}

// ---------------------------------------------------------------------------
// Fused misc prep: waeT pad-T, wh2 pad, bias packs, cross-q bias, action pad.
// ---------------------------------------------------------------------------
__global__ __launch_bounds__(256) void misc_prep_kernel(
    const float* __restrict__ w_ae, const float* __restrict__ wh2,
    const float* __restrict__ bbq, const float* __restrict__ bbk,
    const float* __restrict__ bbv, const float* __restrict__ action,
    __hip_bfloat16* __restrict__ waeT, __hip_bfloat16* __restrict__ wh2p,
    float* __restrict__ selfb, float* __restrict__ ckvb,
    float* __restrict__ bqc, __hip_bfloat16* __restrict__ actb) {
  constexpr int R0 = 512 * 96, R1 = 128 * 512, R2 = NBLK * 1536,
                R3 = NBLK * 1024, R4 = NBLK * 512, R5 = M * 96;
  constexpr int total = R0 + R1 + R2 + R3 + R4 + R5;
  for (int i = blockIdx.x * 256 + threadIdx.x; i < total; i += gridDim.x * 256) {
    int j = i;
    if (j < R0) {
      const int n = j / 96, k = j - n * 96;
      waeT[j] = (k < 65) ? __float2bfloat16(w_ae[(size_t)k * 512 + n]) : __float2bfloat16(0.f);
    } else if ((j -= R0) < R1) {
      const int n = j >> 9, k = j & 511;
      wh2p[j] = (n < 64) ? __float2bfloat16(wh2[(size_t)k * 64 + n]) : __float2bfloat16(0.f);
    } else if ((j -= R1) < R2) {
      const int blk = j / 1536, c = j - blk * 1536;
      const int seg = c >> 9, cc = c & 511;
      const float* s = (seg == 0) ? bbq : (seg == 1) ? bbk : bbv;
      selfb[j] = s[(size_t)(blk * 2) * 512 + cc];
    } else if ((j -= R2) < R3) {
      const int blk = j >> 10, c = j & 1023;
      ckvb[j] = (c < 512) ? bbk[(size_t)(blk * 2 + 1) * 512 + c]
                          : bbv[(size_t)(blk * 2 + 1) * 512 + (c - 512)];
    } else if ((j -= R3) < R4) {
      const int blk = j >> 9, c = j & 511;
      bqc[j] = bbq[(size_t)(blk * 2 + 1) * 512 + c];
    } else {
      j -= R4;
      const int row = j / 96, k = j - row * 96;
      actb[j] = (k < 65) ? __float2bfloat16(action[(size_t)row * 65 + k]) : __float2bfloat16(0.f);
    }
  }
}

// obs_rep fp32 -> bf16 (vectorized)
__global__ __launch_bounds__(256) void cvt_kernel(
    const float* __restrict__ src, __hip_bfloat16* __restrict__ dst, int n4) {
  const int i = blockIdx.x * 256 + threadIdx.x;
  if (i < n4) {
    const float4 v = reinterpret_cast<const float4*>(src)[i];
    ushort4 o;
    o.x = f2b_bits(v.x); o.y = f2b_bits(v.y);
    o.z = f2b_bits(v.z); o.w = f2b_bits(v.w);
    reinterpret_cast<ushort4*>(dst)[i] = o;
  }
}

}  // namespace

extern "C" void kernel_launch(void* const* d_in, const int* in_sizes, int n_in,
                              void* d_out, int out_size, void* d_ws, size_t ws_size,
                              hipStream_t stream) {
  const float* action  = (const float*)d_in[0];
  const float* obs_rep = (const float*)d_in[1];
  const float* w_ae    = (const float*)d_in[3];
  const float* ln0_g   = (const float*)d_in[4];
  const float* ln0_b   = (const float*)d_in[5];
  const float* bln_g   = (const float*)d_in[6];
  const float* bln_b   = (const float*)d_in[7];
  const float* bwq     = (const float*)d_in[8];
  const float* bwk     = (const float*)d_in[9];
  const float* bwv     = (const float*)d_in[10];
  const float* bwp     = (const float*)d_in[11];
  const float* bbq     = (const float*)d_in[12];
  const float* bbk     = (const float*)d_in[13];
  const float* bbv     = (const float*)d_in[14];
  const float* bbp     = (const float*)d_in[15];
  const float* bw1     = (const float*)d_in[16];
  const float* bb1     = (const float*)d_in[17];
  const float* bw2     = (const float*)d_in[18];
  const float* bb2     = (const float*)d_in[19];
  const float* wh1     = (const float*)d_in[20];
  const float* bh1     = (const float*)d_in[21];
  const float* lnh_g   = (const float*)d_in[22];
  const float* lnh_b   = (const float*)d_in[23];
  const float* wh2     = (const float*)d_in[24];
  const float* bh2     = (const float*)d_in[25];

  char* ws = (char*)d_ws;
  const size_t MAT = (size_t)D * D;
  const size_t szB = (size_t)M * D * 2;        // 16 MB

  __hip_bfloat16* xb  = (__hip_bfloat16*)ws; ws += szB;
  __hip_bfloat16* hb  = (__hip_bfloat16*)ws; ws += szB;
  __hip_bfloat16* vtb = (__hip_bfloat16*)ws; ws += szB;
  __hip_bfloat16* orb = (__hip_bfloat16*)ws; ws += szB;
  __hip_bfloat16* qkb = (__hip_bfloat16*)ws; ws += 2 * szB;  // [M][1024]
  __hip_bfloat16* qcb = (__hip_bfloat16*)ws; ws += 4 * szB;  // [M][2048] batched cross Q
  __hip_bfloat16* kb  = (__hip_bfloat16*)ws; ws += szB;      // [M][512] cross K
  __hip_bfloat16* actb = (__hip_bfloat16*)ws; ws += (size_t)M * 96 * 2;
  __hip_bfloat16* wSelf = (__hip_bfloat16*)ws; ws += (size_t)NBLK * 1536 * 512 * 2;
  __hip_bfloat16* wCq   = (__hip_bfloat16*)ws; ws += (size_t)NBLK * 512 * 512 * 2;   // [2048][512]
  __hip_bfloat16* wCkv  = (__hip_bfloat16*)ws; ws += (size_t)NBLK * 1024 * 512 * 2;
  __hip_bfloat16* wTp   = (__hip_bfloat16*)ws; ws += 8 * MAT * 2;
  __hip_bfloat16* wTw1  = (__hip_bfloat16*)ws; ws += 4 * MAT * 2;
  __hip_bfloat16* wTw2  = (__hip_bfloat16*)ws; ws += 4 * MAT * 2;
  __hip_bfloat16* wTh1  = (__hip_bfloat16*)ws; ws += MAT * 2;
  __hip_bfloat16* wh2p  = (__hip_bfloat16*)ws; ws += 128 * 512 * 2;
  __hip_bfloat16* waeT  = (__hip_bfloat16*)ws; ws += 512 * 96 * 2;
  float* selfb         = (float*)ws;         ws += (size_t)NBLK * 1536 * 4;
  float* ckvb          = (float*)ws;         ws += (size_t)NBLK * 1024 * 4;
  float* bqc           = (float*)ws;         ws += (size_t)NBLK * 512 * 4;

  // ---- prep: 3 dispatches ----
  wconv_all_kernel<<<dim3(16, 16, 41), 256, 0, stream>>>(
      bwq, bwk, bwv, bwp, bw1, bw2, wh1,
      wSelf, wCq, wCkv, wTp, wTw1, wTw2, wTh1);
  misc_prep_kernel<<<2048, 256, 0, stream>>>(
      w_ae, wh2, bbq, bbk, bbv, action, waeT, wh2p, selfb, ckvb, bqc, actb);
  cvt_kernel<<<(M * D / 4 + 255) / 256, 256, 0, stream>>>(obs_rep, orb, M * D / 4);

  const size_t SS = (size_t)1536 * 512;
  const size_t KV = (size_t)1024 * 512;
  const int lnGrid = M / 64;   // 256 blocks, 512 threads

  // ---- encoder: xb = LN(gelu(action @ w_ae)) ----
  gemm_ln_kernel<3, true, false><<<lnGrid, 512, 0, stream>>>(
      actb, waeT, nullptr, nullptr, ln0_g, ln0_b, xb);

  // ---- batched cross-attention Q for all 4 blocks: qcb[M][2048] ----
  gemm_dp_kernel<false, NEVER><<<M / 128 * 8, 512, 0, stream>>>(
      orb, wCq, bqc, qcb, 2048, nullptr, 8);

  for (int i = 0; i < NBLK; ++i) {
    const float* g0 = bln_g + (size_t)(i * 3 + 0) * D;
    const float* b0 = bln_b + (size_t)(i * 3 + 0) * D;
    const float* g1 = bln_g + (size_t)(i * 3 + 1) * D;
    const float* b1 = bln_b + (size_t)(i * 3 + 1) * D;
    const float* g2 = bln_g + (size_t)(i * 3 + 2) * D;
    const float* b2 = bln_b + (size_t)(i * 3 + 2) * D;

    // ---- sublayer 1: self-attention ----
    gemm_dp_kernel<false, 1024><<<M / 128 * 6, 512, 0, stream>>>(
        xb, wSelf + (size_t)i * SS, selfb + (size_t)i * 1536, qkb, 1024, vtb, 6);
    attn_mfma_kernel<<<B * H, 256, 0, stream>>>(qkb, 1024, qkb + 512, 1024, vtb, hb);
    gemm_ln_kernel<16, false, true><<<lnGrid, 512, 0, stream>>>(
        hb, wTp + (size_t)(i * 2) * MAT, bbp + (size_t)(i * 2) * D, xb, g0, b0, xb);

    // ---- sublayer 2: cross-attention ----
    gemm_dp_kernel<false, 512><<<M / 128 * 4, 512, 0, stream>>>(
        xb, wCkv + (size_t)i * KV, ckvb + (size_t)i * 1024, kb, 512, vtb, 4);
    attn_mfma_kernel<<<B * H, 256, 0, stream>>>(
        qcb + (size_t)i * 512, 2048, kb, 512, vtb, hb);
    gemm_ln_kernel<16, false, true><<<lnGrid, 512, 0, stream>>>(
        hb, wTp + (size_t)(i * 2 + 1) * MAT, bbp + (size_t)(i * 2 + 1) * D,
        orb, g1, b1, xb);

    // ---- sublayer 3: MLP ----
    gemm_dp_kernel<true, NEVER><<<M / 128 * 2, 512, 0, stream>>>(
        xb, wTw1 + (size_t)i * MAT, bb1 + (size_t)i * D, hb, 512, nullptr, 2);
    gemm_ln_kernel<16, false, true><<<lnGrid, 512, 0, stream>>>(
        hb, wTw2 + (size_t)i * MAT, bb2 + (size_t)i * D, xb, g2, b2, xb);
  }

  // ---- head ----
  gemm_ln_kernel<16, true, false><<<lnGrid, 512, 0, stream>>>(
      xb, wTh1, bh1, nullptr, lnh_g, lnh_b, hb);
  gemm_head_kernel<16><<<dim3(M / 128, 1), 256, 0, stream>>>(
      hb, wh2p, bh2, (float*)d_out, 64, 64);
}

// Round 7
// 1020.979 us; speedup vs baseline: 11.7025x; 1.0175x over previous
//
#include <hip/hip_runtime.h>
#include <hip/hip_bf16.h>
#include <math.h>

namespace {

constexpr int B  = 256;
constexpr int N  = 64;
constexpr int D  = 512;
constexpr int H  = 8;
constexpr int NBLK = 4;
constexpr int M  = B * N;
constexpr float EPS = 1e-5f;
constexpr float SCALE = 0.125f;
constexpr int NEVER = 1 << 20;

typedef __attribute__((ext_vector_type(8))) short short8b;
typedef __attribute__((ext_vector_type(4))) float f32x4;

__device__ __forceinline__ float gelu_exact(float x) {
  return 0.5f * x * (1.0f + erff(x * 0.70710678118654752440f));
}

__device__ __forceinline__ unsigned short f2b_bits(float f) {
  __hip_bfloat16 h = __float2bfloat16(f);
  return *reinterpret_cast<unsigned short*>(&h);
}

#define GLOBAL_AS __attribute__((address_space(1)))
#define LDS_AS    __attribute__((address_space(3)))

__device__ __forceinline__ void gload_lds16(const void* g, void* l) {
  __builtin_amdgcn_global_load_lds((const GLOBAL_AS void*)g, (LDS_AS void*)l, 16, 0, 0);
}

// ---------------------------------------------------------------------------
// Deep-pipelined bf16 MFMA GEMM (unchanged from R5/R6; proven).
// ---------------------------------------------------------------------------
template<bool GELU, int SPLIT>
__global__ __launch_bounds__(512, 2) void gemm_dp_kernel(
    const __hip_bfloat16* __restrict__ A,
    const __hip_bfloat16* __restrict__ Wt,
    const float* __restrict__ bias,
    __hip_bfloat16* __restrict__ out1, int ostr1,
    __hip_bfloat16* __restrict__ vt, int gy) {
  constexpr int K = 512;
  constexpr int NT = 8;
  __shared__ __hip_bfloat16 Als[3][128][64];
  __shared__ __hip_bfloat16 Bls[3][256][64];

  const int nwg = gridDim.x;
  const int hw  = blockIdx.x;
  const int cpx = nwg >> 3;
  const int lg  = (hw & 7) * cpx + (hw >> 3);
  const int bm  = (lg / gy) * 128;
  const int bn  = (lg % gy) * 256;

  const int tid  = threadIdx.x;
  const int wave = tid >> 6;
  const int lane = tid & 63;
  const int wm   = (wave >> 2) * 64;
  const int wn   = (wave & 3) * 64;
  const int fr   = lane & 15;
  const int fg   = lane >> 4;

  const int srow  = tid >> 3;
  const int sslot = (tid & 7) ^ (srow & 7);
  const __hip_bfloat16* gA = A  + (size_t)(bm + srow) * K + sslot * 8;
  const __hip_bfloat16* gB = Wt + (size_t)(bn + srow) * K + sslot * 8;

  auto STAGE = [&](int buf, int kt) {
    const int ko = kt * 64;
    char* la = (char*)&Als[buf][0][0] + wave * 1024;
    char* lb = (char*)&Bls[buf][0][0] + wave * 1024;
    gload_lds16(gA + ko,           la);
    gload_lds16(gA + 64 * K + ko,  la + 8192);
    gload_lds16(gB + ko,           lb);
    gload_lds16(gB + 64 * K + ko,  lb + 8192);
    gload_lds16(gB + 128 * K + ko, lb + 16384);
    gload_lds16(gB + 192 * K + ko, lb + 24576);
  };

  auto lda = [&](int buf, int mi, int ks) -> short8b {
    const int row  = wm + mi * 16 + fr;
    const int byte = row * 128 + (((ks << 2) | fg) ^ (fr & 7)) * 16;
    return *reinterpret_cast<const short8b*>((const char*)&Als[buf][0][0] + byte);
  };
  auto ldb = [&](int buf, int ni, int ks) -> short8b {
    const int row  = wn + ni * 16 + fr;
    const int byte = row * 128 + (((ks << 2) | fg) ^ (fr & 7)) * 16;
    return *reinterpret_cast<const short8b*>((const char*)&Bls[buf][0][0] + byte);
  };

  STAGE(0, 0);
  STAGE(1, 1);
  asm volatile("s_waitcnt vmcnt(6)" ::: "memory");
  __builtin_amdgcn_sched_barrier(0);
  __builtin_amdgcn_s_barrier();
  __builtin_amdgcn_sched_barrier(0);

  f32x4 acc[4][4] = {};
  for (int t = 0; t < NT; ++t) {
    const int cur = t % 3;
    if (t + 2 < NT) STAGE((t + 2) % 3, t + 2);

    short8b a0[4], b0[4], a1[4], b1[4];
#pragma unroll
    for (int mi = 0; mi < 4; ++mi) a0[mi] = lda(cur, mi, 0);
#pragma unroll
    for (int ni = 0; ni < 4; ++ni) b0[ni] = ldb(cur, ni, 0);
#pragma unroll
    for (int mi = 0; mi < 4; ++mi) a1[mi] = lda(cur, mi, 1);
#pragma unroll
    for (int ni = 0; ni < 4; ++ni) b1[ni] = ldb(cur, ni, 1);

    __builtin_amdgcn_s_setprio(1);
#pragma unroll
    for (int mi = 0; mi < 4; ++mi)
#pragma unroll
      for (int ni = 0; ni < 4; ++ni)
        acc[mi][ni] = __builtin_amdgcn_mfma_f32_16x16x32_bf16(a0[mi], b0[ni], acc[mi][ni], 0, 0, 0);
#pragma unroll
    for (int mi = 0; mi < 4; ++mi)
#pragma unroll
      for (int ni = 0; ni < 4; ++ni)
        acc[mi][ni] = __builtin_amdgcn_mfma_f32_16x16x32_bf16(a1[mi], b1[ni], acc[mi][ni], 0, 0, 0);
    __builtin_amdgcn_s_setprio(0);

    if (t + 2 < NT) {
      asm volatile("s_waitcnt vmcnt(6)" ::: "memory");
    } else {
      asm volatile("s_waitcnt vmcnt(0)" ::: "memory");
    }
    __builtin_amdgcn_sched_barrier(0);
    __builtin_amdgcn_s_barrier();
    __builtin_amdgcn_sched_barrier(0);
  }

#pragma unroll
  for (int ni = 0; ni < 4; ++ni) {
    const int col = bn + wn + ni * 16 + fr;
    const float bv = bias ? bias[col] : 0.f;
#pragma unroll
    for (int mi = 0; mi < 4; ++mi) {
      const int row0 = bm + wm + mi * 16 + fg * 4;
      if (col >= SPLIT) {
        const int vcol = col - SPLIT;
        ushort4 o;
        o.x = f2b_bits(acc[mi][ni][0] + bv);
        o.y = f2b_bits(acc[mi][ni][1] + bv);
        o.z = f2b_bits(acc[mi][ni][2] + bv);
        o.w = f2b_bits(acc[mi][ni][3] + bv);
        const int b8 = row0 >> 6, nl = row0 & 63;
        const int hh = vcol >> 6, dl = vcol & 63;
        *reinterpret_cast<ushort4*>(vt +
            ((size_t)(b8 * 8 + hh) * 4096 + dl * 64 + nl)) = o;
      } else {
#pragma unroll
        for (int q = 0; q < 4; ++q) {
          float v = acc[mi][ni][q] + bv;
          if (GELU) v = gelu_exact(v);
          out1[(size_t)(row0 + q) * ostr1 + col] = __float2bfloat16(v);
        }
      }
    }
  }
}

// ---------------------------------------------------------------------------
// GEMM + bias (+GELU) + bf16 residual + LN, BK=64 swizzled (K=512 only).
// BM=64 x BN=512 full width, 512 threads, 8 K-tiles.
// ---------------------------------------------------------------------------
template<bool GELU_PRE, bool RES>
__global__ __launch_bounds__(512) void gemm_ln64_kernel(
    const __hip_bfloat16* __restrict__ A,
    const __hip_bfloat16* __restrict__ Wt,
    const float* __restrict__ bias,
    const __hip_bfloat16* __restrict__ resb,
    const float* __restrict__ g, const float* __restrict__ bb,
    __hip_bfloat16* __restrict__ outB) {
  __shared__ __hip_bfloat16 Als[2][64][64];     // 16 KB
  __shared__ __hip_bfloat16 Bls[2][512][64];    // 128 KB
  __shared__ float red[64][8];
  __shared__ float mrow[64];
  __shared__ float rrow[64];

  const int bm   = blockIdx.x * 64;
  const int tid  = threadIdx.x;
  const int wave = tid >> 6;
  const int lane = tid & 63;
  const int fr   = lane & 15;
  const int fg   = lane >> 4;

  const int srow  = tid >> 3;            // 0..63
  const int sslot = (tid & 7) ^ (srow & 7);

  auto stage = [&](int buf, int kt) {
    const int ko = kt * 64;
    gload_lds16(A + (size_t)(bm + srow) * 512 + ko + sslot * 8,
                (char*)&Als[buf][0][0] + wave * 1024);
#pragma unroll
    for (int j = 0; j < 8; ++j) {
      const int row = j * 64 + srow;
      const int sl  = (tid & 7) ^ (row & 7);
      gload_lds16(Wt + (size_t)row * 512 + ko + sl * 8,
                  (char*)&Bls[buf][0][0] + j * 8192 + wave * 1024);
    }
  };

  auto lda = [&](int buf, int mi, int ks) -> short8b {
    const int row  = mi * 16 + fr;
    const int byte = row * 128 + (((ks << 2) | fg) ^ (row & 7)) * 16;
    return *reinterpret_cast<const short8b*>((const char*)&Als[buf][0][0] + byte);
  };
  auto ldb = [&](int buf, int ni, int ks) -> short8b {
    const int row  = wave * 64 + ni * 16 + fr;
    const int byte = row * 128 + (((ks << 2) | fg) ^ (row & 7)) * 16;
    return *reinterpret_cast<const short8b*>((const char*)&Bls[buf][0][0] + byte);
  };

  f32x4 acc[4][4] = {};
  stage(0, 0);
  int buf = 0;
  for (int kt = 0; kt < 8; ++kt) {
    __syncthreads();
    if (kt + 1 < 8) stage(buf ^ 1, kt + 1);
    short8b a0[4], b0[4], a1[4], b1[4];
#pragma unroll
    for (int mi = 0; mi < 4; ++mi) a0[mi] = lda(buf, mi, 0);
#pragma unroll
    for (int ni = 0; ni < 4; ++ni) b0[ni] = ldb(buf, ni, 0);
#pragma unroll
    for (int mi = 0; mi < 4; ++mi) a1[mi] = lda(buf, mi, 1);
#pragma unroll
    for (int ni = 0; ni < 4; ++ni) b1[ni] = ldb(buf, ni, 1);
    __builtin_amdgcn_s_setprio(1);
#pragma unroll
    for (int mi = 0; mi < 4; ++mi)
#pragma unroll
      for (int ni = 0; ni < 4; ++ni)
        acc[mi][ni] = __builtin_amdgcn_mfma_f32_16x16x32_bf16(a0[mi], b0[ni], acc[mi][ni], 0, 0, 0);
#pragma unroll
    for (int mi = 0; mi < 4; ++mi)
#pragma unroll
      for (int ni = 0; ni < 4; ++ni)
        acc[mi][ni] = __builtin_amdgcn_mfma_f32_16x16x32_bf16(a1[mi], b1[ni], acc[mi][ni], 0, 0, 0);
    __builtin_amdgcn_s_setprio(0);
    buf ^= 1;
  }

  // epilogue: bias (+gelu) (+res) + LN -> bf16
  float v[4][4][4];
  float bvc[4];
#pragma unroll
  for (int ni = 0; ni < 4; ++ni)
    bvc[ni] = bias ? bias[wave * 64 + ni * 16 + fr] : 0.f;
#pragma unroll
  for (int mi = 0; mi < 4; ++mi)
#pragma unroll
    for (int q = 0; q < 4; ++q) {
      const int row = bm + mi * 16 + fg * 4 + q;
#pragma unroll
      for (int ni = 0; ni < 4; ++ni) {
        float t = acc[mi][ni][q] + bvc[ni];
        if (GELU_PRE) t = gelu_exact(t);
        if (RES)
          t += __bfloat162float(resb[(size_t)row * D + wave * 64 + ni * 16 + fr]);
        v[mi][ni][q] = t;
      }
    }

  float ps[16];
#pragma unroll
  for (int mi = 0; mi < 4; ++mi)
#pragma unroll
    for (int q = 0; q < 4; ++q)
      ps[mi * 4 + q] = v[mi][0][q] + v[mi][1][q] + v[mi][2][q] + v[mi][3][q];
#pragma unroll
  for (int mask = 1; mask < 16; mask <<= 1)
#pragma unroll
    for (int t = 0; t < 16; ++t) ps[t] += __shfl_xor(ps[t], mask);
  if (fr == 0) {
#pragma unroll
    for (int mi = 0; mi < 4; ++mi)
#pragma unroll
      for (int q = 0; q < 4; ++q)
        red[mi * 16 + fg * 4 + q][wave] = ps[mi * 4 + q];
  }
  __syncthreads();
  if (tid < 64) {
    float s = 0.f;
#pragma unroll
    for (int w = 0; w < 8; ++w) s += red[tid][w];
    mrow[tid] = s * (1.f / 512.f);
  }
  __syncthreads();
  float mu[16];
#pragma unroll
  for (int mi = 0; mi < 4; ++mi)
#pragma unroll
    for (int q = 0; q < 4; ++q) mu[mi * 4 + q] = mrow[mi * 16 + fg * 4 + q];

  float ps2[16];
#pragma unroll
  for (int mi = 0; mi < 4; ++mi)
#pragma unroll
    for (int q = 0; q < 4; ++q) {
      const float m = mu[mi * 4 + q];
      float s = 0.f;
#pragma unroll
      for (int ni = 0; ni < 4; ++ni) {
        const float d = v[mi][ni][q] - m;
        s += d * d;
      }
      ps2[mi * 4 + q] = s;
    }
#pragma unroll
  for (int mask = 1; mask < 16; mask <<= 1)
#pragma unroll
    for (int t = 0; t < 16; ++t) ps2[t] += __shfl_xor(ps2[t], mask);
  if (fr == 0) {
#pragma unroll
    for (int mi = 0; mi < 4; ++mi)
#pragma unroll
      for (int q = 0; q < 4; ++q)
        red[mi * 16 + fg * 4 + q][wave] = ps2[mi * 4 + q];
  }
  __syncthreads();
  if (tid < 64) {
    float s = 0.f;
#pragma unroll
    for (int w = 0; w < 8; ++w) s += red[tid][w];
    rrow[tid] = rsqrtf(s * (1.f / 512.f) + EPS);
  }
  __syncthreads();

#pragma unroll
  for (int ni = 0; ni < 4; ++ni) {
    const int col = wave * 64 + ni * 16 + fr;
    const float gc = g[col], bc = bb[col];
#pragma unroll
    for (int mi = 0; mi < 4; ++mi)
#pragma unroll
      for (int q = 0; q < 4; ++q) {
        const int lrow = mi * 16 + fg * 4 + q;
        const float o = (v[mi][ni][q] - mu[mi * 4 + q]) * rrow[lrow] * gc + bc;
        outB[(size_t)(bm + lrow) * D + col] = __float2bfloat16(o);
      }
  }
}

// ---------------------------------------------------------------------------
// Fused double-GEMM:
// MODE 0 (MLP):  mid = gelu(A@W1t + b1) in LDS; out = LN(mid@W2t + b2 + res)
// MODE 1 (head): mid = LN(gelu(A@W1t + b1)) in LDS; d_out = mid@W2t + b2 (f32)
// BM=64 x full width, 512 threads, BK=32.
// ---------------------------------------------------------------------------
template<int MODE>
__global__ __launch_bounds__(512) void fused2_kernel(
    const __hip_bfloat16* __restrict__ A,
    const __hip_bfloat16* __restrict__ W1t, const float* __restrict__ b1,
    const __hip_bfloat16* __restrict__ W2t, const float* __restrict__ b2,
    const __hip_bfloat16* __restrict__ resb,
    const float* __restrict__ g, const float* __restrict__ bb,
    __hip_bfloat16* __restrict__ outB, float* __restrict__ outF) {
  __shared__ __hip_bfloat16 Als[2][64][32];     // 8 KB
  __shared__ __hip_bfloat16 Bls[2][512][32];    // 64 KB (shared GEMM1/GEMM2)
  __shared__ __hip_bfloat16 mid[64 * 512];      // 64 KB swizzled
  __shared__ float red[64][8];
  __shared__ float mrow[64];
  __shared__ float rrow[64];

  const int bm   = blockIdx.x * 64;
  const int tid  = threadIdx.x;
  const int wave = tid >> 6;
  const int lane = tid & 63;
  const int fr   = lane & 15;
  const int fg   = lane >> 4;

  auto stageA = [&](int buf, int ks) {
    if (wave < 4) {
      const int row = wave * 16 + (lane >> 2);
      const int sl  = (lane & 3) ^ (row & 3);
      gload_lds16(A + (size_t)(bm + row) * 512 + ks * 32 + sl * 8,
                  (char*)&Als[buf][0][0] + wave * 1024);
    }
  };
  auto stageB = [&](const __hip_bfloat16* W, int buf, int ks) {
#pragma unroll
    for (int c = 0; c < 4; ++c) {
      const int row = wave * 64 + c * 16 + (lane >> 2);
      const int sl  = (lane & 3) ^ (row & 3);
      gload_lds16(W + (size_t)row * 512 + ks * 32 + sl * 8,
                  (char*)&Bls[buf][0][0] + (wave * 64 + c * 16) * 64);
    }
  };
  // MODE1 GEMM2 B: only 128 rows (wh2p), one load/thread.
  auto stageB2h = [&](const __hip_bfloat16* W, int buf, int ks) {
    const int row = (tid >> 2) & 127;
    const int sl  = (tid & 3) ^ (row & 3);
    gload_lds16(W + (size_t)row * 512 + ks * 32 + sl * 8,
                (char*)&Bls[buf][0][0] + wave * 1024);
  };

  auto ldA = [&](int buf, int mi) -> short8b {
    const int row  = mi * 16 + fr;
    const int byte = row * 64 + (fg ^ (row & 3)) * 16;
    return *reinterpret_cast<const short8b*>((const char*)&Als[buf][0][0] + byte);
  };
  auto ldB = [&](int buf, int row) -> short8b {
    const int byte = row * 64 + (fg ^ (row & 3)) * 16;
    return *reinterpret_cast<const short8b*>((const char*)&Bls[buf][0][0] + byte);
  };
  auto ldMid = [&](int mi, int ks) -> short8b {
    const int row  = mi * 16 + fr;
    const int byte = (row * 1024 + ks * 64 + fg * 16) ^ ((row & 7) << 4);
    return *reinterpret_cast<const short8b*>((const char*)mid + byte);
  };

  // ---------------- GEMM1: A @ W1t ----------------
  f32x4 acc[4][4] = {};
  stageA(0, 0); stageB(W1t, 0, 0);
  int buf = 0;
  for (int ks = 0; ks < 16; ++ks) {
    __syncthreads();
    if (ks + 1 < 16) { stageA(buf ^ 1, ks + 1); stageB(W1t, buf ^ 1, ks + 1); }
    short8b a[4], b[4];
#pragma unroll
    for (int mi = 0; mi < 4; ++mi) a[mi] = ldA(buf, mi);
#pragma unroll
    for (int ni = 0; ni < 4; ++ni) b[ni] = ldB(buf, wave * 64 + ni * 16 + fr);
#pragma unroll
    for (int mi = 0; mi < 4; ++mi)
#pragma unroll
      for (int ni = 0; ni < 4; ++ni)
        acc[mi][ni] = __builtin_amdgcn_mfma_f32_16x16x32_bf16(a[mi], b[ni], acc[mi][ni], 0, 0, 0);
    buf ^= 1;
  }

  // stage GEMM2's first tile early (Bls[0] free: last read was step 14)
  if (MODE == 0) stageB(W2t, 0, 0); else stageB2h(W2t, 0, 0);

  // ---------------- epilogue1 -> mid ----------------
  {
    float v[4][4][4];
    float bvc[4];
#pragma unroll
    for (int ni = 0; ni < 4; ++ni)
      bvc[ni] = b1[wave * 64 + ni * 16 + fr];
#pragma unroll
    for (int mi = 0; mi < 4; ++mi)
#pragma unroll
      for (int q = 0; q < 4; ++q)
#pragma unroll
        for (int ni = 0; ni < 4; ++ni)
          v[mi][ni][q] = gelu_exact(acc[mi][ni][q] + bvc[ni]);

    if (MODE == 1) {
      // LN over v before writing mid
      float ps[16];
#pragma unroll
      for (int mi = 0; mi < 4; ++mi)
#pragma unroll
        for (int q = 0; q < 4; ++q)
          ps[mi * 4 + q] = v[mi][0][q] + v[mi][1][q] + v[mi][2][q] + v[mi][3][q];
#pragma unroll
      for (int mask = 1; mask < 16; mask <<= 1)
#pragma unroll
        for (int t = 0; t < 16; ++t) ps[t] += __shfl_xor(ps[t], mask);
      if (fr == 0)
#pragma unroll
        for (int mi = 0; mi < 4; ++mi)
#pragma unroll
          for (int q = 0; q < 4; ++q)
            red[mi * 16 + fg * 4 + q][wave] = ps[mi * 4 + q];
      __syncthreads();
      if (tid < 64) {
        float s = 0.f;
#pragma unroll
        for (int w = 0; w < 8; ++w) s += red[tid][w];
        mrow[tid] = s * (1.f / 512.f);
      }
      __syncthreads();
      float mu[16];
#pragma unroll
      for (int mi = 0; mi < 4; ++mi)
#pragma unroll
        for (int q = 0; q < 4; ++q) mu[mi * 4 + q] = mrow[mi * 16 + fg * 4 + q];
      float ps2[16];
#pragma unroll
      for (int mi = 0; mi < 4; ++mi)
#pragma unroll
        for (int q = 0; q < 4; ++q) {
          const float m = mu[mi * 4 + q];
          float s = 0.f;
#pragma unroll
          for (int ni = 0; ni < 4; ++ni) { const float d = v[mi][ni][q] - m; s += d * d; }
          ps2[mi * 4 + q] = s;
        }
#pragma unroll
      for (int mask = 1; mask < 16; mask <<= 1)
#pragma unroll
        for (int t = 0; t < 16; ++t) ps2[t] += __shfl_xor(ps2[t], mask);
      if (fr == 0)
#pragma unroll
        for (int mi = 0; mi < 4; ++mi)
#pragma unroll
          for (int q = 0; q < 4; ++q)
            red[mi * 16 + fg * 4 + q][wave] = ps2[mi * 4 + q];
      __syncthreads();
      if (tid < 64) {
        float s = 0.f;
#pragma unroll
        for (int w = 0; w < 8; ++w) s += red[tid][w];
        rrow[tid] = rsqrtf(s * (1.f / 512.f) + EPS);
      }
      __syncthreads();
#pragma unroll
      for (int mi = 0; mi < 4; ++mi)
#pragma unroll
        for (int q = 0; q < 4; ++q) {
          const int lrow = mi * 16 + fg * 4 + q;
#pragma unroll
          for (int ni = 0; ni < 4; ++ni) {
            const int col = wave * 64 + ni * 16 + fr;
            v[mi][ni][q] = (v[mi][ni][q] - mu[mi * 4 + q]) * rrow[lrow] * g[col] + bb[col];
          }
        }
    }

    // write mid (swizzled)
#pragma unroll
    for (int mi = 0; mi < 4; ++mi)
#pragma unroll
      for (int q = 0; q < 4; ++q) {
        const int row = mi * 16 + fg * 4 + q;
#pragma unroll
        for (int ni = 0; ni < 4; ++ni) {
          const int col = wave * 64 + ni * 16 + fr;
          const int byte = (row * 1024 + col * 2) ^ ((row & 7) << 4);
          *(unsigned short*)((char*)mid + byte) = f2b_bits(v[mi][ni][q]);
        }
      }
  }
  __syncthreads();

  // ---------------- GEMM2: mid @ W2t ----------------
  if (MODE == 0) {
    f32x4 acc2[4][4] = {};
    int buf2 = 0;
    for (int ks = 0; ks < 16; ++ks) {
      if (ks) __syncthreads();
      if (ks + 1 < 16) stageB(W2t, buf2 ^ 1, ks + 1);
      short8b a[4], b[4];
#pragma unroll
      for (int mi = 0; mi < 4; ++mi) a[mi] = ldMid(mi, ks);
#pragma unroll
      for (int ni = 0; ni < 4; ++ni) b[ni] = ldB(buf2, wave * 64 + ni * 16 + fr);
#pragma unroll
      for (int mi = 0; mi < 4; ++mi)
#pragma unroll
        for (int ni = 0; ni < 4; ++ni)
          acc2[mi][ni] = __builtin_amdgcn_mfma_f32_16x16x32_bf16(a[mi], b[ni], acc2[mi][ni], 0, 0, 0);
      buf2 ^= 1;
    }
    __syncthreads();

    // epilogue2: bias + residual + LN -> outB
    float v[4][4][4];
    float bvc[4];
#pragma unroll
    for (int ni = 0; ni < 4; ++ni)
      bvc[ni] = b2[wave * 64 + ni * 16 + fr];
#pragma unroll
    for (int mi = 0; mi < 4; ++mi)
#pragma unroll
      for (int q = 0; q < 4; ++q) {
        const int row = bm + mi * 16 + fg * 4 + q;
#pragma unroll
        for (int ni = 0; ni < 4; ++ni)
          v[mi][ni][q] = acc2[mi][ni][q] + bvc[ni] +
              __bfloat162float(resb[(size_t)row * D + wave * 64 + ni * 16 + fr]);
      }

    float ps[16];
#pragma unroll
    for (int mi = 0; mi < 4; ++mi)
#pragma unroll
      for (int q = 0; q < 4; ++q)
        ps[mi * 4 + q] = v[mi][0][q] + v[mi][1][q] + v[mi][2][q] + v[mi][3][q];
#pragma unroll
    for (int mask = 1; mask < 16; mask <<= 1)
#pragma unroll
      for (int t = 0; t < 16; ++t) ps[t] += __shfl_xor(ps[t], mask);
    if (fr == 0)
#pragma unroll
      for (int mi = 0; mi < 4; ++mi)
#pragma unroll
        for (int q = 0; q < 4; ++q)
          red[mi * 16 + fg * 4 + q][wave] = ps[mi * 4 + q];
    __syncthreads();
    if (tid < 64) {
      float s = 0.f;
#pragma unroll
      for (int w = 0; w < 8; ++w) s += red[tid][w];
      mrow[tid] = s * (1.f / 512.f);
    }
    __syncthreads();
    float mu[16];
#pragma unroll
    for (int mi = 0; mi < 4; ++mi)
#pragma unroll
      for (int q = 0; q < 4; ++q) mu[mi * 4 + q] = mrow[mi * 16 + fg * 4 + q];
    float ps2[16];
#pragma unroll
    for (int mi = 0; mi < 4; ++mi)
#pragma unroll
      for (int q = 0; q < 4; ++q) {
        const float m = mu[mi * 4 + q];
        float s = 0.f;
#pragma unroll
        for (int ni = 0; ni < 4; ++ni) { const float d = v[mi][ni][q] - m; s += d * d; }
        ps2[mi * 4 + q] = s;
      }
#pragma unroll
    for (int mask = 1; mask < 16; mask <<= 1)
#pragma unroll
      for (int t = 0; t < 16; ++t) ps2[t] += __shfl_xor(ps2[t], mask);
    if (fr == 0)
#pragma unroll
      for (int mi = 0; mi < 4; ++mi)
#pragma unroll
        for (int q = 0; q < 4; ++q)
          red[mi * 16 + fg * 4 + q][wave] = ps2[mi * 4 + q];
    __syncthreads();
    if (tid < 64) {
      float s = 0.f;
#pragma unroll
      for (int w = 0; w < 8; ++w) s += red[tid][w];
      rrow[tid] = rsqrtf(s * (1.f / 512.f) + EPS);
    }
    __syncthreads();

#pragma unroll
    for (int ni = 0; ni < 4; ++ni) {
      const int col = wave * 64 + ni * 16 + fr;
      const float gc = g[col], bc = bb[col];
#pragma unroll
      for (int mi = 0; mi < 4; ++mi)
#pragma unroll
        for (int q = 0; q < 4; ++q) {
          const int lrow = mi * 16 + fg * 4 + q;
          const float o = (v[mi][ni][q] - mu[mi * 4 + q]) * rrow[lrow] * gc + bc;
          outB[(size_t)(bm + lrow) * D + col] = __float2bfloat16(o);
        }
    }
  } else {
    // MODE 1: logits = mid @ wh2p + bh2, N=64 f32 out.
    const int mi = wave >> 1;               // 0..3
    const int nb = (wave & 1) * 2;          // 0 or 2
    f32x4 acc2[2] = {};
    int buf2 = 0;
    for (int ks = 0; ks < 16; ++ks) {
      if (ks) __syncthreads();
      if (ks + 1 < 16) stageB2h(W2t, buf2 ^ 1, ks + 1);
      short8b a = ldMid(mi, ks);
      short8b b0 = ldB(buf2, (nb + 0) * 16 + fr);
      short8b b1 = ldB(buf2, (nb + 1) * 16 + fr);
      acc2[0] = __builtin_amdgcn_mfma_f32_16x16x32_bf16(a, b0, acc2[0], 0, 0, 0);
      acc2[1] = __builtin_amdgcn_mfma_f32_16x16x32_bf16(a, b1, acc2[1], 0, 0, 0);
      buf2 ^= 1;
    }
#pragma unroll
    for (int j = 0; j < 2; ++j) {
      const int col = (nb + j) * 16 + fr;
      const float bv = b2[col];
#pragma unroll
      for (int q = 0; q < 4; ++q) {
        const int row = bm + mi * 16 + fg * 4 + q;
        outF[(size_t)row * 64 + col] = acc2[j][q] + bv;
      }
    }
  }
}

// ---------------------------------------------------------------------------
// Encoder GEMM+GELU+LN (K=96, BK=32) — unchanged proven kernel.
// ---------------------------------------------------------------------------
__global__ __launch_bounds__(512) void gemm_ln_enc_kernel(
    const __hip_bfloat16* __restrict__ A,
    const __hip_bfloat16* __restrict__ Wt,
    const float* __restrict__ g, const float* __restrict__ bb,
    __hip_bfloat16* __restrict__ outB) {
  constexpr int K = 96;
  __shared__ __hip_bfloat16 Als[2][64][32];
  __shared__ __hip_bfloat16 Bls[2][512][32];
  __shared__ float red[64][8];
  __shared__ float mrow[64];
  __shared__ float rrow[64];

  const int bm   = blockIdx.x * 64;
  const int tid  = threadIdx.x;
  const int wave = tid >> 6;
  const int lane = tid & 63;
  const int fr   = lane & 15;
  const int fg   = lane >> 4;
  const int srow = lane >> 2;
  const int scol = (lane & 3) * 8;

  auto stage = [&](int buf, int ks) {
    const int ko = ks * 32;
    if (wave < 4)
      gload_lds16(A + (size_t)(bm + wave * 16 + srow) * K + ko + scol,
                  &Als[buf][wave * 16][0]);
#pragma unroll
    for (int c = 0; c < 4; ++c)
      gload_lds16(Wt + (size_t)(wave * 64 + c * 16 + srow) * K + ko + scol,
                  &Bls[buf][wave * 64 + c * 16][0]);
  };

  f32x4 acc[4][4] = {};
  stage(0, 0);
  int buf = 0;
  for (int ks = 0; ks < 3; ++ks) {
    __syncthreads();
    if (ks + 1 < 3) stage(buf ^ 1, ks + 1);
    short8b a[4], b[4];
#pragma unroll
    for (int mi = 0; mi < 4; ++mi)
      a[mi] = *reinterpret_cast<const short8b*>(&Als[buf][mi * 16 + fr][fg * 8]);
#pragma unroll
    for (int ni = 0; ni < 4; ++ni)
      b[ni] = *reinterpret_cast<const short8b*>(&Bls[buf][wave * 64 + ni * 16 + fr][fg * 8]);
#pragma unroll
    for (int mi = 0; mi < 4; ++mi)
#pragma unroll
      for (int ni = 0; ni < 4; ++ni)
        acc[mi][ni] = __builtin_amdgcn_mfma_f32_16x16x32_bf16(a[mi], b[ni], acc[mi][ni], 0, 0, 0);
    buf ^= 1;
  }

  float v[4][4][4];
#pragma unroll
  for (int mi = 0; mi < 4; ++mi)
#pragma unroll
    for (int q = 0; q < 4; ++q)
#pragma unroll
      for (int ni = 0; ni < 4; ++ni)
        v[mi][ni][q] = gelu_exact(acc[mi][ni][q]);

  float ps[16];
#pragma unroll
  for (int mi = 0; mi < 4; ++mi)
#pragma unroll
    for (int q = 0; q < 4; ++q)
      ps[mi * 4 + q] = v[mi][0][q] + v[mi][1][q] + v[mi][2][q] + v[mi][3][q];
#pragma unroll
  for (int mask = 1; mask < 16; mask <<= 1)
#pragma unroll
    for (int t = 0; t < 16; ++t) ps[t] += __shfl_xor(ps[t], mask);
  if (fr == 0)
#pragma unroll
    for (int mi = 0; mi < 4; ++mi)
#pragma unroll
      for (int q = 0; q < 4; ++q)
        red[mi * 16 + fg * 4 + q][wave] = ps[mi * 4 + q];
  __syncthreads();
  if (tid < 64) {
    float s = 0.f;
#pragma unroll
    for (int w = 0; w < 8; ++w) s += red[tid][w];
    mrow[tid] = s * (1.f / 512.f);
  }
  __syncthreads();
  float mu[16];
#pragma unroll
  for (int mi = 0; mi < 4; ++mi)
#pragma unroll
    for (int q = 0; q < 4; ++q) mu[mi * 4 + q] = mrow[mi * 16 + fg * 4 + q];
  float ps2[16];
#pragma unroll
  for (int mi = 0; mi < 4; ++mi)
#pragma unroll
    for (int q = 0; q < 4; ++q) {
      const float m = mu[mi * 4 + q];
      float s = 0.f;
#pragma unroll
      for (int ni = 0; ni < 4; ++ni) { const float d = v[mi][ni][q] - m; s += d * d; }
      ps2[mi * 4 + q] = s;
    }
#pragma unroll
  for (int mask = 1; mask < 16; mask <<= 1)
#pragma unroll
    for (int t = 0; t < 16; ++t) ps2[t] += __shfl_xor(ps2[t], mask);
  if (fr == 0)
#pragma unroll
    for (int mi = 0; mi < 4; ++mi)
#pragma unroll
      for (int q = 0; q < 4; ++q)
        red[mi * 16 + fg * 4 + q][wave] = ps2[mi * 4 + q];
  __syncthreads();
  if (tid < 64) {
    float s = 0.f;
#pragma unroll
    for (int w = 0; w < 8; ++w) s += red[tid][w];
    rrow[tid] = rsqrtf(s * (1.f / 512.f) + EPS);
  }
  __syncthreads();

#pragma unroll
  for (int ni = 0; ni < 4; ++ni) {
    const int col = wave * 64 + ni * 16 + fr;
    const float gc = g[col], bc = bb[col];
#pragma unroll
    for (int mi = 0; mi < 4; ++mi)
#pragma unroll
      for (int q = 0; q < 4; ++q) {
        const int lrow = mi * 16 + fg * 4 + q;
        const float o = (v[mi][ni][q] - mu[mi * 4 + q]) * rrow[lrow] * gc + bc;
        outB[(size_t)(bm + lrow) * D + col] = __float2bfloat16(o);
      }
  }
}

// ---------------------------------------------------------------------------
// MFMA attention core (unchanged).
// ---------------------------------------------------------------------------
__global__ __launch_bounds__(256) void attn_mfma_kernel(
    const __hip_bfloat16* __restrict__ qg, int qstr,
    const __hip_bfloat16* __restrict__ kg, int kstr,
    const __hip_bfloat16* __restrict__ vt,
    __hip_bfloat16* __restrict__ yg) {
  __shared__ __align__(16) char smem[33280];
  unsigned short* Qs  = (unsigned short*)smem;
  unsigned short* Ks  = (unsigned short*)(smem + 8192);
  float*          Ss  = (float*)smem;
  unsigned short* Vts = (unsigned short*)(smem + 16896);
  unsigned short* Ps  = (unsigned short*)(smem + 25088);

  const int tid  = threadIdx.x;
  const int bh   = blockIdx.x;
  const int bidx = bh >> 3, h = bh & 7;
  const size_t rbase = (size_t)bidx * 64;
  const int col0 = h * 64;

  const __hip_bfloat16* vtg = vt + (size_t)bh * 4096;
#pragma unroll
  for (int p = 0; p < 2; ++p) {
    const int idx = tid + p * 256;
    const int row = idx >> 3, c8 = (idx & 7) * 8;
    const int lb  = (row * 128 + c8 * 2) ^ ((row & 7) << 4);
    const uint4 vq = *reinterpret_cast<const uint4*>(qg + (rbase + row) * qstr + col0 + c8);
    const uint4 vk = *reinterpret_cast<const uint4*>(kg + (rbase + row) * kstr + col0 + c8);
    const uint4 vv = *reinterpret_cast<const uint4*>(vtg + idx * 8);
    *reinterpret_cast<uint4*>((char*)Qs  + lb) = vq;
    *reinterpret_cast<uint4*>((char*)Ks  + lb) = vk;
    *reinterpret_cast<uint4*>((char*)Vts + lb) = vv;
  }
  __syncthreads();

  const int wave = tid >> 6, lane = tid & 63;
  const int fr = lane & 15, fg = lane >> 4;
  const int wr = (wave >> 1) * 32, wc = (wave & 1) * 32;

  auto ldfrag = [&](const unsigned short* base, int row, int ks) -> short8b {
    const int byte = (row * 128 + ks * 64 + fg * 16) ^ ((row & 7) << 4);
    return *reinterpret_cast<const short8b*>((const char*)base + byte);
  };

  f32x4 acc[2][2] = {};
#pragma unroll
  for (int ks = 0; ks < 2; ++ks) {
    short8b a[2], b[2];
    a[0] = ldfrag(Qs, wr + fr, ks);
    a[1] = ldfrag(Qs, wr + 16 + fr, ks);
    b[0] = ldfrag(Ks, wc + fr, ks);
    b[1] = ldfrag(Ks, wc + 16 + fr, ks);
#pragma unroll
    for (int mi = 0; mi < 2; ++mi)
#pragma unroll
      for (int ni = 0; ni < 2; ++ni)
        acc[mi][ni] = __builtin_amdgcn_mfma_f32_16x16x32_bf16(a[mi], b[ni], acc[mi][ni], 0, 0, 0);
  }
  __syncthreads();

#pragma unroll
  for (int mi = 0; mi < 2; ++mi)
#pragma unroll
    for (int ni = 0; ni < 2; ++ni) {
      const int m2 = wc + ni * 16 + fr;
#pragma unroll
      for (int r = 0; r < 4; ++r) {
        const int n = wr + mi * 16 + fg * 4 + r;
        Ss[n * 66 + m2] = (m2 <= n) ? acc[mi][ni][r] * SCALE : -1e30f;
      }
    }
  __syncthreads();

  for (int n = wave * 16; n < wave * 16 + 16; ++n) {
    const float vv = Ss[n * 66 + lane];
    float mx = vv;
#pragma unroll
    for (int off = 1; off < 64; off <<= 1) mx = fmaxf(mx, __shfl_xor(mx, off));
    const float p = (lane <= n) ? __expf(vv - mx) : 0.f;
    float sum = p;
#pragma unroll
    for (int off = 1; off < 64; off <<= 1) sum += __shfl_xor(sum, off);
    const int byte = (n * 128 + lane * 2) ^ ((n & 7) << 4);
    *(unsigned short*)((char*)Ps + byte) = f2b_bits(p / sum);
  }
  __syncthreads();

  f32x4 acc2[2][2] = {};
#pragma unroll
  for (int ks = 0; ks < 2; ++ks) {
    short8b a[2], b[2];
    a[0] = ldfrag(Ps, wr + fr, ks);
    a[1] = ldfrag(Ps, wr + 16 + fr, ks);
    b[0] = ldfrag(Vts, wc + fr, ks);
    b[1] = ldfrag(Vts, wc + 16 + fr, ks);
#pragma unroll
    for (int mi = 0; mi < 2; ++mi)
#pragma unroll
      for (int ni = 0; ni < 2; ++ni)
        acc2[mi][ni] = __builtin_amdgcn_mfma_f32_16x16x32_bf16(a[mi], b[ni], acc2[mi][ni], 0, 0, 0);
  }
#pragma unroll
  for (int mi = 0; mi < 2; ++mi)
#pragma unroll
    for (int r = 0; r < 4; ++r) {
      const int n = wr + mi * 16 + fg * 4 + r;
      yg[(rbase + n) * 512 + col0 + wc + fr]      = __float2bfloat16(acc2[mi][0][r]);
      yg[(rbase + n) * 512 + col0 + wc + 16 + fr] = __float2bfloat16(acc2[mi][1][r]);
    }
}

// ---------------------------------------------------------------------------
// Prep kernels (unchanged).
// ---------------------------------------------------------------------------
__global__ __launch_bounds__(256) void wconv_all_kernel(
    const float* __restrict__ bwq, const float* __restrict__ bwk,
    const float* __restrict__ bwv, const float* __restrict__ bwp,
    const float* __restrict__ bw1, const float* __restrict__ bw2,
    const float* __restrict__ wh1,
    __hip_bfloat16* __restrict__ wSelf, __hip_bfloat16* __restrict__ wCq,
    __hip_bfloat16* __restrict__ wCkv, __hip_bfloat16* __restrict__ wTp,
    __hip_bfloat16* __restrict__ wTw1, __hip_bfloat16* __restrict__ wTw2,
    __hip_bfloat16* __restrict__ wTh1) {
  const size_t MAT = (size_t)D * D;
  const size_t SS = (size_t)1536 * 512, KV = (size_t)1024 * 512;
  const int z = blockIdx.z;
  const float* src;
  __hip_bfloat16* dst;
  if (z < 8)       { int i = z >> 1; src = bwq + (size_t)z * MAT;
                     dst = (z & 1) ? wCq + (size_t)i * MAT : wSelf + (size_t)i * SS; }
  else if (z < 16) { int zz = z - 8, i = zz >> 1; src = bwk + (size_t)zz * MAT;
                     dst = (zz & 1) ? wCkv + (size_t)i * KV
                                    : wSelf + (size_t)i * SS + 512 * 512; }
  else if (z < 24) { int zz = z - 16, i = zz >> 1; src = bwv + (size_t)zz * MAT;
                     dst = (zz & 1) ? wCkv + (size_t)i * KV + 512 * 512
                                    : wSelf + (size_t)i * SS + 1024 * 512; }
  else if (z < 32) { int zz = z - 24; src = bwp + (size_t)zz * MAT; dst = wTp + (size_t)zz * MAT; }
  else if (z < 36) { int zz = z - 32; src = bw1 + (size_t)zz * MAT; dst = wTw1 + (size_t)zz * MAT; }
  else if (z < 40) { int zz = z - 36; src = bw2 + (size_t)zz * MAT; dst = wTw2 + (size_t)zz * MAT; }
  else             { src = wh1; dst = wTh1; }

  __shared__ float tile[32][33];
  const int r0 = blockIdx.y * 32, c0 = blockIdx.x * 32;
  const int tr = threadIdx.x >> 5;
  const int tc = threadIdx.x & 31;
#pragma unroll
  for (int i = 0; i < 4; ++i)
    tile[tr + 8 * i][tc] = src[(size_t)(r0 + tr + 8 * i) * D + c0 + tc];
  __syncthreads();
#pragma unroll
  for (int i = 0; i < 4; ++i)
    dst[(size_t)(c0 + tr + 8 * i) * D + r0 + tc] = __float2bfloat16(tile[tc][tr + 8 * i]);
}

__global__ __launch_bounds__(256) void misc_prep_kernel(
    const float* __restrict__ w_ae, const float* __restrict__ wh2,
    const float* __restrict__ bbq, const float* __restrict__ bbk,
    const float* __restrict__ bbv, const float* __restrict__ action,
    __hip_bfloat16* __restrict__ waeT, __hip_bfloat16* __restrict__ wh2p,
    float* __restrict__ selfb, float* __restrict__ ckvb,
    float* __restrict__ bqc, __hip_bfloat16* __restrict__ actb) {
  constexpr int R0 = 512 * 96, R1 = 128 * 512, R2 = NBLK * 1536,
                R3 = NBLK * 1024, R4 = NBLK * 512, R5 = M * 96;
  constexpr int total = R0 + R1 + R2 + R3 + R4 + R5;
  for (int i = blockIdx.x * 256 + threadIdx.x; i < total; i += gridDim.x * 256) {
    int j = i;
    if (j < R0) {
      const int n = j / 96, k = j - n * 96;
      waeT[j] = (k < 65) ? __float2bfloat16(w_ae[(size_t)k * 512 + n]) : __float2bfloat16(0.f);
    } else if ((j -= R0) < R1) {
      const int n = j >> 9, k = j & 511;
      wh2p[j] = (n < 64) ? __float2bfloat16(wh2[(size_t)k * 64 + n]) : __float2bfloat16(0.f);
    } else if ((j -= R1) < R2) {
      const int blk = j / 1536, c = j - blk * 1536;
      const int seg = c >> 9, cc = c & 511;
      const float* s = (seg == 0) ? bbq : (seg == 1) ? bbk : bbv;
      selfb[j] = s[(size_t)(blk * 2) * 512 + cc];
    } else if ((j -= R2) < R3) {
      const int blk = j >> 10, c = j & 1023;
      ckvb[j] = (c < 512) ? bbk[(size_t)(blk * 2 + 1) * 512 + c]
                          : bbv[(size_t)(blk * 2 + 1) * 512 + (c - 512)];
    } else if ((j -= R3) < R4) {
      const int blk = j >> 9, c = j & 511;
      bqc[j] = bbq[(size_t)(blk * 2 + 1) * 512 + c];
    } else {
      j -= R4;
      const int row = j / 96, k = j - row * 96;
      actb[j] = (k < 65) ? __float2bfloat16(action[(size_t)row * 65 + k]) : __float2bfloat16(0.f);
    }
  }
}

__global__ __launch_bounds__(256) void cvt_kernel(
    const float* __restrict__ src, __hip_bfloat16* __restrict__ dst, int n4) {
  const int i = blockIdx.x * 256 + threadIdx.x;
  if (i < n4) {
    const float4 v = reinterpret_cast<const float4*>(src)[i];
    ushort4 o;
    o.x = f2b_bits(v.x); o.y = f2b_bits(v.y);
    o.z = f2b_bits(v.z); o.w = f2b_bits(v.w);
    reinterpret_cast<ushort4*>(dst)[i] = o;
  }
}

}  // namespace

extern "C" void kernel_launch(void* const* d_in, const int* in_sizes, int n_in,
                              void* d_out, int out_size, void* d_ws, size_t ws_size,
                              hipStream_t stream) {
  const float* action  = (const float*)d_in[0];
  const float* obs_rep = (const float*)d_in[1];
  const float* w_ae    = (const float*)d_in[3];
  const float* ln0_g   = (const float*)d_in[4];
  const float* ln0_b   = (const float*)d_in[5];
  const float* bln_g   = (const float*)d_in[6];
  const float* bln_b   = (const float*)d_in[7];
  const float* bwq     = (const float*)d_in[8];
  const float* bwk     = (const float*)d_in[9];
  const float* bwv     = (const float*)d_in[10];
  const float* bwp     = (const float*)d_in[11];
  const float* bbq     = (const float*)d_in[12];
  const float* bbk     = (const float*)d_in[13];
  const float* bbv     = (const float*)d_in[14];
  const float* bbp     = (const float*)d_in[15];
  const float* bw1     = (const float*)d_in[16];
  const float* bb1     = (const float*)d_in[17];
  const float* bw2     = (const float*)d_in[18];
  const float* bb2     = (const float*)d_in[19];
  const float* wh1     = (const float*)d_in[20];
  const float* bh1     = (const float*)d_in[21];
  const float* lnh_g   = (const float*)d_in[22];
  const float* lnh_b   = (const float*)d_in[23];
  const float* wh2     = (const float*)d_in[24];
  const float* bh2     = (const float*)d_in[25];

  char* ws = (char*)d_ws;
  const size_t MAT = (size_t)D * D;
  const size_t szB = (size_t)M * D * 2;

  __hip_bfloat16* xb  = (__hip_bfloat16*)ws; ws += szB;
  __hip_bfloat16* hb  = (__hip_bfloat16*)ws; ws += szB;
  __hip_bfloat16* vtb = (__hip_bfloat16*)ws; ws += szB;
  __hip_bfloat16* orb = (__hip_bfloat16*)ws; ws += szB;
  __hip_bfloat16* qkb = (__hip_bfloat16*)ws; ws += 2 * szB;
  __hip_bfloat16* qcb = (__hip_bfloat16*)ws; ws += 4 * szB;
  __hip_bfloat16* kb  = (__hip_bfloat16*)ws; ws += szB;
  __hip_bfloat16* actb = (__hip_bfloat16*)ws; ws += (size_t)M * 96 * 2;
  __hip_bfloat16* wSelf = (__hip_bfloat16*)ws; ws += (size_t)NBLK * 1536 * 512 * 2;
  __hip_bfloat16* wCq   = (__hip_bfloat16*)ws; ws += (size_t)NBLK * 512 * 512 * 2;
  __hip_bfloat16* wCkv  = (__hip_bfloat16*)ws; ws += (size_t)NBLK * 1024 * 512 * 2;
  __hip_bfloat16* wTp   = (__hip_bfloat16*)ws; ws += 8 * MAT * 2;
  __hip_bfloat16* wTw1  = (__hip_bfloat16*)ws; ws += 4 * MAT * 2;
  __hip_bfloat16* wTw2  = (__hip_bfloat16*)ws; ws += 4 * MAT * 2;
  __hip_bfloat16* wTh1  = (__hip_bfloat16*)ws; ws += MAT * 2;
  __hip_bfloat16* wh2p  = (__hip_bfloat16*)ws; ws += 128 * 512 * 2;
  __hip_bfloat16* waeT  = (__hip_bfloat16*)ws; ws += 512 * 96 * 2;
  float* selfb         = (float*)ws;         ws += (size_t)NBLK * 1536 * 4;
  float* ckvb          = (float*)ws;         ws += (size_t)NBLK * 1024 * 4;
  float* bqc           = (float*)ws;         ws += (size_t)NBLK * 512 * 4;

  // ---- prep ----
  wconv_all_kernel<<<dim3(16, 16, 41), 256, 0, stream>>>(
      bwq, bwk, bwv, bwp, bw1, bw2, wh1,
      wSelf, wCq, wCkv, wTp, wTw1, wTw2, wTh1);
  misc_prep_kernel<<<2048, 256, 0, stream>>>(
      w_ae, wh2, bbq, bbk, bbv, action, waeT, wh2p, selfb, ckvb, bqc, actb);
  cvt_kernel<<<(M * D / 4 + 255) / 256, 256, 0, stream>>>(obs_rep, orb, M * D / 4);

  const size_t SS = (size_t)1536 * 512;
  const size_t KV = (size_t)1024 * 512;
  const int lnGrid = M / 64;

  // ---- encoder ----
  gemm_ln_enc_kernel<<<lnGrid, 512, 0, stream>>>(actb, waeT, ln0_g, ln0_b, xb);

  // ---- batched cross-attention Q for all 4 blocks ----
  gemm_dp_kernel<false, NEVER><<<M / 128 * 8, 512, 0, stream>>>(
      orb, wCq, bqc, qcb, 2048, nullptr, 8);

  for (int i = 0; i < NBLK; ++i) {
    const float* g0 = bln_g + (size_t)(i * 3 + 0) * D;
    const float* b0 = bln_b + (size_t)(i * 3 + 0) * D;
    const float* g1 = bln_g + (size_t)(i * 3 + 1) * D;
    const float* b1 = bln_b + (size_t)(i * 3 + 1) * D;
    const float* g2 = bln_g + (size_t)(i * 3 + 2) * D;
    const float* b2 = bln_b + (size_t)(i * 3 + 2) * D;

    // sublayer 1: self-attention
    gemm_dp_kernel<false, 1024><<<M / 128 * 6, 512, 0, stream>>>(
        xb, wSelf + (size_t)i * SS, selfb + (size_t)i * 1536, qkb, 1024, vtb, 6);
    attn_mfma_kernel<<<B * H, 256, 0, stream>>>(qkb, 1024, qkb + 512, 1024, vtb, hb);
    gemm_ln64_kernel<false, true><<<lnGrid, 512, 0, stream>>>(
        hb, wTp + (size_t)(i * 2) * MAT, bbp + (size_t)(i * 2) * D, xb, g0, b0, xb);

    // sublayer 2: cross-attention
    gemm_dp_kernel<false, 512><<<M / 128 * 4, 512, 0, stream>>>(
        xb, wCkv + (size_t)i * KV, ckvb + (size_t)i * 1024, kb, 512, vtb, 4);
    attn_mfma_kernel<<<B * H, 256, 0, stream>>>(
        qcb + (size_t)i * 512, 2048, kb, 512, vtb, hb);
    gemm_ln64_kernel<false, true><<<lnGrid, 512, 0, stream>>>(
        hb, wTp + (size_t)(i * 2 + 1) * MAT, bbp + (size_t)(i * 2 + 1) * D,
        orb, g1, b1, xb);

    // sublayer 3: fused MLP
    fused2_kernel<0><<<lnGrid, 512, 0, stream>>>(
        xb, wTw1 + (size_t)i * MAT, bb1 + (size_t)i * D,
        wTw2 + (size_t)i * MAT, bb2 + (size_t)i * D,
        xb, g2, b2, xb, nullptr);
  }

  // ---- head (fused GEMM+GELU+LN+GEMM) ----
  fused2_kernel<1><<<lnGrid, 512, 0, stream>>>(
      xb, wTh1, bh1, wh2p, bh2, nullptr, lnh_g, lnh_b, nullptr, (float*)d_out);
}

// Round 8
// 998.541 us; speedup vs baseline: 11.9655x; 1.0225x over previous
//
#include <hip/hip_runtime.h>
#include <hip/hip_bf16.h>
#include <math.h>

namespace {

constexpr int B  = 256;
constexpr int N  = 64;
constexpr int D  = 512;
constexpr int H  = 8;
constexpr int NBLK = 4;
constexpr int M  = B * N;
constexpr float EPS = 1e-5f;
constexpr float SCALE = 0.125f;
constexpr int NEVER = 1 << 20;

typedef __attribute__((ext_vector_type(8))) short short8b;
typedef __attribute__((ext_vector_type(4))) float f32x4;

__device__ __forceinline__ float gelu_exact(float x) {
  return 0.5f * x * (1.0f + erff(x * 0.70710678118654752440f));
}

__device__ __forceinline__ unsigned short f2b_bits(float f) {
  __hip_bfloat16 h = __float2bfloat16(f);
  return *reinterpret_cast<unsigned short*>(&h);
}

#define GLOBAL_AS __attribute__((address_space(1)))
#define LDS_AS    __attribute__((address_space(3)))

__device__ __forceinline__ void gload_lds16(const void* g, void* l) {
  __builtin_amdgcn_global_load_lds((const GLOBAL_AS void*)g, (LDS_AS void*)l, 16, 0, 0);
}

// ---------------------------------------------------------------------------
// Deep-pipelined bf16 MFMA GEMM (proven; unchanged).
// ---------------------------------------------------------------------------
template<bool GELU, int SPLIT>
__global__ __launch_bounds__(512, 2) void gemm_dp_kernel(
    const __hip_bfloat16* __restrict__ A,
    const __hip_bfloat16* __restrict__ Wt,
    const float* __restrict__ bias,
    __hip_bfloat16* __restrict__ out1, int ostr1,
    __hip_bfloat16* __restrict__ vt, int gy) {
  constexpr int K = 512;
  constexpr int NT = 8;
  __shared__ __hip_bfloat16 Als[3][128][64];
  __shared__ __hip_bfloat16 Bls[3][256][64];

  const int nwg = gridDim.x;
  const int hw  = blockIdx.x;
  const int cpx = nwg >> 3;
  const int lg  = (hw & 7) * cpx + (hw >> 3);
  const int bm  = (lg / gy) * 128;
  const int bn  = (lg % gy) * 256;

  const int tid  = threadIdx.x;
  const int wave = tid >> 6;
  const int lane = tid & 63;
  const int wm   = (wave >> 2) * 64;
  const int wn   = (wave & 3) * 64;
  const int fr   = lane & 15;
  const int fg   = lane >> 4;

  const int srow  = tid >> 3;
  const int sslot = (tid & 7) ^ (srow & 7);
  const __hip_bfloat16* gA = A  + (size_t)(bm + srow) * K + sslot * 8;
  const __hip_bfloat16* gB = Wt + (size_t)(bn + srow) * K + sslot * 8;

  auto STAGE = [&](int buf, int kt) {
    const int ko = kt * 64;
    char* la = (char*)&Als[buf][0][0] + wave * 1024;
    char* lb = (char*)&Bls[buf][0][0] + wave * 1024;
    gload_lds16(gA + ko,           la);
    gload_lds16(gA + 64 * K + ko,  la + 8192);
    gload_lds16(gB + ko,           lb);
    gload_lds16(gB + 64 * K + ko,  lb + 8192);
    gload_lds16(gB + 128 * K + ko, lb + 16384);
    gload_lds16(gB + 192 * K + ko, lb + 24576);
  };

  auto lda = [&](int buf, int mi, int ks) -> short8b {
    const int row  = wm + mi * 16 + fr;
    const int byte = row * 128 + (((ks << 2) | fg) ^ (fr & 7)) * 16;
    return *reinterpret_cast<const short8b*>((const char*)&Als[buf][0][0] + byte);
  };
  auto ldb = [&](int buf, int ni, int ks) -> short8b {
    const int row  = wn + ni * 16 + fr;
    const int byte = row * 128 + (((ks << 2) | fg) ^ (fr & 7)) * 16;
    return *reinterpret_cast<const short8b*>((const char*)&Bls[buf][0][0] + byte);
  };

  STAGE(0, 0);
  STAGE(1, 1);
  asm volatile("s_waitcnt vmcnt(6)" ::: "memory");
  __builtin_amdgcn_sched_barrier(0);
  __builtin_amdgcn_s_barrier();
  __builtin_amdgcn_sched_barrier(0);

  f32x4 acc[4][4] = {};
  for (int t = 0; t < NT; ++t) {
    const int cur = t % 3;
    if (t + 2 < NT) STAGE((t + 2) % 3, t + 2);

    short8b a0[4], b0[4], a1[4], b1[4];
#pragma unroll
    for (int mi = 0; mi < 4; ++mi) a0[mi] = lda(cur, mi, 0);
#pragma unroll
    for (int ni = 0; ni < 4; ++ni) b0[ni] = ldb(cur, ni, 0);
#pragma unroll
    for (int mi = 0; mi < 4; ++mi) a1[mi] = lda(cur, mi, 1);
#pragma unroll
    for (int ni = 0; ni < 4; ++ni) b1[ni] = ldb(cur, ni, 1);

    __builtin_amdgcn_s_setprio(1);
#pragma unroll
    for (int mi = 0; mi < 4; ++mi)
#pragma unroll
      for (int ni = 0; ni < 4; ++ni)
        acc[mi][ni] = __builtin_amdgcn_mfma_f32_16x16x32_bf16(a0[mi], b0[ni], acc[mi][ni], 0, 0, 0);
#pragma unroll
    for (int mi = 0; mi < 4; ++mi)
#pragma unroll
      for (int ni = 0; ni < 4; ++ni)
        acc[mi][ni] = __builtin_amdgcn_mfma_f32_16x16x32_bf16(a1[mi], b1[ni], acc[mi][ni], 0, 0, 0);
    __builtin_amdgcn_s_setprio(0);

    if (t + 2 < NT) {
      asm volatile("s_waitcnt vmcnt(6)" ::: "memory");
    } else {
      asm volatile("s_waitcnt vmcnt(0)" ::: "memory");
    }
    __builtin_amdgcn_sched_barrier(0);
    __builtin_amdgcn_s_barrier();
    __builtin_amdgcn_sched_barrier(0);
  }

#pragma unroll
  for (int ni = 0; ni < 4; ++ni) {
    const int col = bn + wn + ni * 16 + fr;
    const float bv = bias ? bias[col] : 0.f;
#pragma unroll
    for (int mi = 0; mi < 4; ++mi) {
      const int row0 = bm + wm + mi * 16 + fg * 4;
      if (col >= SPLIT) {
        const int vcol = col - SPLIT;
        ushort4 o;
        o.x = f2b_bits(acc[mi][ni][0] + bv);
        o.y = f2b_bits(acc[mi][ni][1] + bv);
        o.z = f2b_bits(acc[mi][ni][2] + bv);
        o.w = f2b_bits(acc[mi][ni][3] + bv);
        const int b8 = row0 >> 6, nl = row0 & 63;
        const int hh = vcol >> 6, dl = vcol & 63;
        *reinterpret_cast<ushort4*>(vt +
            ((size_t)(b8 * 8 + hh) * 4096 + dl * 64 + nl)) = o;
      } else {
#pragma unroll
        for (int q = 0; q < 4; ++q) {
          float v = acc[mi][ni][q] + bv;
          if (GELU) v = gelu_exact(v);
          out1[(size_t)(row0 + q) * ostr1 + col] = __float2bfloat16(v);
        }
      }
    }
  }
}

// ---------------------------------------------------------------------------
// GEMM + bias (+GELU) + bf16 residual + LN, BK=64 swizzled (K=512).
// BM=64 x BN=512 full width, 512 threads, 8 K-tiles. (Proven in R7.)
// ---------------------------------------------------------------------------
template<bool GELU_PRE, bool RES>
__global__ __launch_bounds__(512) void gemm_ln64_kernel(
    const __hip_bfloat16* __restrict__ A,
    const __hip_bfloat16* __restrict__ Wt,
    const float* __restrict__ bias,
    const __hip_bfloat16* __restrict__ resb,
    const float* __restrict__ g, const float* __restrict__ bb,
    __hip_bfloat16* __restrict__ outB) {
  __shared__ __hip_bfloat16 Als[2][64][64];
  __shared__ __hip_bfloat16 Bls[2][512][64];
  __shared__ float red[64][8];
  __shared__ float mrow[64];
  __shared__ float rrow[64];

  const int bm   = blockIdx.x * 64;
  const int tid  = threadIdx.x;
  const int wave = tid >> 6;
  const int lane = tid & 63;
  const int fr   = lane & 15;
  const int fg   = lane >> 4;

  const int srow  = tid >> 3;
  const int sslot = (tid & 7) ^ (srow & 7);

  auto stage = [&](int buf, int kt) {
    const int ko = kt * 64;
    gload_lds16(A + (size_t)(bm + srow) * 512 + ko + sslot * 8,
                (char*)&Als[buf][0][0] + wave * 1024);
#pragma unroll
    for (int j = 0; j < 8; ++j) {
      const int row = j * 64 + srow;
      const int sl  = (tid & 7) ^ (row & 7);
      gload_lds16(Wt + (size_t)row * 512 + ko + sl * 8,
                  (char*)&Bls[buf][0][0] + j * 8192 + wave * 1024);
    }
  };

  auto lda = [&](int buf, int mi, int ks) -> short8b {
    const int row  = mi * 16 + fr;
    const int byte = row * 128 + (((ks << 2) | fg) ^ (row & 7)) * 16;
    return *reinterpret_cast<const short8b*>((const char*)&Als[buf][0][0] + byte);
  };
  auto ldb = [&](int buf, int ni, int ks) -> short8b {
    const int row  = wave * 64 + ni * 16 + fr;
    const int byte = row * 128 + (((ks << 2) | fg) ^ (row & 7)) * 16;
    return *reinterpret_cast<const short8b*>((const char*)&Bls[buf][0][0] + byte);
  };

  f32x4 acc[4][4] = {};
  stage(0, 0);
  int buf = 0;
  for (int kt = 0; kt < 8; ++kt) {
    __syncthreads();
    if (kt + 1 < 8) stage(buf ^ 1, kt + 1);
    short8b a0[4], b0[4], a1[4], b1[4];
#pragma unroll
    for (int mi = 0; mi < 4; ++mi) a0[mi] = lda(buf, mi, 0);
#pragma unroll
    for (int ni = 0; ni < 4; ++ni) b0[ni] = ldb(buf, ni, 0);
#pragma unroll
    for (int mi = 0; mi < 4; ++mi) a1[mi] = lda(buf, mi, 1);
#pragma unroll
    for (int ni = 0; ni < 4; ++ni) b1[ni] = ldb(buf, ni, 1);
    __builtin_amdgcn_s_setprio(1);
#pragma unroll
    for (int mi = 0; mi < 4; ++mi)
#pragma unroll
      for (int ni = 0; ni < 4; ++ni)
        acc[mi][ni] = __builtin_amdgcn_mfma_f32_16x16x32_bf16(a0[mi], b0[ni], acc[mi][ni], 0, 0, 0);
#pragma unroll
    for (int mi = 0; mi < 4; ++mi)
#pragma unroll
      for (int ni = 0; ni < 4; ++ni)
        acc[mi][ni] = __builtin_amdgcn_mfma_f32_16x16x32_bf16(a1[mi], b1[ni], acc[mi][ni], 0, 0, 0);
    __builtin_amdgcn_s_setprio(0);
    buf ^= 1;
  }

  float v[4][4][4];
  float bvc[4];
#pragma unroll
  for (int ni = 0; ni < 4; ++ni)
    bvc[ni] = bias ? bias[wave * 64 + ni * 16 + fr] : 0.f;
#pragma unroll
  for (int mi = 0; mi < 4; ++mi)
#pragma unroll
    for (int q = 0; q < 4; ++q) {
      const int row = bm + mi * 16 + fg * 4 + q;
#pragma unroll
      for (int ni = 0; ni < 4; ++ni) {
        float t = acc[mi][ni][q] + bvc[ni];
        if (GELU_PRE) t = gelu_exact(t);
        if (RES)
          t += __bfloat162float(resb[(size_t)row * D + wave * 64 + ni * 16 + fr]);
        v[mi][ni][q] = t;
      }
    }

  float ps[16];
#pragma unroll
  for (int mi = 0; mi < 4; ++mi)
#pragma unroll
    for (int q = 0; q < 4; ++q)
      ps[mi * 4 + q] = v[mi][0][q] + v[mi][1][q] + v[mi][2][q] + v[mi][3][q];
#pragma unroll
  for (int mask = 1; mask < 16; mask <<= 1)
#pragma unroll
    for (int t = 0; t < 16; ++t) ps[t] += __shfl_xor(ps[t], mask);
  if (fr == 0) {
#pragma unroll
    for (int mi = 0; mi < 4; ++mi)
#pragma unroll
      for (int q = 0; q < 4; ++q)
        red[mi * 16 + fg * 4 + q][wave] = ps[mi * 4 + q];
  }
  __syncthreads();
  if (tid < 64) {
    float s = 0.f;
#pragma unroll
    for (int w = 0; w < 8; ++w) s += red[tid][w];
    mrow[tid] = s * (1.f / 512.f);
  }
  __syncthreads();
  float mu[16];
#pragma unroll
  for (int mi = 0; mi < 4; ++mi)
#pragma unroll
    for (int q = 0; q < 4; ++q) mu[mi * 4 + q] = mrow[mi * 16 + fg * 4 + q];

  float ps2[16];
#pragma unroll
  for (int mi = 0; mi < 4; ++mi)
#pragma unroll
    for (int q = 0; q < 4; ++q) {
      const float m = mu[mi * 4 + q];
      float s = 0.f;
#pragma unroll
      for (int ni = 0; ni < 4; ++ni) {
        const float d = v[mi][ni][q] - m;
        s += d * d;
      }
      ps2[mi * 4 + q] = s;
    }
#pragma unroll
  for (int mask = 1; mask < 16; mask <<= 1)
#pragma unroll
    for (int t = 0; t < 16; ++t) ps2[t] += __shfl_xor(ps2[t], mask);
  if (fr == 0) {
#pragma unroll
    for (int mi = 0; mi < 4; ++mi)
#pragma unroll
      for (int q = 0; q < 4; ++q)
        red[mi * 16 + fg * 4 + q][wave] = ps2[mi * 4 + q];
  }
  __syncthreads();
  if (tid < 64) {
    float s = 0.f;
#pragma unroll
    for (int w = 0; w < 8; ++w) s += red[tid][w];
    rrow[tid] = rsqrtf(s * (1.f / 512.f) + EPS);
  }
  __syncthreads();

#pragma unroll
  for (int ni = 0; ni < 4; ++ni) {
    const int col = wave * 64 + ni * 16 + fr;
    const float gc = g[col], bc = bb[col];
#pragma unroll
    for (int mi = 0; mi < 4; ++mi)
#pragma unroll
      for (int q = 0; q < 4; ++q) {
        const int lrow = mi * 16 + fg * 4 + q;
        const float o = (v[mi][ni][q] - mu[mi * 4 + q]) * rrow[lrow] * gc + bc;
        outB[(size_t)(bm + lrow) * D + col] = __float2bfloat16(o);
      }
  }
}

// ---------------------------------------------------------------------------
// Small head GEMM (m97 structure, f32 out, N=64 valid). Proven in R5/R6.
// ---------------------------------------------------------------------------
template<int KSTEPS>
__global__ __launch_bounds__(256) void gemm_head_kernel(
    const __hip_bfloat16* __restrict__ A,
    const __hip_bfloat16* __restrict__ Wt,
    const float* __restrict__ bias,
    float* __restrict__ out1, int ostr1, int nvalid) {
  constexpr int K = KSTEPS * 32;
  __shared__ __hip_bfloat16 Als[2][128][32];
  __shared__ __hip_bfloat16 Bls[2][128][32];

  const int bm   = blockIdx.x * 128;
  const int bn   = blockIdx.y * 128;
  const int tid  = threadIdx.x;
  const int wave = tid >> 6;
  const int lane = tid & 63;
  const int wm   = (wave >> 1) * 64;
  const int wn   = (wave & 1) * 64;
  const int fr   = lane & 15;
  const int fg   = lane >> 4;

  const int srow = (lane >> 2);
  const int scol = (lane & 3) * 8;
  const __hip_bfloat16* gA0 = A  + (size_t)(bm + wave * 32 + srow) * K + scol;
  const __hip_bfloat16* gA1 = gA0 + 16 * K;
  const __hip_bfloat16* gB0 = Wt + (size_t)(bn + wave * 32 + srow) * K + scol;
  const __hip_bfloat16* gB1 = gB0 + 16 * K;

  f32x4 acc[4][4] = {};

  auto stage = [&](int buf, int ks) {
    const int ko = ks * 32;
    gload_lds16(gA0 + ko, &Als[buf][wave * 32][0]);
    gload_lds16(gA1 + ko, &Als[buf][wave * 32 + 16][0]);
    gload_lds16(gB0 + ko, &Bls[buf][wave * 32][0]);
    gload_lds16(gB1 + ko, &Bls[buf][wave * 32 + 16][0]);
  };

  stage(0, 0);
  int buf = 0;
  for (int ks = 0; ks < KSTEPS; ++ks) {
    __syncthreads();
    if (ks + 1 < KSTEPS) stage(buf ^ 1, ks + 1);
    short8b a[4], b[4];
#pragma unroll
    for (int mi = 0; mi < 4; ++mi)
      a[mi] = *reinterpret_cast<const short8b*>(&Als[buf][wm + mi * 16 + fr][fg * 8]);
#pragma unroll
    for (int ni = 0; ni < 4; ++ni)
      b[ni] = *reinterpret_cast<const short8b*>(&Bls[buf][wn + ni * 16 + fr][fg * 8]);
#pragma unroll
    for (int mi = 0; mi < 4; ++mi)
#pragma unroll
      for (int ni = 0; ni < 4; ++ni)
        acc[mi][ni] = __builtin_amdgcn_mfma_f32_16x16x32_bf16(a[mi], b[ni], acc[mi][ni], 0, 0, 0);
    buf ^= 1;
  }

#pragma unroll
  for (int ni = 0; ni < 4; ++ni) {
    const int col = bn + wn + ni * 16 + fr;
    if (col >= nvalid) continue;
    const float bv = bias ? bias[col] : 0.f;
#pragma unroll
    for (int mi = 0; mi < 4; ++mi) {
      const int row0 = bm + wm + mi * 16 + fg * 4;
#pragma unroll
      for (int q = 0; q < 4; ++q)
        out1[(size_t)(row0 + q) * ostr1 + col] = acc[mi][ni][q] + bv;
    }
  }
}

// ---------------------------------------------------------------------------
// Encoder GEMM+GELU+LN (K=96, BK=32). Proven.
// ---------------------------------------------------------------------------
__global__ __launch_bounds__(512) void gemm_ln_enc_kernel(
    const __hip_bfloat16* __restrict__ A,
    const __hip_bfloat16* __restrict__ Wt,
    const float* __restrict__ g, const float* __restrict__ bb,
    __hip_bfloat16* __restrict__ outB) {
  constexpr int K = 96;
  __shared__ __hip_bfloat16 Als[2][64][32];
  __shared__ __hip_bfloat16 Bls[2][512][32];
  __shared__ float red[64][8];
  __shared__ float mrow[64];
  __shared__ float rrow[64];

  const int bm   = blockIdx.x * 64;
  const int tid  = threadIdx.x;
  const int wave = tid >> 6;
  const int lane = tid & 63;
  const int fr   = lane & 15;
  const int fg   = lane >> 4;
  const int srow = lane >> 2;
  const int scol = (lane & 3) * 8;

  auto stage = [&](int buf, int ks) {
    const int ko = ks * 32;
    if (wave < 4)
      gload_lds16(A + (size_t)(bm + wave * 16 + srow) * K + ko + scol,
                  &Als[buf][wave * 16][0]);
#pragma unroll
    for (int c = 0; c < 4; ++c)
      gload_lds16(Wt + (size_t)(wave * 64 + c * 16 + srow) * K + ko + scol,
                  &Bls[buf][wave * 64 + c * 16][0]);
  };

  f32x4 acc[4][4] = {};
  stage(0, 0);
  int buf = 0;
  for (int ks = 0; ks < 3; ++ks) {
    __syncthreads();
    if (ks + 1 < 3) stage(buf ^ 1, ks + 1);
    short8b a[4], b[4];
#pragma unroll
    for (int mi = 0; mi < 4; ++mi)
      a[mi] = *reinterpret_cast<const short8b*>(&Als[buf][mi * 16 + fr][fg * 8]);
#pragma unroll
    for (int ni = 0; ni < 4; ++ni)
      b[ni] = *reinterpret_cast<const short8b*>(&Bls[buf][wave * 64 + ni * 16 + fr][fg * 8]);
#pragma unroll
    for (int mi = 0; mi < 4; ++mi)
#pragma unroll
      for (int ni = 0; ni < 4; ++ni)
        acc[mi][ni] = __builtin_amdgcn_mfma_f32_16x16x32_bf16(a[mi], b[ni], acc[mi][ni], 0, 0, 0);
    buf ^= 1;
  }

  float v[4][4][4];
#pragma unroll
  for (int mi = 0; mi < 4; ++mi)
#pragma unroll
    for (int q = 0; q < 4; ++q)
#pragma unroll
      for (int ni = 0; ni < 4; ++ni)
        v[mi][ni][q] = gelu_exact(acc[mi][ni][q]);

  float ps[16];
#pragma unroll
  for (int mi = 0; mi < 4; ++mi)
#pragma unroll
    for (int q = 0; q < 4; ++q)
      ps[mi * 4 + q] = v[mi][0][q] + v[mi][1][q] + v[mi][2][q] + v[mi][3][q];
#pragma unroll
  for (int mask = 1; mask < 16; mask <<= 1)
#pragma unroll
    for (int t = 0; t < 16; ++t) ps[t] += __shfl_xor(ps[t], mask);
  if (fr == 0)
#pragma unroll
    for (int mi = 0; mi < 4; ++mi)
#pragma unroll
      for (int q = 0; q < 4; ++q)
        red[mi * 16 + fg * 4 + q][wave] = ps[mi * 4 + q];
  __syncthreads();
  if (tid < 64) {
    float s = 0.f;
#pragma unroll
    for (int w = 0; w < 8; ++w) s += red[tid][w];
    mrow[tid] = s * (1.f / 512.f);
  }
  __syncthreads();
  float mu[16];
#pragma unroll
  for (int mi = 0; mi < 4; ++mi)
#pragma unroll
    for (int q = 0; q < 4; ++q) mu[mi * 4 + q] = mrow[mi * 16 + fg * 4 + q];
  float ps2[16];
#pragma unroll
  for (int mi = 0; mi < 4; ++mi)
#pragma unroll
    for (int q = 0; q < 4; ++q) {
      const float m = mu[mi * 4 + q];
      float s = 0.f;
#pragma unroll
      for (int ni = 0; ni < 4; ++ni) { const float d = v[mi][ni][q] - m; s += d * d; }
      ps2[mi * 4 + q] = s;
    }
#pragma unroll
  for (int mask = 1; mask < 16; mask <<= 1)
#pragma unroll
    for (int t = 0; t < 16; ++t) ps2[t] += __shfl_xor(ps2[t], mask);
  if (fr == 0)
#pragma unroll
    for (int mi = 0; mi < 4; ++mi)
#pragma unroll
      for (int q = 0; q < 4; ++q)
        red[mi * 16 + fg * 4 + q][wave] = ps2[mi * 4 + q];
  __syncthreads();
  if (tid < 64) {
    float s = 0.f;
#pragma unroll
    for (int w = 0; w < 8; ++w) s += red[tid][w];
    rrow[tid] = rsqrtf(s * (1.f / 512.f) + EPS);
  }
  __syncthreads();

#pragma unroll
  for (int ni = 0; ni < 4; ++ni) {
    const int col = wave * 64 + ni * 16 + fr;
    const float gc = g[col], bc = bb[col];
#pragma unroll
    for (int mi = 0; mi < 4; ++mi)
#pragma unroll
      for (int q = 0; q < 4; ++q) {
        const int lrow = mi * 16 + fg * 4 + q;
        const float o = (v[mi][ni][q] - mu[mi * 4 + q]) * rrow[lrow] * gc + bc;
        outB[(size_t)(bm + lrow) * D + col] = __float2bfloat16(o);
      }
  }
}

// ---------------------------------------------------------------------------
// MFMA attention core (unchanged).
// ---------------------------------------------------------------------------
__global__ __launch_bounds__(256) void attn_mfma_kernel(
    const __hip_bfloat16* __restrict__ qg, int qstr,
    const __hip_bfloat16* __restrict__ kg, int kstr,
    const __hip_bfloat16* __restrict__ vt,
    __hip_bfloat16* __restrict__ yg) {
  __shared__ __align__(16) char smem[33280];
  unsigned short* Qs  = (unsigned short*)smem;
  unsigned short* Ks  = (unsigned short*)(smem + 8192);
  float*          Ss  = (float*)smem;
  unsigned short* Vts = (unsigned short*)(smem + 16896);
  unsigned short* Ps  = (unsigned short*)(smem + 25088);

  const int tid  = threadIdx.x;
  const int bh   = blockIdx.x;
  const int bidx = bh >> 3, h = bh & 7;
  const size_t rbase = (size_t)bidx * 64;
  const int col0 = h * 64;

  const __hip_bfloat16* vtg = vt + (size_t)bh * 4096;
#pragma unroll
  for (int p = 0; p < 2; ++p) {
    const int idx = tid + p * 256;
    const int row = idx >> 3, c8 = (idx & 7) * 8;
    const int lb  = (row * 128 + c8 * 2) ^ ((row & 7) << 4);
    const uint4 vq = *reinterpret_cast<const uint4*>(qg + (rbase + row) * qstr + col0 + c8);
    const uint4 vk = *reinterpret_cast<const uint4*>(kg + (rbase + row) * kstr + col0 + c8);
    const uint4 vv = *reinterpret_cast<const uint4*>(vtg + idx * 8);
    *reinterpret_cast<uint4*>((char*)Qs  + lb) = vq;
    *reinterpret_cast<uint4*>((char*)Ks  + lb) = vk;
    *reinterpret_cast<uint4*>((char*)Vts + lb) = vv;
  }
  __syncthreads();

  const int wave = tid >> 6, lane = tid & 63;
  const int fr = lane & 15, fg = lane >> 4;
  const int wr = (wave >> 1) * 32, wc = (wave & 1) * 32;

  auto ldfrag = [&](const unsigned short* base, int row, int ks) -> short8b {
    const int byte = (row * 128 + ks * 64 + fg * 16) ^ ((row & 7) << 4);
    return *reinterpret_cast<const short8b*>((const char*)base + byte);
  };

  f32x4 acc[2][2] = {};
#pragma unroll
  for (int ks = 0; ks < 2; ++ks) {
    short8b a[2], b[2];
    a[0] = ldfrag(Qs, wr + fr, ks);
    a[1] = ldfrag(Qs, wr + 16 + fr, ks);
    b[0] = ldfrag(Ks, wc + fr, ks);
    b[1] = ldfrag(Ks, wc + 16 + fr, ks);
#pragma unroll
    for (int mi = 0; mi < 2; ++mi)
#pragma unroll
      for (int ni = 0; ni < 2; ++ni)
        acc[mi][ni] = __builtin_amdgcn_mfma_f32_16x16x32_bf16(a[mi], b[ni], acc[mi][ni], 0, 0, 0);
  }
  __syncthreads();

#pragma unroll
  for (int mi = 0; mi < 2; ++mi)
#pragma unroll
    for (int ni = 0; ni < 2; ++ni) {
      const int m2 = wc + ni * 16 + fr;
#pragma unroll
      for (int r = 0; r < 4; ++r) {
        const int n = wr + mi * 16 + fg * 4 + r;
        Ss[n * 66 + m2] = (m2 <= n) ? acc[mi][ni][r] * SCALE : -1e30f;
      }
    }
  __syncthreads();

  for (int n = wave * 16; n < wave * 16 + 16; ++n) {
    const float vv = Ss[n * 66 + lane];
    float mx = vv;
#pragma unroll
    for (int off = 1; off < 64; off <<= 1) mx = fmaxf(mx, __shfl_xor(mx, off));
    const float p = (lane <= n) ? __expf(vv - mx) : 0.f;
    float sum = p;
#pragma unroll
    for (int off = 1; off < 64; off <<= 1) sum += __shfl_xor(sum, off);
    const int byte = (n * 128 + lane * 2) ^ ((n & 7) << 4);
    *(unsigned short*)((char*)Ps + byte) = f2b_bits(p / sum);
  }
  __syncthreads();

  f32x4 acc2[2][2] = {};
#pragma unroll
  for (int ks = 0; ks < 2; ++ks) {
    short8b a[2], b[2];
    a[0] = ldfrag(Ps, wr + fr, ks);
    a[1] = ldfrag(Ps, wr + 16 + fr, ks);
    b[0] = ldfrag(Vts, wc + fr, ks);
    b[1] = ldfrag(Vts, wc + 16 + fr, ks);
#pragma unroll
    for (int mi = 0; mi < 2; ++mi)
#pragma unroll
      for (int ni = 0; ni < 2; ++ni)
        acc2[mi][ni] = __builtin_amdgcn_mfma_f32_16x16x32_bf16(a[mi], b[ni], acc2[mi][ni], 0, 0, 0);
  }
#pragma unroll
  for (int mi = 0; mi < 2; ++mi)
#pragma unroll
    for (int r = 0; r < 4; ++r) {
      const int n = wr + mi * 16 + fg * 4 + r;
      yg[(rbase + n) * 512 + col0 + wc + fr]      = __float2bfloat16(acc2[mi][0][r]);
      yg[(rbase + n) * 512 + col0 + wc + 16 + fr] = __float2bfloat16(acc2[mi][1][r]);
    }
}

// ---------------------------------------------------------------------------
// Prep kernels.
// ---------------------------------------------------------------------------
__global__ __launch_bounds__(256) void wconv_all_kernel(
    const float* __restrict__ bwq, const float* __restrict__ bwk,
    const float* __restrict__ bwv, const float* __restrict__ bwp,
    const float* __restrict__ bw1, const float* __restrict__ bw2,
    const float* __restrict__ wh1,
    __hip_bfloat16* __restrict__ wSelf, __hip_bfloat16* __restrict__ wCq,
    __hip_bfloat16* __restrict__ wCkv, __hip_bfloat16* __restrict__ wTp,
    __hip_bfloat16* __restrict__ wTw1, __hip_bfloat16* __restrict__ wTw2,
    __hip_bfloat16* __restrict__ wTh1) {
  const size_t MAT = (size_t)D * D;
  const size_t SS = (size_t)1536 * 512, KV = (size_t)1024 * 512;
  const int z = blockIdx.z;
  const float* src;
  __hip_bfloat16* dst;
  if (z < 8)       { int i = z >> 1; src = bwq + (size_t)z * MAT;
                     dst = (z & 1) ? wCq + (size_t)i * MAT : wSelf + (size_t)i * SS; }
  else if (z < 16) { int zz = z - 8, i = zz >> 1; src = bwk + (size_t)zz * MAT;
                     dst = (zz & 1) ? wCkv + (size_t)i * KV
                                    : wSelf + (size_t)i * SS + 512 * 512; }
  else if (z < 24) { int zz = z - 16, i = zz >> 1; src = bwv + (size_t)zz * MAT;
                     dst = (zz & 1) ? wCkv + (size_t)i * KV + 512 * 512
                                    : wSelf + (size_t)i * SS + 1024 * 512; }
  else if (z < 32) { int zz = z - 24; src = bwp + (size_t)zz * MAT; dst = wTp + (size_t)zz * MAT; }
  else if (z < 36) { int zz = z - 32; src = bw1 + (size_t)zz * MAT; dst = wTw1 + (size_t)zz * MAT; }
  else if (z < 40) { int zz = z - 36; src = bw2 + (size_t)zz * MAT; dst = wTw2 + (size_t)zz * MAT; }
  else             { src = wh1; dst = wTh1; }

  __shared__ float tile[32][33];
  const int r0 = blockIdx.y * 32, c0 = blockIdx.x * 32;
  const int tr = threadIdx.x >> 5;
  const int tc = threadIdx.x & 31;
#pragma unroll
  for (int i = 0; i < 4; ++i)
    tile[tr + 8 * i][tc] = src[(size_t)(r0 + tr + 8 * i) * D + c0 + tc];
  __syncthreads();
#pragma unroll
  for (int i = 0; i < 4; ++i)
    dst[(size_t)(c0 + tr + 8 * i) * D + r0 + tc] = __float2bfloat16(tile[tc][tr + 8 * i]);
}

__global__ __launch_bounds__(256) void misc_prep_kernel(
    const float* __restrict__ w_ae, const float* __restrict__ wh2,
    const float* __restrict__ bbq, const float* __restrict__ bbk,
    const float* __restrict__ bbv, const float* __restrict__ action,
    const float* __restrict__ obs_rep,
    __hip_bfloat16* __restrict__ waeT, __hip_bfloat16* __restrict__ wh2p,
    float* __restrict__ selfb, float* __restrict__ ckvb,
    float* __restrict__ bqc, __hip_bfloat16* __restrict__ actb,
    __hip_bfloat16* __restrict__ orb) {
  constexpr int R0 = 512 * 96, R1 = 128 * 512, R2 = NBLK * 1536,
                R3 = NBLK * 1024, R4 = NBLK * 512, R5 = M * 96;
  constexpr int R6 = M * D / 4;   // obs_rep cvt, float4 granules
  constexpr int total = R0 + R1 + R2 + R3 + R4 + R5 + R6;
  for (int i = blockIdx.x * 256 + threadIdx.x; i < total; i += gridDim.x * 256) {
    int j = i;
    if (j < R0) {
      const int n = j / 96, k = j - n * 96;
      waeT[j] = (k < 65) ? __float2bfloat16(w_ae[(size_t)k * 512 + n]) : __float2bfloat16(0.f);
    } else if ((j -= R0) < R1) {
      const int n = j >> 9, k = j & 511;
      wh2p[j] = (n < 64) ? __float2bfloat16(wh2[(size_t)k * 64 + n]) : __float2bfloat16(0.f);
    } else if ((j -= R1) < R2) {
      const int blk = j / 1536, c = j - blk * 1536;
      const int seg = c >> 9, cc = c & 511;
      const float* s = (seg == 0) ? bbq : (seg == 1) ? bbk : bbv;
      selfb[j] = s[(size_t)(blk * 2) * 512 + cc];
    } else if ((j -= R2) < R3) {
      const int blk = j >> 10, c = j & 1023;
      ckvb[j] = (c < 512) ? bbk[(size_t)(blk * 2 + 1) * 512 + c]
                          : bbv[(size_t)(blk * 2 + 1) * 512 + (c - 512)];
    } else if ((j -= R3) < R4) {
      const int blk = j >> 9, c = j & 511;
      bqc[j] = bbq[(size_t)(blk * 2 + 1) * 512 + c];
    } else if ((j -= R4) < R5) {
      const int row = j / 96, k = j - row * 96;
      actb[j] = (k < 65) ? __float2bfloat16(action[(size_t)row * 65 + k]) : __float2bfloat16(0.f);
    } else {
      j -= R5;
      const float4 v = reinterpret_cast<const float4*>(obs_rep)[j];
      ushort4 o;
      o.x = f2b_bits(v.x); o.y = f2b_bits(v.y);
      o.z = f2b_bits(v.z); o.w = f2b_bits(v.w);
      reinterpret_cast<ushort4*>(orb)[j] = o;
    }
  }
}

}  // namespace

extern "C" void kernel_launch(void* const* d_in, const int* in_sizes, int n_in,
                              void* d_out, int out_size, void* d_ws, size_t ws_size,
                              hipStream_t stream) {
  const float* action  = (const float*)d_in[0];
  const float* obs_rep = (const float*)d_in[1];
  const float* w_ae    = (const float*)d_in[3];
  const float* ln0_g   = (const float*)d_in[4];
  const float* ln0_b   = (const float*)d_in[5];
  const float* bln_g   = (const float*)d_in[6];
  const float* bln_b   = (const float*)d_in[7];
  const float* bwq     = (const float*)d_in[8];
  const float* bwk     = (const float*)d_in[9];
  const float* bwv     = (const float*)d_in[10];
  const float* bwp     = (const float*)d_in[11];
  const float* bbq     = (const float*)d_in[12];
  const float* bbk     = (const float*)d_in[13];
  const float* bbv     = (const float*)d_in[14];
  const float* bbp     = (const float*)d_in[15];
  const float* bw1     = (const float*)d_in[16];
  const float* bb1     = (const float*)d_in[17];
  const float* bw2     = (const float*)d_in[18];
  const float* bb2     = (const float*)d_in[19];
  const float* wh1     = (const float*)d_in[20];
  const float* bh1     = (const float*)d_in[21];
  const float* lnh_g   = (const float*)d_in[22];
  const float* lnh_b   = (const float*)d_in[23];
  const float* wh2     = (const float*)d_in[24];
  const float* bh2     = (const float*)d_in[25];

  char* ws = (char*)d_ws;
  const size_t MAT = (size_t)D * D;
  const size_t szB = (size_t)M * D * 2;

  __hip_bfloat16* xb  = (__hip_bfloat16*)ws; ws += szB;
  __hip_bfloat16* hb  = (__hip_bfloat16*)ws; ws += szB;
  __hip_bfloat16* vtb = (__hip_bfloat16*)ws; ws += szB;
  __hip_bfloat16* orb = (__hip_bfloat16*)ws; ws += szB;
  __hip_bfloat16* qkb = (__hip_bfloat16*)ws; ws += 2 * szB;
  __hip_bfloat16* qcb = (__hip_bfloat16*)ws; ws += 4 * szB;
  __hip_bfloat16* kb  = (__hip_bfloat16*)ws; ws += szB;
  __hip_bfloat16* actb = (__hip_bfloat16*)ws; ws += (size_t)M * 96 * 2;
  __hip_bfloat16* wSelf = (__hip_bfloat16*)ws; ws += (size_t)NBLK * 1536 * 512 * 2;
  __hip_bfloat16* wCq   = (__hip_bfloat16*)ws; ws += (size_t)NBLK * 512 * 512 * 2;
  __hip_bfloat16* wCkv  = (__hip_bfloat16*)ws; ws += (size_t)NBLK * 1024 * 512 * 2;
  __hip_bfloat16* wTp   = (__hip_bfloat16*)ws; ws += 8 * MAT * 2;
  __hip_bfloat16* wTw1  = (__hip_bfloat16*)ws; ws += 4 * MAT * 2;
  __hip_bfloat16* wTw2  = (__hip_bfloat16*)ws; ws += 4 * MAT * 2;
  __hip_bfloat16* wTh1  = (__hip_bfloat16*)ws; ws += MAT * 2;
  __hip_bfloat16* wh2p  = (__hip_bfloat16*)ws; ws += 128 * 512 * 2;
  __hip_bfloat16* waeT  = (__hip_bfloat16*)ws; ws += 512 * 96 * 2;
  float* selfb         = (float*)ws;         ws += (size_t)NBLK * 1536 * 4;
  float* ckvb          = (float*)ws;         ws += (size_t)NBLK * 1024 * 4;
  float* bqc           = (float*)ws;         ws += (size_t)NBLK * 512 * 4;

  // ---- prep: 2 dispatches ----
  wconv_all_kernel<<<dim3(16, 16, 41), 256, 0, stream>>>(
      bwq, bwk, bwv, bwp, bw1, bw2, wh1,
      wSelf, wCq, wCkv, wTp, wTw1, wTw2, wTh1);
  misc_prep_kernel<<<2048, 256, 0, stream>>>(
      w_ae, wh2, bbq, bbk, bbv, action, obs_rep,
      waeT, wh2p, selfb, ckvb, bqc, actb, orb);

  const size_t SS = (size_t)1536 * 512;
  const size_t KV = (size_t)1024 * 512;
  const int lnGrid = M / 64;

  // ---- encoder ----
  gemm_ln_enc_kernel<<<lnGrid, 512, 0, stream>>>(actb, waeT, ln0_g, ln0_b, xb);

  // ---- batched cross-attention Q for all 4 blocks ----
  gemm_dp_kernel<false, NEVER><<<M / 128 * 8, 512, 0, stream>>>(
      orb, wCq, bqc, qcb, 2048, nullptr, 8);

  for (int i = 0; i < NBLK; ++i) {
    const float* g0 = bln_g + (size_t)(i * 3 + 0) * D;
    const float* b0 = bln_b + (size_t)(i * 3 + 0) * D;
    const float* g1 = bln_g + (size_t)(i * 3 + 1) * D;
    const float* b1 = bln_b + (size_t)(i * 3 + 1) * D;
    const float* g2 = bln_g + (size_t)(i * 3 + 2) * D;
    const float* b2 = bln_b + (size_t)(i * 3 + 2) * D;

    // sublayer 1: self-attention
    gemm_dp_kernel<false, 1024><<<M / 128 * 6, 512, 0, stream>>>(
        xb, wSelf + (size_t)i * SS, selfb + (size_t)i * 1536, qkb, 1024, vtb, 6);
    attn_mfma_kernel<<<B * H, 256, 0, stream>>>(qkb, 1024, qkb + 512, 1024, vtb, hb);
    gemm_ln64_kernel<false, true><<<lnGrid, 512, 0, stream>>>(
        hb, wTp + (size_t)(i * 2) * MAT, bbp + (size_t)(i * 2) * D, xb, g0, b0, xb);

    // sublayer 2: cross-attention
    gemm_dp_kernel<false, 512><<<M / 128 * 4, 512, 0, stream>>>(
        xb, wCkv + (size_t)i * KV, ckvb + (size_t)i * 1024, kb, 512, vtb, 4);
    attn_mfma_kernel<<<B * H, 256, 0, stream>>>(
        qcb + (size_t)i * 512, 2048, kb, 512, vtb, hb);
    gemm_ln64_kernel<false, true><<<lnGrid, 512, 0, stream>>>(
        hb, wTp + (size_t)(i * 2 + 1) * MAT, bbp + (size_t)(i * 2 + 1) * D,
        orb, g1, b1, xb);

    // sublayer 3: MLP (proven pair)
    gemm_dp_kernel<true, NEVER><<<M / 128 * 2, 512, 0, stream>>>(
        xb, wTw1 + (size_t)i * MAT, bb1 + (size_t)i * D, hb, 512, nullptr, 2);
    gemm_ln64_kernel<false, true><<<lnGrid, 512, 0, stream>>>(
        hb, wTw2 + (size_t)i * MAT, bb2 + (size_t)i * D, xb, g2, b2, xb);
  }

  // ---- head: GEMM+GELU+LN then small GEMM ----
  gemm_ln64_kernel<true, false><<<lnGrid, 512, 0, stream>>>(
      xb, wTh1, bh1, nullptr, lnh_g, lnh_b, hb);
  gemm_head_kernel<16><<<dim3(M / 128, 1), 256, 0, stream>>>(
      hb, wh2p, bh2, (float*)d_out, 64, 64);
}